// Round 1
// baseline (920.157 us; speedup 1.0000x reference)
//
#include <hip/hip_runtime.h>
#include <math.h>

#define Bg   32
#define NPGc 2048
#define Nn   (Bg*NPGc)      // 65536
#define DEGc 8
#define Ee   (Nn*DEGc)      // 524288
#define INc  64
#define H1c  128
#define H2c  256
#define K1c  1024
#define K2c  512
#define N1c  (Bg*K1c)       // 32768
#define N2c  (Bg*K2c)       // 16384

// ---------------- CSR build ----------------
__global__ void count_kernel(const int* __restrict__ tgt, int ne, int* __restrict__ deg) {
    int e = blockIdx.x * blockDim.x + threadIdx.x;
    if (e < ne) atomicAdd(&deg[tgt[e]], 1);
}

__global__ void count_dyn_kernel(const int* __restrict__ tgt, const int* __restrict__ ecnt,
                                 int* __restrict__ deg) {
    int e = blockIdx.x * blockDim.x + threadIdx.x;
    if (e < *ecnt) atomicAdd(&deg[tgt[e]], 1);
}

__global__ void __launch_bounds__(1024) scan_excl_kernel(const int* __restrict__ in,
                                                         int* __restrict__ out, int n) {
    __shared__ int buf[1024];
    __shared__ int carry_s;
    if (threadIdx.x == 0) carry_s = 0;
    __syncthreads();
    for (int base = 0; base < n; base += 1024) {
        int i = base + (int)threadIdx.x;
        int v = (i < n) ? in[i] : 0;
        buf[threadIdx.x] = v;
        __syncthreads();
        for (int off = 1; off < 1024; off <<= 1) {
            int t = (threadIdx.x >= (unsigned)off) ? buf[threadIdx.x - off] : 0;
            __syncthreads();
            buf[threadIdx.x] += t;
            __syncthreads();
        }
        int incl = buf[threadIdx.x];
        int c = carry_s;
        int tot = buf[1023];
        __syncthreads();
        if (i < n) out[i] = c + incl - v;
        if (threadIdx.x == 0) carry_s = c + tot;
        __syncthreads();
    }
    if (threadIdx.x == 0) out[n] = carry_s;
}

__global__ void fill_kernel(const int* __restrict__ src, const int* __restrict__ tgt, int ne,
                            const int* __restrict__ rowptr, int* __restrict__ wcur,
                            int* __restrict__ col) {
    int e = blockIdx.x * blockDim.x + threadIdx.x;
    if (e >= ne) return;
    int t = tgt[e];
    int p = rowptr[t] + atomicAdd(&wcur[t], 1);
    col[p] = src[e];
}

__global__ void fill_dyn_kernel(const int* __restrict__ src, const int* __restrict__ tgt,
                                const int* __restrict__ ecnt,
                                const int* __restrict__ rowptr, int* __restrict__ wcur,
                                int* __restrict__ col) {
    int e = blockIdx.x * blockDim.x + threadIdx.x;
    if (e >= *ecnt) return;
    int t = tgt[e];
    int p = rowptr[t] + atomicAdd(&wcur[t], 1);
    col[p] = src[e];
}

// ---------------- mean aggregation (wave per node) ----------------
__global__ void agg_mean_kernel(const float* __restrict__ x, const int* __restrict__ rowptr,
                                const int* __restrict__ col, float* __restrict__ out,
                                int n, int C) {
    int gid = blockIdx.x * blockDim.x + threadIdx.x;
    int node = gid >> 6;
    int lane = gid & 63;
    if (node >= n) return;
    int b = rowptr[node], e = rowptr[node + 1];
    float a0 = 0.f, a1 = 0.f;
    for (int i = b; i < e; i++) {
        int s = col[i];
        a0 += x[(size_t)s * C + lane];
        if (C > 64) a1 += x[(size_t)s * C + lane + 64];
    }
    int cnt = e - b; if (cnt < 1) cnt = 1;
    float inv = 1.f / (float)cnt;
    out[(size_t)node * C + lane] = a0 * inv;
    if (C > 64) out[(size_t)node * C + lane + 64] = a1 * inv;
}

// ---------------- GEMM layer1: [M,64]x[64,128] two mats ----------------
__global__ void __launch_bounds__(128) gemm1_kernel(const float* __restrict__ agg,
                                                    const float* __restrict__ x,
                                                    const float* __restrict__ Wl,
                                                    const float* __restrict__ Wr,
                                                    const float* __restrict__ bias,
                                                    float* __restrict__ out) {
    __shared__ float a_lds[16 * 64];
    __shared__ float x_lds[16 * 64];
    int node0 = blockIdx.x * 16;
    for (int idx = threadIdx.x; idx < 16 * 64; idx += 128) {
        a_lds[idx] = agg[(size_t)node0 * 64 + idx];
        x_lds[idx] = x[(size_t)node0 * 64 + idx];
    }
    __syncthreads();
    int ch = threadIdx.x;
    float acc[16];
#pragma unroll
    for (int i = 0; i < 16; i++) acc[i] = 0.f;
    for (int k = 0; k < 64; k++) {
        float wl = Wl[k * 128 + ch];
        float wr = Wr[k * 128 + ch];
#pragma unroll
        for (int i = 0; i < 16; i++)
            acc[i] += a_lds[i * 64 + k] * wl + x_lds[i * 64 + k] * wr;
    }
    float b = bias[ch];
#pragma unroll
    for (int i = 0; i < 16; i++) out[(size_t)(node0 + i) * 128 + ch] = acc[i] + b;
}

// ---------------- GEMM layer2: [M,128]x[128,256] two mats ----------------
__global__ void __launch_bounds__(256) gemm2_kernel(const float* __restrict__ agg,
                                                    const float* __restrict__ x,
                                                    const float* __restrict__ Wl,
                                                    const float* __restrict__ Wr,
                                                    const float* __restrict__ bias,
                                                    float* __restrict__ out) {
    __shared__ float a_lds[8 * 128];
    __shared__ float x_lds[8 * 128];
    int node0 = blockIdx.x * 8;
    for (int idx = threadIdx.x; idx < 8 * 128; idx += 256) {
        a_lds[idx] = agg[(size_t)node0 * 128 + idx];
        x_lds[idx] = x[(size_t)node0 * 128 + idx];
    }
    __syncthreads();
    int ch = threadIdx.x;
    float acc[8];
#pragma unroll
    for (int i = 0; i < 8; i++) acc[i] = 0.f;
    for (int k = 0; k < 128; k++) {
        float wl = Wl[k * 256 + ch];
        float wr = Wr[k * 256 + ch];
#pragma unroll
        for (int i = 0; i < 8; i++)
            acc[i] += a_lds[i * 128 + k] * wl + x_lds[i * 128 + k] * wr;
    }
    float b = bias[ch];
#pragma unroll
    for (int i = 0; i < 8; i++) out[(size_t)(node0 + i) * 256 + ch] = acc[i] + b;
}

// ---------------- BatchNorm stats (f64 atomics for accuracy) ----------------
__global__ void __launch_bounds__(256) bnstats_kernel(const float* __restrict__ h, int n, int C,
                                                      double* __restrict__ dsum,
                                                      double* __restrict__ dsq) {
    __shared__ float s1[256], s2[256];
    int c = threadIdx.x & (C - 1);
    int rpg = 256 / C;
    int sub = threadIdx.x / C;
    float s = 0.f, sq = 0.f;
    for (int row = blockIdx.x * rpg + sub; row < n; row += gridDim.x * rpg) {
        float v = h[(size_t)row * C + c];
        s += v; sq += v * v;
    }
    s1[threadIdx.x] = s; s2[threadIdx.x] = sq;
    __syncthreads();
    if (C == 128 && threadIdx.x < 128) {
        s1[threadIdx.x] += s1[threadIdx.x + 128];
        s2[threadIdx.x] += s2[threadIdx.x + 128];
    }
    __syncthreads();
    if ((int)threadIdx.x < C) {
        atomicAdd(&dsum[threadIdx.x], (double)s1[threadIdx.x]);
        atomicAdd(&dsq[threadIdx.x], (double)s2[threadIdx.x]);
    }
}

__global__ void bnfin_kernel(const double* __restrict__ dsum, const double* __restrict__ dsq,
                             const float* __restrict__ g, const float* __restrict__ b,
                             float* __restrict__ scale, float* __restrict__ shift,
                             int n, int C) {
    int c = threadIdx.x;
    if (c >= C) return;
    double m = dsum[c] / (double)n;
    double var = dsq[c] / (double)n - m * m;
    float sc = g[c] * (float)(1.0 / sqrt(var + 1e-5));
    scale[c] = sc;
    shift[c] = b[c] - (float)m * sc;
}

// ---------------- BN apply + ReLU + score dot-products (wave/node) ----------------
__global__ void bn_relu_score_kernel(float* __restrict__ h, const float* __restrict__ scale,
                                     const float* __restrict__ shift,
                                     const float* __restrict__ wrel,
                                     const float* __restrict__ wroot,
                                     float* __restrict__ r, float* __restrict__ root,
                                     int n, int C) {
    int gid = blockIdx.x * blockDim.x + threadIdx.x;
    int node = gid >> 6;
    int lane = gid & 63;
    if (node >= n) return;
    float rr = 0.f, rt = 0.f;
    for (int c = lane; c < C; c += 64) {
        float v = h[(size_t)node * C + c] * scale[c] + shift[c];
        v = fmaxf(v, 0.f);
        h[(size_t)node * C + c] = v;
        rr += v * wrel[c];
        rt += v * wroot[c];
    }
    for (int off = 32; off; off >>= 1) {
        rr += __shfl_down(rr, off);
        rt += __shfl_down(rt, off);
    }
    if (lane == 0) { r[node] = rr; root[node] = rt; }
}

// ---------------- score = brel + root + segsum(r[src]) ----------------
__global__ void segscore_kernel(const float* __restrict__ r, const float* __restrict__ root,
                                const int* __restrict__ rowptr, const int* __restrict__ col,
                                const float* __restrict__ brel, float* __restrict__ s, int n) {
    int t = blockIdx.x * blockDim.x + threadIdx.x;
    if (t >= n) return;
    float acc = brel[0] + root[t];
    for (int i = rowptr[t]; i < rowptr[t + 1]; i++) acc += r[col[i]];
    s[t] = acc;
}

// ---------------- per-graph bitonic top-k (exact top_k semantics) ----------------
__device__ __forceinline__ bool before_cmp(float av, int ai, float bv, int bi) {
    return (av > bv) || (av == bv && ai < bi);
}

__global__ void __launch_bounds__(1024) topk_kernel(const float* __restrict__ score, int npg,
                                                    int k, int* __restrict__ perm,
                                                    float* __restrict__ tval,
                                                    int* __restrict__ map) {
    __shared__ float vals[2048];
    __shared__ int idxs[2048];
    int g = blockIdx.x;
    for (int i = threadIdx.x; i < npg; i += blockDim.x) {
        vals[i] = score[(size_t)g * npg + i];
        idxs[i] = i;
    }
    __syncthreads();
    for (int kk = 2; kk <= npg; kk <<= 1) {
        for (int j = kk >> 1; j > 0; j >>= 1) {
            for (int i = threadIdx.x; i < npg; i += blockDim.x) {
                int ixj = i ^ j;
                if (ixj > i) {
                    bool up = ((i & kk) == 0);
                    float v1 = vals[i], v2 = vals[ixj];
                    int i1 = idxs[i], i2 = idxs[ixj];
                    bool sw = up ? before_cmp(v2, i2, v1, i1) : before_cmp(v1, i1, v2, i2);
                    if (sw) { vals[i] = v2; idxs[i] = i2; vals[ixj] = v1; idxs[ixj] = i1; }
                }
            }
            __syncthreads();
        }
    }
    for (int jj = threadIdx.x; jj < k; jj += blockDim.x) {
        int old_global = g * npg + idxs[jj];
        int m = g * k + jj;
        perm[m] = old_global;
        tval[m] = tanhf(vals[jj]);
        if (map) map[old_global] = m;
    }
}

// ---------------- gather pooled rows scaled by tanh(score) ----------------
__global__ void gather_kernel(const float* __restrict__ h, const int* __restrict__ perm,
                              const float* __restrict__ tval, float* __restrict__ out,
                              int total, int shift) {
    int t = blockIdx.x * blockDim.x + threadIdx.x;
    if (t >= total) return;
    int m = t >> shift;
    int c = t & ((1 << shift) - 1);
    out[t] = h[((size_t)perm[m] << shift) + c] * tval[m];
}

// ---------------- edge remap + compaction ----------------
__global__ void remap_kernel(const int* __restrict__ src, const int* __restrict__ tgt,
                             const int* __restrict__ map, int ne, int* __restrict__ ecnt,
                             int* __restrict__ src2, int* __restrict__ tgt2) {
    int e = blockIdx.x * blockDim.x + threadIdx.x;
    if (e >= ne) return;
    int ns = map[src[e]];
    int nt = map[tgt[e]];
    if (ns >= 0 && nt >= 0) {
        int p = atomicAdd(ecnt, 1);
        src2[p] = ns;
        tgt2[p] = nt;
    }
}

// ---------------- final: per-graph mean -> relu -> linear(2) -> softmax ----------------
__global__ void __launch_bounds__(256) final_kernel(const float* __restrict__ h2p,
                                                    const float* __restrict__ Wlin,
                                                    const float* __restrict__ blin,
                                                    float* __restrict__ out) {
    __shared__ float p0s[256], p1s[256];
    int g = blockIdx.x, c = threadIdx.x;
    const float* base = h2p + (size_t)g * K2c * 256;
    float s = 0.f;
    for (int i = 0; i < K2c; i++) s += base[(size_t)i * 256 + c];
    s = fmaxf(s * (1.f / (float)K2c), 0.f);
    p0s[c] = s * Wlin[c * 2 + 0];
    p1s[c] = s * Wlin[c * 2 + 1];
    __syncthreads();
    for (int off = 128; off; off >>= 1) {
        if (c < off) { p0s[c] += p0s[c + off]; p1s[c] += p1s[c + off]; }
        __syncthreads();
    }
    if (c == 0) {
        float o0 = p0s[0] + blin[0], o1 = p1s[0] + blin[1];
        float m = fmaxf(o0, o1);
        float e0 = expf(o0 - m), e1 = expf(o1 - m);
        float inv = 1.f / (e0 + e1);
        out[g * 2 + 0] = e0 * inv;
        out[g * 2 + 1] = e1 * inv;
    }
}

extern "C" void kernel_launch(void* const* d_in, const int* in_sizes, int n_in,
                              void* d_out, int out_size, void* d_ws, size_t ws_size,
                              hipStream_t stream) {
    const float* x      = (const float*)d_in[0];
    const int*   ei     = (const int*)d_in[1];
    const int*   src    = ei;
    const int*   tgt    = ei + Ee;
    const float* W1l    = (const float*)d_in[3];
    const float* b1l    = (const float*)d_in[4];
    const float* W1r    = (const float*)d_in[5];
    const float* bn1g   = (const float*)d_in[6];
    const float* bn1b   = (const float*)d_in[7];
    const float* p1Wrel = (const float*)d_in[8];
    const float* p1brel = (const float*)d_in[9];
    const float* p1Wroot= (const float*)d_in[10];
    const float* W2l    = (const float*)d_in[11];
    const float* b2l    = (const float*)d_in[12];
    const float* W2r    = (const float*)d_in[13];
    const float* bn2g   = (const float*)d_in[14];
    const float* bn2b   = (const float*)d_in[15];
    const float* p2Wrel = (const float*)d_in[16];
    const float* p2brel = (const float*)d_in[17];
    const float* p2Wroot= (const float*)d_in[18];
    const float* Wlin   = (const float*)d_in[19];
    const float* blin   = (const float*)d_in[20];
    float* out = (float*)d_out;
    char* ws = (char*)d_ws;

    // ---- workspace layout (lifetimes disjoint where aliased) ----
    size_t o = 0;
    auto A = [&](size_t b) { size_t r = o; o += (b + 255) & ~(size_t)255; return r; };
    size_t oBIG1 = A((size_t)Nn * H1c * 4);        // h1, later h2 (33.5 MB)
    size_t oBIG2 = A((size_t)Nn * INc * 4);        // agg1 -> agg2 -> h2p (16.8 MB)
    size_t oH1P  = A((size_t)N1c * H1c * 4);       // pooled layer-1 features (16.8 MB)
    size_t oCol1 = A((size_t)Ee * 4);
    size_t oRp1  = A((size_t)(Nn + 1) * 4);
    size_t oWc1  = A((size_t)Nn * 4);
    size_t oMap  = A((size_t)Nn * 4);
    size_t oR1   = A((size_t)Nn * 4);
    size_t oRoot1= A((size_t)Nn * 4);
    size_t oS1   = A((size_t)Nn * 4);
    size_t oPerm1= A((size_t)N1c * 4);
    size_t oTv1  = A((size_t)N1c * 4);
    size_t oSrc2 = A((size_t)Ee * 4);
    size_t oTgt2 = A((size_t)Ee * 4);
    size_t oCol2 = A((size_t)Ee * 4);
    size_t oRp2  = A((size_t)(N1c + 1) * 4);
    size_t oWc2  = A((size_t)N1c * 4);
    size_t oR2   = A((size_t)N1c * 4);
    size_t oRoot2= A((size_t)N1c * 4);
    size_t oS2   = A((size_t)N1c * 4);
    size_t oPerm2= A((size_t)N2c * 4);
    size_t oTv2  = A((size_t)N2c * 4);
    size_t oEc   = A(256);
    size_t oDsum = A(256 * 8);
    size_t oDsq  = A(256 * 8);
    size_t oScale= A(256 * 4);
    size_t oShift= A(256 * 4);
    (void)ws_size; (void)in_sizes; (void)n_in; (void)out_size;

    float* h1    = (float*)(ws + oBIG1);
    float* h2    = (float*)(ws + oBIG1);
    float* agg1  = (float*)(ws + oBIG2);
    float* agg2  = (float*)(ws + oBIG2);
    float* h2p   = (float*)(ws + oBIG2);
    float* h1p   = (float*)(ws + oH1P);
    int* col1    = (int*)(ws + oCol1);
    int* rp1     = (int*)(ws + oRp1);
    int* wc1     = (int*)(ws + oWc1);
    int* map1    = (int*)(ws + oMap);
    float* r1    = (float*)(ws + oR1);
    float* root1 = (float*)(ws + oRoot1);
    float* s1    = (float*)(ws + oS1);
    int* perm1   = (int*)(ws + oPerm1);
    float* tv1   = (float*)(ws + oTv1);
    int* src2    = (int*)(ws + oSrc2);
    int* tgt2    = (int*)(ws + oTgt2);
    int* col2    = (int*)(ws + oCol2);
    int* rp2     = (int*)(ws + oRp2);
    int* wc2     = (int*)(ws + oWc2);
    float* r2    = (float*)(ws + oR2);
    float* root2 = (float*)(ws + oRoot2);
    float* s2    = (float*)(ws + oS2);
    int* perm2   = (int*)(ws + oPerm2);
    float* tv2   = (float*)(ws + oTv2);
    int* ecnt2   = (int*)(ws + oEc);
    double* dsum = (double*)(ws + oDsum);
    double* dsq  = (double*)(ws + oDsq);
    float* scale = (float*)(ws + oScale);
    float* shift = (float*)(ws + oShift);

    // ===== Layer 1: CSR build =====
    hipMemsetAsync(wc1, 0, (size_t)Nn * 4, stream);
    count_kernel<<<Ee / 256, 256, 0, stream>>>(tgt, Ee, wc1);
    scan_excl_kernel<<<1, 1024, 0, stream>>>(wc1, rp1, Nn);
    hipMemsetAsync(wc1, 0, (size_t)Nn * 4, stream);
    fill_kernel<<<Ee / 256, 256, 0, stream>>>(src, tgt, Ee, rp1, wc1, col1);

    // SAGEConv1: mean-agg then linear
    agg_mean_kernel<<<(Nn * 64) / 256, 256, 0, stream>>>(x, rp1, col1, agg1, Nn, INc);
    gemm1_kernel<<<Nn / 16, 128, 0, stream>>>(agg1, x, W1l, W1r, b1l, h1);

    // BN1 + ReLU + score dots
    hipMemsetAsync(dsum, 0, 4096, stream);  // dsum + dsq contiguous
    bnstats_kernel<<<256, 256, 0, stream>>>(h1, Nn, H1c, dsum, dsq);
    bnfin_kernel<<<1, H1c, 0, stream>>>(dsum, dsq, bn1g, bn1b, scale, shift, Nn, H1c);
    bn_relu_score_kernel<<<(Nn * 64) / 256, 256, 0, stream>>>(h1, scale, shift, p1Wrel,
                                                              p1Wroot, r1, root1, Nn, H1c);
    segscore_kernel<<<Nn / 256, 256, 0, stream>>>(r1, root1, rp1, col1, p1brel, s1, Nn);

    // SAGPool1
    hipMemsetAsync(map1, 0xFF, (size_t)Nn * 4, stream);
    topk_kernel<<<Bg, 1024, 0, stream>>>(s1, NPGc, K1c, perm1, tv1, map1);
    gather_kernel<<<(N1c * H1c) / 256, 256, 0, stream>>>(h1, perm1, tv1, h1p, N1c * H1c, 7);
    hipMemsetAsync(ecnt2, 0, 4, stream);
    remap_kernel<<<Ee / 256, 256, 0, stream>>>(src, tgt, map1, Ee, ecnt2, src2, tgt2);

    // ===== Layer 2: CSR build on pooled graph =====
    hipMemsetAsync(wc2, 0, (size_t)N1c * 4, stream);
    count_dyn_kernel<<<Ee / 256, 256, 0, stream>>>(tgt2, ecnt2, wc2);
    scan_excl_kernel<<<1, 1024, 0, stream>>>(wc2, rp2, N1c);
    hipMemsetAsync(wc2, 0, (size_t)N1c * 4, stream);
    fill_dyn_kernel<<<Ee / 256, 256, 0, stream>>>(src2, tgt2, ecnt2, rp2, wc2, col2);

    // SAGEConv2
    agg_mean_kernel<<<(N1c * 64) / 256, 256, 0, stream>>>(h1p, rp2, col2, agg2, N1c, H1c);
    gemm2_kernel<<<N1c / 8, 256, 0, stream>>>(agg2, h1p, W2l, W2r, b2l, h2);

    // BN2 + ReLU + score dots
    hipMemsetAsync(dsum, 0, 4096, stream);
    bnstats_kernel<<<256, 256, 0, stream>>>(h2, N1c, H2c, dsum, dsq);
    bnfin_kernel<<<1, H2c, 0, stream>>>(dsum, dsq, bn2g, bn2b, scale, shift, N1c, H2c);
    bn_relu_score_kernel<<<(N1c * 64) / 256, 256, 0, stream>>>(h2, scale, shift, p2Wrel,
                                                               p2Wroot, r2, root2, N1c, H2c);
    segscore_kernel<<<N1c / 256, 256, 0, stream>>>(r2, root2, rp2, col2, p2brel, s2, N1c);

    // SAGPool2 (remapped edges unused downstream — skip remap)
    topk_kernel<<<Bg, 1024, 0, stream>>>(s2, K1c, K2c, perm2, tv2, nullptr);
    gather_kernel<<<(N2c * H2c) / 256, 256, 0, stream>>>(h2, perm2, tv2, h2p, N2c * H2c, 8);

    // Final readout
    final_kernel<<<Bg, 256, 0, stream>>>(h2p, Wlin, blin, out);
}

// Round 2
// 585.083 us; speedup vs baseline: 1.5727x; 1.5727x over previous
//
#include <hip/hip_runtime.h>
#include <math.h>

#define Bg   32
#define NPGc 2048
#define Nn   (Bg*NPGc)      // 65536
#define DEGc 8
#define Ee   (Nn*DEGc)      // 524288
#define INc  64
#define H1c  128
#define H2c  256
#define K1c  1024
#define K2c  512
#define N1c  (Bg*K1c)       // 32768
#define N2c  (Bg*K2c)       // 16384

typedef __attribute__((ext_vector_type(8))) short short8;
typedef __attribute__((ext_vector_type(4))) float f32x4;

__device__ __forceinline__ ushort f2bf(float f) {
    uint u = __float_as_uint(f);
    uint r = (u + 0x7fffu + ((u >> 16) & 1u)) >> 16;
    return (ushort)r;
}
__device__ __forceinline__ float bfhi(uint v) { return __uint_as_float(v & 0xffff0000u); }
__device__ __forceinline__ float bflo(uint v) { return __uint_as_float(v << 16); }

// ---------------- weight prep: transpose [K][C] f32 -> [C][K] bf16, all 4 mats ----------------
__global__ void wt_all_kernel(const float* __restrict__ W1l, const float* __restrict__ W1r,
                              const float* __restrict__ W2l, const float* __restrict__ W2r,
                              ushort* __restrict__ T1l, ushort* __restrict__ T1r,
                              ushort* __restrict__ T2l, ushort* __restrict__ T2r) {
    int id = blockIdx.x * blockDim.x + threadIdx.x;
    // ranges: 8192, 8192, 32768, 32768
    if (id < 8192) {
        int c = id / 64, k = id % 64;
        T1l[id] = f2bf(W1l[k * 128 + c]);
        T1r[id] = f2bf(W1r[k * 128 + c]);
    } else {
        id -= 8192;
        if (id >= 32768) return;
        int c = id / 128, k = id % 128;
        T2l[id] = f2bf(W2l[k * 256 + c]);
        T2r[id] = f2bf(W2r[k * 256 + c]);
    }
}

// ---------------- x f32 -> bf16 ----------------
__global__ void xconv_kernel(const float* __restrict__ x, ushort* __restrict__ xb, int n4) {
    int t = blockIdx.x * blockDim.x + threadIdx.x;
    if (t >= n4) return;
    float4 v = ((const float4*)x)[t];
    ushort4 o; o.x = f2bf(v.x); o.y = f2bf(v.y); o.z = f2bf(v.z); o.w = f2bf(v.w);
    ((ushort4*)xb)[t] = o;
}

// ---------------- CSR build ----------------
__global__ void count_kernel(const int* __restrict__ tgt, int ne, int* __restrict__ deg) {
    int e = blockIdx.x * blockDim.x + threadIdx.x;
    if (e < ne) atomicAdd(&deg[tgt[e]], 1);
}

__global__ void count_dyn_kernel(const int* __restrict__ tgt, const int* __restrict__ ecnt,
                                 int* __restrict__ deg) {
    int e = blockIdx.x * blockDim.x + threadIdx.x;
    if (e < *ecnt) atomicAdd(&deg[tgt[e]], 1);
}

// 3-phase scan: block=256 covers 1024 elements each
__global__ void __launch_bounds__(256) scan_part_kernel(const int* __restrict__ in,
                                                        int* __restrict__ bsum) {
    __shared__ int red[256];
    int base = blockIdx.x * 1024;
    int4 v = ((const int4*)&in[base])[threadIdx.x];
    int s = v.x + v.y + v.z + v.w;
    red[threadIdx.x] = s;
    __syncthreads();
    for (int off = 128; off; off >>= 1) {
        if ((int)threadIdx.x < off) red[threadIdx.x] += red[threadIdx.x + off];
        __syncthreads();
    }
    if (threadIdx.x == 0) bsum[blockIdx.x] = red[0];
}

__global__ void scan_mid_kernel(int* __restrict__ bsum, int nb, int* __restrict__ rp_last) {
    int t = threadIdx.x;
    int orig = (t < nb) ? bsum[t] : 0;
    int v = orig;
    for (int off = 1; off < 64; off <<= 1) {
        int u = __shfl_up(v, off);
        if (t >= off) v += u;
    }
    int total = __shfl(v, 63);
    if (t < nb) bsum[t] = v - orig;  // exclusive
    if (t == 0) *rp_last = total;
}

__global__ void __launch_bounds__(256) scan_fin_kernel(const int* __restrict__ in,
                                                       const int* __restrict__ bsum,
                                                       int* __restrict__ rp) {
    __shared__ int red[256];
    int base = blockIdx.x * 1024;
    int4 v = ((const int4*)&in[base])[threadIdx.x];
    int s = v.x + v.y + v.z + v.w;
    red[threadIdx.x] = s;
    __syncthreads();
    int val = s;
    for (int off = 1; off < 256; off <<= 1) {
        int t = ((int)threadIdx.x >= off) ? red[threadIdx.x - off] : 0;
        __syncthreads();
        val += t;
        red[threadIdx.x] = val;
        __syncthreads();
    }
    int o = val - s + bsum[blockIdx.x];
    int i0 = base + threadIdx.x * 4;
    rp[i0 + 0] = o; o += v.x;
    rp[i0 + 1] = o; o += v.y;
    rp[i0 + 2] = o; o += v.z;
    rp[i0 + 3] = o;
}

__global__ void fill_kernel(const int* __restrict__ src, const int* __restrict__ tgt, int ne,
                            const int* __restrict__ rowptr, int* __restrict__ wcur,
                            int* __restrict__ col) {
    int e = blockIdx.x * blockDim.x + threadIdx.x;
    if (e >= ne) return;
    int t = tgt[e];
    int p = rowptr[t] + atomicAdd(&wcur[t], 1);
    col[p] = src[e];
}

__global__ void fill_dyn_kernel(const int* __restrict__ src, const int* __restrict__ tgt,
                                const int* __restrict__ ecnt,
                                const int* __restrict__ rowptr, int* __restrict__ wcur,
                                int* __restrict__ col) {
    int e = blockIdx.x * blockDim.x + threadIdx.x;
    if (e >= *ecnt) return;
    int t = tgt[e];
    int p = rowptr[t] + atomicAdd(&wcur[t], 1);
    col[p] = src[e];
}

// ---------------- mean aggregation (wave per node) ----------------
// layer1: f32 in (C=64), bf16 out
__global__ void agg1_kernel(const float* __restrict__ x, const int* __restrict__ rowptr,
                            const int* __restrict__ col, ushort* __restrict__ out, int n) {
    int gid = blockIdx.x * blockDim.x + threadIdx.x;
    int node = gid >> 6;
    int lane = gid & 63;
    if (node >= n) return;
    int b = rowptr[node], e = rowptr[node + 1];
    float a0 = 0.f;
    for (int i = b; i < e; i++) a0 += x[(size_t)col[i] * 64 + lane];
    int cnt = e - b; if (cnt < 1) cnt = 1;
    out[(size_t)node * 64 + lane] = f2bf(a0 / (float)cnt);
}

// layer2: bf16 in (C=128), bf16 out; lane handles channel pair 2*lane
__global__ void agg2_kernel(const ushort* __restrict__ xb, const int* __restrict__ rowptr,
                            const int* __restrict__ col, ushort* __restrict__ out, int n) {
    int gid = blockIdx.x * blockDim.x + threadIdx.x;
    int node = gid >> 6;
    int lane = gid & 63;
    if (node >= n) return;
    int b = rowptr[node], e = rowptr[node + 1];
    float a0 = 0.f, a1 = 0.f;
    for (int i = b; i < e; i++) {
        uint v = *(const uint*)&xb[(size_t)col[i] * 128 + 2 * lane];
        a0 += bflo(v);
        a1 += bfhi(v);
    }
    int cnt = e - b; if (cnt < 1) cnt = 1;
    float inv = 1.f / (float)cnt;
    ushort2 st; st.x = f2bf(a0 * inv); st.y = f2bf(a1 * inv);
    *(ushort2*)&out[(size_t)node * 128 + 2 * lane] = st;
}

// ---------------- MFMA GEMM: out[M,COUT] = Aagg@Wl + Ax@Wr + bias ----------------
// A row-major bf16 [M][K]; Wt* = transposed bf16 weights [COUT][K].
// block = 256 thr = 4 waves; block tile 64 rows x 64 ch; K chunked by 64.
template<int K, int COUT>
__global__ __launch_bounds__(256) void gemm_mfma_kernel(
        const ushort* __restrict__ Aagg, const ushort* __restrict__ Ax,
        const ushort* __restrict__ Wtl, const ushort* __restrict__ Wtr,
        const float* __restrict__ bias, float* __restrict__ out) {
    __shared__ ushort As[2][64][72];   // pad 72: row stride 144B -> 2-way LDS (free)
    __shared__ ushort Bs[2][64][72];
    int m0 = blockIdx.x * 64;
    int c0 = blockIdx.y * 64;
    int lane = threadIdx.x & 63;
    int wid = threadIdx.x >> 6;
    int wr = (wid & 1) * 32, wc = (wid >> 1) * 32;
    int l16 = lane & 15, quad = lane >> 4;

    f32x4 acc[2][2];
#pragma unroll
    for (int a = 0; a < 2; a++)
#pragma unroll
        for (int b = 0; b < 2; b++) acc[a][b] = (f32x4){0.f, 0.f, 0.f, 0.f};

    for (int kk0 = 0; kk0 < K; kk0 += 64) {
        // stage 64x64 bf16 chunk of each of the 4 arrays (8KB each)
        for (int idx = threadIdx.x; idx < 512; idx += 256) {
            int r = idx >> 3, ck = (idx & 7) * 8;
            *(uint4*)&As[0][r][ck] = *(const uint4*)&Aagg[(size_t)(m0 + r) * K + kk0 + ck];
            *(uint4*)&As[1][r][ck] = *(const uint4*)&Ax[(size_t)(m0 + r) * K + kk0 + ck];
            *(uint4*)&Bs[0][r][ck] = *(const uint4*)&Wtl[(size_t)(c0 + r) * K + kk0 + ck];
            *(uint4*)&Bs[1][r][ck] = *(const uint4*)&Wtr[(size_t)(c0 + r) * K + kk0 + ck];
        }
        __syncthreads();
#pragma unroll
        for (int kk = 0; kk < 64; kk += 32) {
            short8 a[2][2], b[2][2];
#pragma unroll
            for (int s = 0; s < 2; s++)
#pragma unroll
                for (int mt = 0; mt < 2; mt++)
                    a[s][mt] = *(const short8*)&As[s][wr + mt * 16 + l16][kk + quad * 8];
#pragma unroll
            for (int s = 0; s < 2; s++)
#pragma unroll
                for (int nt = 0; nt < 2; nt++)
                    b[s][nt] = *(const short8*)&Bs[s][wc + nt * 16 + l16][kk + quad * 8];
#pragma unroll
            for (int mt = 0; mt < 2; mt++)
#pragma unroll
                for (int nt = 0; nt < 2; nt++) {
                    acc[mt][nt] = __builtin_amdgcn_mfma_f32_16x16x32_bf16(
                        a[0][mt], b[0][nt], acc[mt][nt], 0, 0, 0);
                    acc[mt][nt] = __builtin_amdgcn_mfma_f32_16x16x32_bf16(
                        a[1][mt], b[1][nt], acc[mt][nt], 0, 0, 0);
                }
        }
        __syncthreads();
    }
    // epilogue: D[row=quad*4+r][col=l16] per 16x16 tile
#pragma unroll
    for (int mt = 0; mt < 2; mt++)
#pragma unroll
        for (int nt = 0; nt < 2; nt++) {
            int col = c0 + wc + nt * 16 + l16;
            float bv = bias[col];
#pragma unroll
            for (int r = 0; r < 4; r++) {
                int row = m0 + wr + mt * 16 + quad * 4 + r;
                out[(size_t)row * COUT + col] = acc[mt][nt][r] + bv;
            }
        }
}

// ---------------- BatchNorm stats (f64 atomics for accuracy) ----------------
__global__ void __launch_bounds__(256) bnstats_kernel(const float* __restrict__ h, int n, int C,
                                                      double* __restrict__ dsum,
                                                      double* __restrict__ dsq) {
    __shared__ float s1[256], s2[256];
    int c = threadIdx.x & (C - 1);
    int rpg = 256 / C;
    int sub = threadIdx.x / C;
    float s = 0.f, sq = 0.f;
    for (int row = blockIdx.x * rpg + sub; row < n; row += gridDim.x * rpg) {
        float v = h[(size_t)row * C + c];
        s += v; sq += v * v;
    }
    s1[threadIdx.x] = s; s2[threadIdx.x] = sq;
    __syncthreads();
    if (C == 128 && threadIdx.x < 128) {
        s1[threadIdx.x] += s1[threadIdx.x + 128];
        s2[threadIdx.x] += s2[threadIdx.x + 128];
    }
    __syncthreads();
    if ((int)threadIdx.x < C) {
        atomicAdd(&dsum[threadIdx.x], (double)s1[threadIdx.x]);
        atomicAdd(&dsq[threadIdx.x], (double)s2[threadIdx.x]);
    }
}

__global__ void bnfin_kernel(const double* __restrict__ dsum, const double* __restrict__ dsq,
                             const float* __restrict__ g, const float* __restrict__ b,
                             float* __restrict__ scale, float* __restrict__ shift,
                             int n, int C) {
    int c = threadIdx.x;
    if (c >= C) return;
    double m = dsum[c] / (double)n;
    double var = dsq[c] / (double)n - m * m;
    float sc = g[c] * (float)(1.0 / sqrt(var + 1e-5));
    scale[c] = sc;
    shift[c] = b[c] - (float)m * sc;
}

// ---------------- BN apply + ReLU + score dot-products (wave/node) ----------------
__global__ void bn_relu_score_kernel(float* __restrict__ h, const float* __restrict__ scale,
                                     const float* __restrict__ shift,
                                     const float* __restrict__ wrel,
                                     const float* __restrict__ wroot,
                                     float* __restrict__ r, float* __restrict__ root,
                                     int n, int C) {
    int gid = blockIdx.x * blockDim.x + threadIdx.x;
    int node = gid >> 6;
    int lane = gid & 63;
    if (node >= n) return;
    float rr = 0.f, rt = 0.f;
    for (int c = lane; c < C; c += 64) {
        float v = h[(size_t)node * C + c] * scale[c] + shift[c];
        v = fmaxf(v, 0.f);
        h[(size_t)node * C + c] = v;
        rr += v * wrel[c];
        rt += v * wroot[c];
    }
    for (int off = 32; off; off >>= 1) {
        rr += __shfl_down(rr, off);
        rt += __shfl_down(rt, off);
    }
    if (lane == 0) { r[node] = rr; root[node] = rt; }
}

// ---------------- score = brel + root + segsum(r[src]) ----------------
__global__ void segscore_kernel(const float* __restrict__ r, const float* __restrict__ root,
                                const int* __restrict__ rowptr, const int* __restrict__ col,
                                const float* __restrict__ brel, float* __restrict__ s, int n) {
    int t = blockIdx.x * blockDim.x + threadIdx.x;
    if (t >= n) return;
    float acc = brel[0] + root[t];
    for (int i = rowptr[t]; i < rowptr[t + 1]; i++) acc += r[col[i]];
    s[t] = acc;
}

// ---------------- per-graph bitonic top-k (exact top_k semantics) ----------------
__device__ __forceinline__ bool before_cmp(float av, int ai, float bv, int bi) {
    return (av > bv) || (av == bv && ai < bi);
}

__global__ void __launch_bounds__(1024) topk_kernel(const float* __restrict__ score, int npg,
                                                    int k, int* __restrict__ perm,
                                                    float* __restrict__ tval,
                                                    int* __restrict__ map) {
    __shared__ float vals[2048];
    __shared__ int idxs[2048];
    int g = blockIdx.x;
    for (int i = threadIdx.x; i < npg; i += blockDim.x) {
        vals[i] = score[(size_t)g * npg + i];
        idxs[i] = i;
    }
    __syncthreads();
    for (int kk = 2; kk <= npg; kk <<= 1) {
        for (int j = kk >> 1; j > 0; j >>= 1) {
            for (int i = threadIdx.x; i < npg; i += blockDim.x) {
                int ixj = i ^ j;
                if (ixj > i) {
                    bool up = ((i & kk) == 0);
                    float v1 = vals[i], v2 = vals[ixj];
                    int i1 = idxs[i], i2 = idxs[ixj];
                    bool sw = up ? before_cmp(v2, i2, v1, i1) : before_cmp(v1, i1, v2, i2);
                    if (sw) { vals[i] = v2; idxs[i] = i2; vals[ixj] = v1; idxs[ixj] = i1; }
                }
            }
            __syncthreads();
        }
    }
    for (int jj = threadIdx.x; jj < k; jj += blockDim.x) {
        int old_global = g * npg + idxs[jj];
        int m = g * k + jj;
        perm[m] = old_global;
        tval[m] = tanhf(vals[jj]);
        if (map) map[old_global] = m;
    }
}

// ---------------- gathers ----------------
__global__ void gather_bf16_kernel(const float* __restrict__ h, const int* __restrict__ perm,
                                   const float* __restrict__ tval, ushort* __restrict__ out,
                                   int total) {
    int t = blockIdx.x * blockDim.x + threadIdx.x;
    if (t >= total) return;
    int m = t >> 7;
    int c = t & 127;
    out[t] = f2bf(h[((size_t)perm[m] << 7) + c] * tval[m]);
}

__global__ void gather_f32_kernel(const float* __restrict__ h, const int* __restrict__ perm,
                                  const float* __restrict__ tval, float* __restrict__ out,
                                  int total) {
    int t = blockIdx.x * blockDim.x + threadIdx.x;
    if (t >= total) return;
    int m = t >> 8;
    int c = t & 255;
    out[t] = h[((size_t)perm[m] << 8) + c] * tval[m];
}

// ---------------- edge remap + compaction ----------------
__global__ void remap_kernel(const int* __restrict__ src, const int* __restrict__ tgt,
                             const int* __restrict__ map, int ne, int* __restrict__ ecnt,
                             int* __restrict__ src2, int* __restrict__ tgt2) {
    int e = blockIdx.x * blockDim.x + threadIdx.x;
    if (e >= ne) return;
    int ns = map[src[e]];
    int nt = map[tgt[e]];
    if (ns >= 0 && nt >= 0) {
        int p = atomicAdd(ecnt, 1);
        src2[p] = ns;
        tgt2[p] = nt;
    }
}

// ---------------- final readout ----------------
__global__ void __launch_bounds__(256) pool_part_kernel(const float* __restrict__ h2p,
                                                        float* __restrict__ pooled) {
    int g = blockIdx.x, p = blockIdx.y, c = threadIdx.x;
    const float* base = h2p + ((size_t)g * K2c + p * 64) * H2c + c;
    float s = 0.f;
    for (int i = 0; i < 64; i++) s += base[(size_t)i * H2c];
    atomicAdd(&pooled[g * H2c + c], s);
}

__global__ void __launch_bounds__(256) pool_fin_kernel(const float* __restrict__ pooled,
                                                       const float* __restrict__ Wlin,
                                                       const float* __restrict__ blin,
                                                       float* __restrict__ out) {
    __shared__ float p0s[256], p1s[256];
    int g = blockIdx.x, c = threadIdx.x;
    float s = fmaxf(pooled[g * 256 + c] * (1.f / (float)K2c), 0.f);
    p0s[c] = s * Wlin[c * 2 + 0];
    p1s[c] = s * Wlin[c * 2 + 1];
    __syncthreads();
    for (int off = 128; off; off >>= 1) {
        if (c < off) { p0s[c] += p0s[c + off]; p1s[c] += p1s[c + off]; }
        __syncthreads();
    }
    if (c == 0) {
        float o0 = p0s[0] + blin[0], o1 = p1s[0] + blin[1];
        float m = fmaxf(o0, o1);
        float e0 = expf(o0 - m), e1 = expf(o1 - m);
        float inv = 1.f / (e0 + e1);
        out[g * 2 + 0] = e0 * inv;
        out[g * 2 + 1] = e1 * inv;
    }
}

extern "C" void kernel_launch(void* const* d_in, const int* in_sizes, int n_in,
                              void* d_out, int out_size, void* d_ws, size_t ws_size,
                              hipStream_t stream) {
    const float* x      = (const float*)d_in[0];
    const int*   ei     = (const int*)d_in[1];
    const int*   src    = ei;
    const int*   tgt    = ei + Ee;
    const float* W1l    = (const float*)d_in[3];
    const float* b1l    = (const float*)d_in[4];
    const float* W1r    = (const float*)d_in[5];
    const float* bn1g   = (const float*)d_in[6];
    const float* bn1b   = (const float*)d_in[7];
    const float* p1Wrel = (const float*)d_in[8];
    const float* p1brel = (const float*)d_in[9];
    const float* p1Wroot= (const float*)d_in[10];
    const float* W2l    = (const float*)d_in[11];
    const float* b2l    = (const float*)d_in[12];
    const float* W2r    = (const float*)d_in[13];
    const float* bn2g   = (const float*)d_in[14];
    const float* bn2b   = (const float*)d_in[15];
    const float* p2Wrel = (const float*)d_in[16];
    const float* p2brel = (const float*)d_in[17];
    const float* p2Wroot= (const float*)d_in[18];
    const float* Wlin   = (const float*)d_in[19];
    const float* blin   = (const float*)d_in[20];
    float* out = (float*)d_out;
    char* ws = (char*)d_ws;

    size_t o = 0;
    auto A = [&](size_t b) { size_t r = o; o += (b + 255) & ~(size_t)255; return r; };
    size_t oBIG1 = A((size_t)Nn * H1c * 4);        // h1 / h2 f32 (33.5 MB)
    size_t oBIG2 = A((size_t)Nn * INc * 4);        // xb+aggb1 bf16 -> later h2p f32 (16.8 MB)
    size_t oPB   = A((size_t)N1c * H1c * 4);       // h1pb bf16 + aggb2 bf16 (16.8 MB)
    size_t oCol1 = A((size_t)Ee * 4);
    size_t oRp1  = A((size_t)(Nn + 1) * 4);
    size_t oWc1  = A((size_t)Nn * 4);
    size_t oMap  = A((size_t)Nn * 4);
    size_t oR1   = A((size_t)Nn * 4);
    size_t oRoot1= A((size_t)Nn * 4);
    size_t oS1   = A((size_t)Nn * 4);
    size_t oPerm1= A((size_t)N1c * 4);
    size_t oTv1  = A((size_t)N1c * 4);
    size_t oSrc2 = A((size_t)Ee * 4);
    size_t oTgt2 = A((size_t)Ee * 4);
    size_t oCol2 = A((size_t)Ee * 4);
    size_t oRp2  = A((size_t)(N1c + 1) * 4);
    size_t oWc2  = A((size_t)N1c * 4);
    size_t oR2   = A((size_t)N1c * 4);
    size_t oRoot2= A((size_t)N1c * 4);
    size_t oS2   = A((size_t)N1c * 4);
    size_t oPerm2= A((size_t)N2c * 4);
    size_t oTv2  = A((size_t)N2c * 4);
    size_t oEc   = A(256);
    size_t oDsum = A(256 * 8);
    size_t oDsq  = A(256 * 8);
    size_t oScale= A(256 * 4);
    size_t oShift= A(256 * 4);
    size_t oBsum = A(64 * 4);
    size_t oWt1l = A(8192 * 2);
    size_t oWt1r = A(8192 * 2);
    size_t oWt2l = A(32768 * 2);
    size_t oWt2r = A(32768 * 2);
    size_t oPool = A(Bg * H2c * 4);
    (void)ws_size; (void)in_sizes; (void)n_in; (void)out_size;

    float* h1    = (float*)(ws + oBIG1);
    float* h2    = (float*)(ws + oBIG1);
    ushort* xb   = (ushort*)(ws + oBIG2);
    ushort* aggb1= (ushort*)(ws + oBIG2 + (size_t)Nn * 64 * 2);
    float* h2p   = (float*)(ws + oBIG2);
    ushort* h1pb = (ushort*)(ws + oPB);
    ushort* aggb2= (ushort*)(ws + oPB + (size_t)N1c * 128 * 2);
    int* col1    = (int*)(ws + oCol1);
    int* rp1     = (int*)(ws + oRp1);
    int* wc1     = (int*)(ws + oWc1);
    int* map1    = (int*)(ws + oMap);
    float* r1    = (float*)(ws + oR1);
    float* root1 = (float*)(ws + oRoot1);
    float* s1    = (float*)(ws + oS1);
    int* perm1   = (int*)(ws + oPerm1);
    float* tv1   = (float*)(ws + oTv1);
    int* src2    = (int*)(ws + oSrc2);
    int* tgt2    = (int*)(ws + oTgt2);
    int* col2    = (int*)(ws + oCol2);
    int* rp2     = (int*)(ws + oRp2);
    int* wc2     = (int*)(ws + oWc2);
    float* r2    = (float*)(ws + oR2);
    float* root2 = (float*)(ws + oRoot2);
    float* s2    = (float*)(ws + oS2);
    int* perm2   = (int*)(ws + oPerm2);
    float* tv2   = (float*)(ws + oTv2);
    int* ecnt2   = (int*)(ws + oEc);
    double* dsum = (double*)(ws + oDsum);
    double* dsq  = (double*)(ws + oDsq);
    float* scale = (float*)(ws + oScale);
    float* shift = (float*)(ws + oShift);
    int* bsum    = (int*)(ws + oBsum);
    ushort* T1l  = (ushort*)(ws + oWt1l);
    ushort* T1r  = (ushort*)(ws + oWt1r);
    ushort* T2l  = (ushort*)(ws + oWt2l);
    ushort* T2r  = (ushort*)(ws + oWt2r);
    float* pooled= (float*)(ws + oPool);

    // prep: weights + x -> bf16
    wt_all_kernel<<<(8192 + 32768 + 255) / 256, 256, 0, stream>>>(W1l, W1r, W2l, W2r,
                                                                  T1l, T1r, T2l, T2r);
    xconv_kernel<<<(Nn * 64 / 4 + 255) / 256, 256, 0, stream>>>(x, xb, Nn * 64 / 4);

    // ===== Layer 1: CSR build =====
    hipMemsetAsync(wc1, 0, (size_t)Nn * 4, stream);
    count_kernel<<<Ee / 256, 256, 0, stream>>>(tgt, Ee, wc1);
    scan_part_kernel<<<Nn / 1024, 256, 0, stream>>>(wc1, bsum);
    scan_mid_kernel<<<1, 64, 0, stream>>>(bsum, Nn / 1024, rp1 + Nn);
    scan_fin_kernel<<<Nn / 1024, 256, 0, stream>>>(wc1, bsum, rp1);
    hipMemsetAsync(wc1, 0, (size_t)Nn * 4, stream);
    fill_kernel<<<Ee / 256, 256, 0, stream>>>(src, tgt, Ee, rp1, wc1, col1);

    // SAGEConv1
    agg1_kernel<<<(Nn * 64) / 256, 256, 0, stream>>>(x, rp1, col1, aggb1, Nn);
    {
        dim3 g(Nn / 64, H1c / 64);
        gemm_mfma_kernel<INc, H1c><<<g, 256, 0, stream>>>(aggb1, xb, T1l, T1r, b1l, h1);
    }

    // BN1 + ReLU + score
    hipMemsetAsync(dsum, 0, 4096, stream);
    bnstats_kernel<<<256, 256, 0, stream>>>(h1, Nn, H1c, dsum, dsq);
    bnfin_kernel<<<1, H1c, 0, stream>>>(dsum, dsq, bn1g, bn1b, scale, shift, Nn, H1c);
    bn_relu_score_kernel<<<(Nn * 64) / 256, 256, 0, stream>>>(h1, scale, shift, p1Wrel,
                                                              p1Wroot, r1, root1, Nn, H1c);
    segscore_kernel<<<Nn / 256, 256, 0, stream>>>(r1, root1, rp1, col1, p1brel, s1, Nn);

    // SAGPool1
    hipMemsetAsync(map1, 0xFF, (size_t)Nn * 4, stream);
    topk_kernel<<<Bg, 1024, 0, stream>>>(s1, NPGc, K1c, perm1, tv1, map1);
    gather_bf16_kernel<<<(N1c * H1c) / 256, 256, 0, stream>>>(h1, perm1, tv1, h1pb, N1c * H1c);
    hipMemsetAsync(ecnt2, 0, 4, stream);
    remap_kernel<<<Ee / 256, 256, 0, stream>>>(src, tgt, map1, Ee, ecnt2, src2, tgt2);

    // ===== Layer 2: CSR =====
    hipMemsetAsync(wc2, 0, (size_t)N1c * 4, stream);
    count_dyn_kernel<<<Ee / 256, 256, 0, stream>>>(tgt2, ecnt2, wc2);
    scan_part_kernel<<<N1c / 1024, 256, 0, stream>>>(wc2, bsum);
    scan_mid_kernel<<<1, 64, 0, stream>>>(bsum, N1c / 1024, rp2 + N1c);
    scan_fin_kernel<<<N1c / 1024, 256, 0, stream>>>(wc2, bsum, rp2);
    hipMemsetAsync(wc2, 0, (size_t)N1c * 4, stream);
    fill_dyn_kernel<<<Ee / 256, 256, 0, stream>>>(src2, tgt2, ecnt2, rp2, wc2, col2);

    // SAGEConv2
    agg2_kernel<<<(N1c * 64) / 256, 256, 0, stream>>>(h1pb, rp2, col2, aggb2, N1c);
    {
        dim3 g(N1c / 64, H2c / 64);
        gemm_mfma_kernel<H1c, H2c><<<g, 256, 0, stream>>>(aggb2, h1pb, T2l, T2r, b2l, h2);
    }

    // BN2 + ReLU + score
    hipMemsetAsync(dsum, 0, 4096, stream);
    bnstats_kernel<<<256, 256, 0, stream>>>(h2, N1c, H2c, dsum, dsq);
    bnfin_kernel<<<1, H2c, 0, stream>>>(dsum, dsq, bn2g, bn2b, scale, shift, N1c, H2c);
    bn_relu_score_kernel<<<(N1c * 64) / 256, 256, 0, stream>>>(h2, scale, shift, p2Wrel,
                                                               p2Wroot, r2, root2, N1c, H2c);
    segscore_kernel<<<N1c / 256, 256, 0, stream>>>(r2, root2, rp2, col2, p2brel, s2, N1c);

    // SAGPool2
    topk_kernel<<<Bg, 1024, 0, stream>>>(s2, K1c, K2c, perm2, tv2, nullptr);
    gather_f32_kernel<<<(N2c * H2c) / 256, 256, 0, stream>>>(h2, perm2, tv2, h2p, N2c * H2c);

    // Final readout
    hipMemsetAsync(pooled, 0, Bg * H2c * 4, stream);
    {
        dim3 g(Bg, K2c / 64);
        pool_part_kernel<<<g, 256, 0, stream>>>(h2p, pooled);
    }
    pool_fin_kernel<<<Bg, 256, 0, stream>>>(pooled, Wlin, blin, out);
}

// Round 3
// 477.653 us; speedup vs baseline: 1.9264x; 1.2249x over previous
//
#include <hip/hip_runtime.h>
#include <math.h>

#define Bg   32
#define NPGc 2048
#define Nn   (Bg*NPGc)      // 65536
#define DEGc 8
#define Ee   (Nn*DEGc)      // 524288
#define INc  64
#define H1c  128
#define H2c  256
#define K1c  1024
#define K2c  512
#define N1c  (Bg*K1c)       // 32768
#define N2c  (Bg*K2c)       // 16384

typedef __attribute__((ext_vector_type(8))) short short8;
typedef __attribute__((ext_vector_type(4))) float f32x4;

__device__ __forceinline__ ushort f2bf(float f) {
    uint u = __float_as_uint(f);
    uint r = (u + 0x7fffu + ((u >> 16) & 1u)) >> 16;
    return (ushort)r;
}
__device__ __forceinline__ float bfhi(uint v) { return __uint_as_float(v & 0xffff0000u); }
__device__ __forceinline__ float bflo(uint v) { return __uint_as_float(v << 16); }

// ---------------- prep: weight transposes + all buffer inits (replaces 6 memsets) ----------------
// ranges: [0,8192) T1 pair, [8192,40960) T2 pair, then int4 zero/init jobs
__global__ void misc_prep_kernel(const float* __restrict__ W1l, const float* __restrict__ W1r,
                                 const float* __restrict__ W2l, const float* __restrict__ W2r,
                                 ushort* __restrict__ T1l, ushort* __restrict__ T1r,
                                 ushort* __restrict__ T2l, ushort* __restrict__ T2r,
                                 int* __restrict__ map1, int* __restrict__ wc1,
                                 int* __restrict__ wc2, int* __restrict__ dstats,
                                 int* __restrict__ pooled) {
    int id = blockIdx.x * blockDim.x + threadIdx.x;
    if (id < 8192) {
        int c = id / 64, k = id % 64;
        T1l[id] = f2bf(W1l[k * 128 + c]);
        T1r[id] = f2bf(W1r[k * 128 + c]);
        return;
    }
    id -= 8192;
    if (id < 32768) {
        int c = id / 128, k = id % 128;
        T2l[id] = f2bf(W2l[k * 256 + c]);
        T2r[id] = f2bf(W2r[k * 256 + c]);
        return;
    }
    id -= 32768;
    if (id < 16384) { ((int4*)map1)[id] = (int4){-1, -1, -1, -1}; return; }
    id -= 16384;
    if (id < 16384) { ((int4*)wc1)[id] = (int4){0, 0, 0, 0}; return; }
    id -= 16384;
    if (id < 8192)  { ((int4*)wc2)[id] = (int4){0, 0, 0, 0}; return; }
    id -= 8192;
    if (id < 384)   { ((int4*)dstats)[id] = (int4){0, 0, 0, 0}; return; }
    id -= 384;
    if (id < 2048)  { ((int4*)pooled)[id] = (int4){0, 0, 0, 0}; return; }
}

// ---------------- x f32 -> bf16 ----------------
__global__ void xconv_kernel(const float* __restrict__ x, ushort* __restrict__ xb, int n4) {
    int t = blockIdx.x * blockDim.x + threadIdx.x;
    if (t >= n4) return;
    float4 v = ((const float4*)x)[t];
    ushort4 o; o.x = f2bf(v.x); o.y = f2bf(v.y); o.z = f2bf(v.z); o.w = f2bf(v.w);
    ((ushort4*)xb)[t] = o;
}

// ---------------- CSR build ----------------
__global__ void count_kernel(const int* __restrict__ tgt, int ne, int* __restrict__ deg) {
    int e = blockIdx.x * blockDim.x + threadIdx.x;
    if (e < ne) atomicAdd(&deg[tgt[e]], 1);
}

// layer2: count directly from original edges through map (no compaction pass)
__global__ void count2_kernel(const int* __restrict__ src, const int* __restrict__ tgt,
                              const int* __restrict__ map, int* __restrict__ deg) {
    int e = blockIdx.x * blockDim.x + threadIdx.x;
    if (e >= Ee) return;
    int ns = map[src[e]];
    int nt = map[tgt[e]];
    if (ns >= 0 && nt >= 0) atomicAdd(&deg[nt], 1);
}

// 3-phase scan: block=256 covers 1024 elements each
__global__ void __launch_bounds__(256) scan_part_kernel(const int* __restrict__ in,
                                                        int* __restrict__ bsum) {
    __shared__ int red[256];
    int base = blockIdx.x * 1024;
    int4 v = ((const int4*)&in[base])[threadIdx.x];
    int s = v.x + v.y + v.z + v.w;
    red[threadIdx.x] = s;
    __syncthreads();
    for (int off = 128; off; off >>= 1) {
        if ((int)threadIdx.x < off) red[threadIdx.x] += red[threadIdx.x + off];
        __syncthreads();
    }
    if (threadIdx.x == 0) bsum[blockIdx.x] = red[0];
}

__global__ void scan_mid_kernel(int* __restrict__ bsum, int nb, int* __restrict__ rp_last) {
    int t = threadIdx.x;
    int orig = (t < nb) ? bsum[t] : 0;
    int v = orig;
    for (int off = 1; off < 64; off <<= 1) {
        int u = __shfl_up(v, off);
        if (t >= off) v += u;
    }
    int total = __shfl(v, 63);
    if (t < nb) bsum[t] = v - orig;  // exclusive
    if (t == 0) *rp_last = total;
}

// also emits cursor copy so fill needs no rowptr read / second zeroing pass
__global__ void __launch_bounds__(256) scan_fin_kernel(const int* __restrict__ in,
                                                       const int* __restrict__ bsum,
                                                       int* __restrict__ rp,
                                                       int* __restrict__ cur) {
    __shared__ int red[256];
    int base = blockIdx.x * 1024;
    int4 v = ((const int4*)&in[base])[threadIdx.x];
    int s = v.x + v.y + v.z + v.w;
    red[threadIdx.x] = s;
    __syncthreads();
    int val = s;
    for (int off = 1; off < 256; off <<= 1) {
        int t = ((int)threadIdx.x >= off) ? red[threadIdx.x - off] : 0;
        __syncthreads();
        val += t;
        red[threadIdx.x] = val;
        __syncthreads();
    }
    int o = val - s + bsum[blockIdx.x];
    int i0 = base + threadIdx.x * 4;
    int4 w;
    w.x = o; o += v.x;
    w.y = o; o += v.y;
    w.z = o; o += v.z;
    w.w = o;
    *(int4*)&rp[i0] = w;   // rp has extra slot; rp[n] written by scan_mid
    *(int4*)&cur[i0] = w;
}

__global__ void fill_kernel(const int* __restrict__ src, const int* __restrict__ tgt, int ne,
                            int* __restrict__ cur, int* __restrict__ col) {
    int e = blockIdx.x * blockDim.x + threadIdx.x;
    if (e >= ne) return;
    int p = atomicAdd(&cur[tgt[e]], 1);
    col[p] = src[e];
}

__global__ void fill2_kernel(const int* __restrict__ src, const int* __restrict__ tgt,
                             const int* __restrict__ map, int* __restrict__ cur,
                             int* __restrict__ col) {
    int e = blockIdx.x * blockDim.x + threadIdx.x;
    if (e >= Ee) return;
    int ns = map[src[e]];
    int nt = map[tgt[e]];
    if (ns >= 0 && nt >= 0) {
        int p = atomicAdd(&cur[nt], 1);
        col[p] = ns;
    }
}

// ---------------- mean aggregation (wave per node) ----------------
// layer1: f32 in (C=64), bf16 out
__global__ void agg1_kernel(const float* __restrict__ x, const int* __restrict__ rowptr,
                            const int* __restrict__ col, ushort* __restrict__ out, int n) {
    int gid = blockIdx.x * blockDim.x + threadIdx.x;
    int node = gid >> 6;
    int lane = gid & 63;
    if (node >= n) return;
    int b = rowptr[node], e = rowptr[node + 1];
    float a0 = 0.f;
    for (int i = b; i < e; i++) a0 += x[(size_t)col[i] * 64 + lane];
    int cnt = e - b; if (cnt < 1) cnt = 1;
    out[(size_t)node * 64 + lane] = f2bf(a0 / (float)cnt);
}

// layer2: bf16 in (C=128), bf16 out; lane handles channel pair 2*lane
__global__ void agg2_kernel(const ushort* __restrict__ xb, const int* __restrict__ rowptr,
                            const int* __restrict__ col, ushort* __restrict__ out, int n) {
    int gid = blockIdx.x * blockDim.x + threadIdx.x;
    int node = gid >> 6;
    int lane = gid & 63;
    if (node >= n) return;
    int b = rowptr[node], e = rowptr[node + 1];
    float a0 = 0.f, a1 = 0.f;
    for (int i = b; i < e; i++) {
        uint v = *(const uint*)&xb[(size_t)col[i] * 128 + 2 * lane];
        a0 += bflo(v);
        a1 += bfhi(v);
    }
    int cnt = e - b; if (cnt < 1) cnt = 1;
    float inv = 1.f / (float)cnt;
    ushort2 st; st.x = f2bf(a0 * inv); st.y = f2bf(a1 * inv);
    *(ushort2*)&out[(size_t)node * 128 + 2 * lane] = st;
}

// ---------------- MFMA GEMM: out[M,COUT] = Aagg@Wl + Ax@Wr + bias ----------------
template<int K, int COUT>
__global__ __launch_bounds__(256) void gemm_mfma_kernel(
        const ushort* __restrict__ Aagg, const ushort* __restrict__ Ax,
        const ushort* __restrict__ Wtl, const ushort* __restrict__ Wtr,
        const float* __restrict__ bias, float* __restrict__ out) {
    __shared__ ushort As[2][64][72];
    __shared__ ushort Bs[2][64][72];
    int m0 = blockIdx.x * 64;
    int c0 = blockIdx.y * 64;
    int lane = threadIdx.x & 63;
    int wid = threadIdx.x >> 6;
    int wr = (wid & 1) * 32, wc = (wid >> 1) * 32;
    int l16 = lane & 15, quad = lane >> 4;

    f32x4 acc[2][2];
#pragma unroll
    for (int a = 0; a < 2; a++)
#pragma unroll
        for (int b = 0; b < 2; b++) acc[a][b] = (f32x4){0.f, 0.f, 0.f, 0.f};

    for (int kk0 = 0; kk0 < K; kk0 += 64) {
        for (int idx = threadIdx.x; idx < 512; idx += 256) {
            int r = idx >> 3, ck = (idx & 7) * 8;
            *(uint4*)&As[0][r][ck] = *(const uint4*)&Aagg[(size_t)(m0 + r) * K + kk0 + ck];
            *(uint4*)&As[1][r][ck] = *(const uint4*)&Ax[(size_t)(m0 + r) * K + kk0 + ck];
            *(uint4*)&Bs[0][r][ck] = *(const uint4*)&Wtl[(size_t)(c0 + r) * K + kk0 + ck];
            *(uint4*)&Bs[1][r][ck] = *(const uint4*)&Wtr[(size_t)(c0 + r) * K + kk0 + ck];
        }
        __syncthreads();
#pragma unroll
        for (int kk = 0; kk < 64; kk += 32) {
            short8 a[2][2], b[2][2];
#pragma unroll
            for (int s = 0; s < 2; s++)
#pragma unroll
                for (int mt = 0; mt < 2; mt++)
                    a[s][mt] = *(const short8*)&As[s][wr + mt * 16 + l16][kk + quad * 8];
#pragma unroll
            for (int s = 0; s < 2; s++)
#pragma unroll
                for (int nt = 0; nt < 2; nt++)
                    b[s][nt] = *(const short8*)&Bs[s][wc + nt * 16 + l16][kk + quad * 8];
#pragma unroll
            for (int mt = 0; mt < 2; mt++)
#pragma unroll
                for (int nt = 0; nt < 2; nt++) {
                    acc[mt][nt] = __builtin_amdgcn_mfma_f32_16x16x32_bf16(
                        a[0][mt], b[0][nt], acc[mt][nt], 0, 0, 0);
                    acc[mt][nt] = __builtin_amdgcn_mfma_f32_16x16x32_bf16(
                        a[1][mt], b[1][nt], acc[mt][nt], 0, 0, 0);
                }
        }
        __syncthreads();
    }
#pragma unroll
    for (int mt = 0; mt < 2; mt++)
#pragma unroll
        for (int nt = 0; nt < 2; nt++) {
            int col = c0 + wc + nt * 16 + l16;
            float bv = bias[col];
#pragma unroll
            for (int r = 0; r < 4; r++) {
                int row = m0 + wr + mt * 16 + quad * 4 + r;
                out[(size_t)row * COUT + col] = acc[mt][nt][r] + bv;
            }
        }
}

// ---------------- BatchNorm stats (f64 atomics for accuracy) ----------------
__global__ void __launch_bounds__(256) bnstats_kernel(const float* __restrict__ h, int n, int C,
                                                      double* __restrict__ dsum,
                                                      double* __restrict__ dsq) {
    __shared__ float s1[256], s2[256];
    int c = threadIdx.x & (C - 1);
    int rpg = 256 / C;
    int sub = threadIdx.x / C;
    float s = 0.f, sq = 0.f;
    for (int row = blockIdx.x * rpg + sub; row < n; row += gridDim.x * rpg) {
        float v = h[(size_t)row * C + c];
        s += v; sq += v * v;
    }
    s1[threadIdx.x] = s; s2[threadIdx.x] = sq;
    __syncthreads();
    if (C == 128 && threadIdx.x < 128) {
        s1[threadIdx.x] += s1[threadIdx.x + 128];
        s2[threadIdx.x] += s2[threadIdx.x + 128];
    }
    __syncthreads();
    if ((int)threadIdx.x < C) {
        atomicAdd(&dsum[threadIdx.x], (double)s1[threadIdx.x]);
        atomicAdd(&dsq[threadIdx.x], (double)s2[threadIdx.x]);
    }
}

__global__ void bnfin_kernel(const double* __restrict__ dsum, const double* __restrict__ dsq,
                             const float* __restrict__ g, const float* __restrict__ b,
                             float* __restrict__ scale, float* __restrict__ shift,
                             int n, int C) {
    int c = threadIdx.x;
    if (c >= C) return;
    double m = dsum[c] / (double)n;
    double var = dsq[c] / (double)n - m * m;
    float sc = g[c] * (float)(1.0 / sqrt(var + 1e-5));
    scale[c] = sc;
    shift[c] = b[c] - (float)m * sc;
}

// ---------------- BN apply + ReLU + score dot-products (wave/node) ----------------
__global__ void bn_relu_score_kernel(float* __restrict__ h, const float* __restrict__ scale,
                                     const float* __restrict__ shift,
                                     const float* __restrict__ wrel,
                                     const float* __restrict__ wroot,
                                     float* __restrict__ r, float* __restrict__ root,
                                     int n, int C) {
    int gid = blockIdx.x * blockDim.x + threadIdx.x;
    int node = gid >> 6;
    int lane = gid & 63;
    if (node >= n) return;
    float rr = 0.f, rt = 0.f;
    for (int c = lane; c < C; c += 64) {
        float v = h[(size_t)node * C + c] * scale[c] + shift[c];
        v = fmaxf(v, 0.f);
        h[(size_t)node * C + c] = v;
        rr += v * wrel[c];
        rt += v * wroot[c];
    }
    for (int off = 32; off; off >>= 1) {
        rr += __shfl_down(rr, off);
        rt += __shfl_down(rt, off);
    }
    if (lane == 0) { r[node] = rr; root[node] = rt; }
}

// ---------------- score = brel + root + segsum(r[src]) ----------------
__global__ void segscore_kernel(const float* __restrict__ r, const float* __restrict__ root,
                                const int* __restrict__ rowptr, const int* __restrict__ col,
                                const float* __restrict__ brel, float* __restrict__ s, int n) {
    int t = blockIdx.x * blockDim.x + threadIdx.x;
    if (t >= n) return;
    float acc = brel[0] + root[t];
    for (int i = rowptr[t]; i < rowptr[t + 1]; i++) acc += r[col[i]];
    s[t] = acc;
}

// ---------------- per-graph bitonic top-k (exact top_k semantics) ----------------
__device__ __forceinline__ bool before_cmp(float av, int ai, float bv, int bi) {
    return (av > bv) || (av == bv && ai < bi);
}

__global__ void __launch_bounds__(1024) topk_kernel(const float* __restrict__ score, int npg,
                                                    int k, int* __restrict__ perm,
                                                    float* __restrict__ tval,
                                                    int* __restrict__ map) {
    __shared__ float vals[2048];
    __shared__ int idxs[2048];
    int g = blockIdx.x;
    for (int i = threadIdx.x; i < npg; i += blockDim.x) {
        vals[i] = score[(size_t)g * npg + i];
        idxs[i] = i;
    }
    __syncthreads();
    for (int kk = 2; kk <= npg; kk <<= 1) {
        for (int j = kk >> 1; j > 0; j >>= 1) {
            for (int i = threadIdx.x; i < npg; i += blockDim.x) {
                int ixj = i ^ j;
                if (ixj > i) {
                    bool up = ((i & kk) == 0);
                    float v1 = vals[i], v2 = vals[ixj];
                    int i1 = idxs[i], i2 = idxs[ixj];
                    bool sw = up ? before_cmp(v2, i2, v1, i1) : before_cmp(v1, i1, v2, i2);
                    if (sw) { vals[i] = v2; idxs[i] = i2; vals[ixj] = v1; idxs[ixj] = i1; }
                }
            }
            __syncthreads();
        }
    }
    for (int jj = threadIdx.x; jj < k; jj += blockDim.x) {
        int old_global = g * npg + idxs[jj];
        int m = g * k + jj;
        perm[m] = old_global;
        tval[m] = tanhf(vals[jj]);
        if (map) map[old_global] = m;
    }
}

// ---------------- gathers ----------------
__global__ void gather_bf16_kernel(const float* __restrict__ h, const int* __restrict__ perm,
                                   const float* __restrict__ tval, ushort* __restrict__ out,
                                   int total) {
    int t = blockIdx.x * blockDim.x + threadIdx.x;
    if (t >= total) return;
    int m = t >> 7;
    int c = t & 127;
    out[t] = f2bf(h[((size_t)perm[m] << 7) + c] * tval[m]);
}

__global__ void gather_f32_kernel(const float* __restrict__ h, const int* __restrict__ perm,
                                  const float* __restrict__ tval, float* __restrict__ out,
                                  int total) {
    int t = blockIdx.x * blockDim.x + threadIdx.x;
    if (t >= total) return;
    int m = t >> 8;
    int c = t & 255;
    out[t] = h[((size_t)perm[m] << 8) + c] * tval[m];
}

// ---------------- final readout ----------------
__global__ void __launch_bounds__(256) pool_part_kernel(const float* __restrict__ h2p,
                                                        float* __restrict__ pooled) {
    int g = blockIdx.x, p = blockIdx.y, c = threadIdx.x;
    const float* base = h2p + ((size_t)g * K2c + p * 64) * H2c + c;
    float s = 0.f;
    for (int i = 0; i < 64; i++) s += base[(size_t)i * H2c];
    atomicAdd(&pooled[g * H2c + c], s);
}

__global__ void __launch_bounds__(256) pool_fin_kernel(const float* __restrict__ pooled,
                                                       const float* __restrict__ Wlin,
                                                       const float* __restrict__ blin,
                                                       float* __restrict__ out) {
    __shared__ float p0s[256], p1s[256];
    int g = blockIdx.x, c = threadIdx.x;
    float s = fmaxf(pooled[g * 256 + c] * (1.f / (float)K2c), 0.f);
    p0s[c] = s * Wlin[c * 2 + 0];
    p1s[c] = s * Wlin[c * 2 + 1];
    __syncthreads();
    for (int off = 128; off; off >>= 1) {
        if (c < off) { p0s[c] += p0s[c + off]; p1s[c] += p1s[c + off]; }
        __syncthreads();
    }
    if (c == 0) {
        float o0 = p0s[0] + blin[0], o1 = p1s[0] + blin[1];
        float m = fmaxf(o0, o1);
        float e0 = expf(o0 - m), e1 = expf(o1 - m);
        float inv = 1.f / (e0 + e1);
        out[g * 2 + 0] = e0 * inv;
        out[g * 2 + 1] = e1 * inv;
    }
}

extern "C" void kernel_launch(void* const* d_in, const int* in_sizes, int n_in,
                              void* d_out, int out_size, void* d_ws, size_t ws_size,
                              hipStream_t stream) {
    const float* x      = (const float*)d_in[0];
    const int*   ei     = (const int*)d_in[1];
    const int*   src    = ei;
    const int*   tgt    = ei + Ee;
    const float* W1l    = (const float*)d_in[3];
    const float* b1l    = (const float*)d_in[4];
    const float* W1r    = (const float*)d_in[5];
    const float* bn1g   = (const float*)d_in[6];
    const float* bn1b   = (const float*)d_in[7];
    const float* p1Wrel = (const float*)d_in[8];
    const float* p1brel = (const float*)d_in[9];
    const float* p1Wroot= (const float*)d_in[10];
    const float* W2l    = (const float*)d_in[11];
    const float* b2l    = (const float*)d_in[12];
    const float* W2r    = (const float*)d_in[13];
    const float* bn2g   = (const float*)d_in[14];
    const float* bn2b   = (const float*)d_in[15];
    const float* p2Wrel = (const float*)d_in[16];
    const float* p2brel = (const float*)d_in[17];
    const float* p2Wroot= (const float*)d_in[18];
    const float* Wlin   = (const float*)d_in[19];
    const float* blin   = (const float*)d_in[20];
    float* out = (float*)d_out;
    char* ws = (char*)d_ws;

    size_t o = 0;
    auto A = [&](size_t b) { size_t r = o; o += (b + 255) & ~(size_t)255; return r; };
    size_t oBIG1 = A((size_t)Nn * H1c * 4);        // h1 / h2 f32 (33.5 MB)
    size_t oBIG2 = A((size_t)Nn * INc * 4);        // xb+aggb1 bf16 -> later h2p f32 (16.8 MB)
    size_t oPB   = A((size_t)N1c * H1c * 4);       // h1pb bf16 + aggb2 bf16 (16.8 MB)
    size_t oCol1 = A((size_t)Ee * 4);
    size_t oCol2 = A((size_t)Ee * 4);
    size_t oRp1  = A((size_t)(Nn + 1) * 4);
    size_t oWc1  = A((size_t)Nn * 4);
    size_t oCur1 = A((size_t)Nn * 4);
    size_t oMap  = A((size_t)Nn * 4);
    size_t oR1   = A((size_t)Nn * 4);
    size_t oRoot1= A((size_t)Nn * 4);
    size_t oS1   = A((size_t)Nn * 4);
    size_t oPerm1= A((size_t)N1c * 4);
    size_t oTv1  = A((size_t)N1c * 4);
    size_t oRp2  = A((size_t)(N1c + 1) * 4);
    size_t oWc2  = A((size_t)N1c * 4);
    size_t oCur2 = A((size_t)N1c * 4);
    size_t oR2   = A((size_t)N1c * 4);
    size_t oRoot2= A((size_t)N1c * 4);
    size_t oS2   = A((size_t)N1c * 4);
    size_t oPerm2= A((size_t)N2c * 4);
    size_t oTv2  = A((size_t)N2c * 4);
    size_t oDst  = A(768 * 8);                     // dsum1(128)+dsq1(128)+dsum2(256)+dsq2(256)
    size_t oScale= A(256 * 4);
    size_t oShift= A(256 * 4);
    size_t oBsum = A(64 * 4);
    size_t oWt1l = A(8192 * 2);
    size_t oWt1r = A(8192 * 2);
    size_t oWt2l = A(32768 * 2);
    size_t oWt2r = A(32768 * 2);
    size_t oPool = A(Bg * H2c * 4);
    (void)ws_size; (void)in_sizes; (void)n_in; (void)out_size;

    float* h1    = (float*)(ws + oBIG1);
    float* h2    = (float*)(ws + oBIG1);
    ushort* xb   = (ushort*)(ws + oBIG2);
    ushort* aggb1= (ushort*)(ws + oBIG2 + (size_t)Nn * 64 * 2);
    float* h2p   = (float*)(ws + oBIG2);
    ushort* h1pb = (ushort*)(ws + oPB);
    ushort* aggb2= (ushort*)(ws + oPB + (size_t)N1c * 128 * 2);
    int* col1    = (int*)(ws + oCol1);
    int* col2    = (int*)(ws + oCol2);
    int* rp1     = (int*)(ws + oRp1);
    int* wc1     = (int*)(ws + oWc1);
    int* cur1    = (int*)(ws + oCur1);
    int* map1    = (int*)(ws + oMap);
    float* r1    = (float*)(ws + oR1);
    float* root1 = (float*)(ws + oRoot1);
    float* s1    = (float*)(ws + oS1);
    int* perm1   = (int*)(ws + oPerm1);
    float* tv1   = (float*)(ws + oTv1);
    int* rp2     = (int*)(ws + oRp2);
    int* wc2     = (int*)(ws + oWc2);
    int* cur2    = (int*)(ws + oCur2);
    float* r2    = (float*)(ws + oR2);
    float* root2 = (float*)(ws + oRoot2);
    float* s2    = (float*)(ws + oS2);
    int* perm2   = (int*)(ws + oPerm2);
    float* tv2   = (float*)(ws + oTv2);
    double* dsum1= (double*)(ws + oDst);
    double* dsq1 = dsum1 + 128;
    double* dsum2= dsum1 + 256;
    double* dsq2 = dsum1 + 512;
    float* scale = (float*)(ws + oScale);
    float* shift = (float*)(ws + oShift);
    int* bsum    = (int*)(ws + oBsum);
    ushort* T1l  = (ushort*)(ws + oWt1l);
    ushort* T1r  = (ushort*)(ws + oWt1r);
    ushort* T2l  = (ushort*)(ws + oWt2l);
    ushort* T2r  = (ushort*)(ws + oWt2r);
    float* pooled= (float*)(ws + oPool);

    // prep: weights->bf16, x->bf16, all zero/init jobs (no memsets needed)
    misc_prep_kernel<<<(84352 + 255) / 256, 256, 0, stream>>>(
        W1l, W1r, W2l, W2r, T1l, T1r, T2l, T2r, map1, wc1, wc2, (int*)dsum1, (int*)pooled);
    xconv_kernel<<<(Nn * 64 / 4 + 255) / 256, 256, 0, stream>>>(x, xb, Nn * 64 / 4);

    // ===== Layer 1: CSR =====
    count_kernel<<<Ee / 256, 256, 0, stream>>>(tgt, Ee, wc1);
    scan_part_kernel<<<Nn / 1024, 256, 0, stream>>>(wc1, bsum);
    scan_mid_kernel<<<1, 64, 0, stream>>>(bsum, Nn / 1024, rp1 + Nn);
    scan_fin_kernel<<<Nn / 1024, 256, 0, stream>>>(wc1, bsum, rp1, cur1);
    fill_kernel<<<Ee / 256, 256, 0, stream>>>(src, tgt, Ee, cur1, col1);

    // SAGEConv1
    agg1_kernel<<<(Nn * 64) / 256, 256, 0, stream>>>(x, rp1, col1, aggb1, Nn);
    {
        dim3 g(Nn / 64, H1c / 64);
        gemm_mfma_kernel<INc, H1c><<<g, 256, 0, stream>>>(aggb1, xb, T1l, T1r, b1l, h1);
    }

    // BN1 + ReLU + score
    bnstats_kernel<<<256, 256, 0, stream>>>(h1, Nn, H1c, dsum1, dsq1);
    bnfin_kernel<<<1, H1c, 0, stream>>>(dsum1, dsq1, bn1g, bn1b, scale, shift, Nn, H1c);
    bn_relu_score_kernel<<<(Nn * 64) / 256, 256, 0, stream>>>(h1, scale, shift, p1Wrel,
                                                              p1Wroot, r1, root1, Nn, H1c);
    segscore_kernel<<<Nn / 256, 256, 0, stream>>>(r1, root1, rp1, col1, p1brel, s1, Nn);

    // SAGPool1
    topk_kernel<<<Bg, 1024, 0, stream>>>(s1, NPGc, K1c, perm1, tv1, map1);
    gather_bf16_kernel<<<(N1c * H1c) / 256, 256, 0, stream>>>(h1, perm1, tv1, h1pb, N1c * H1c);

    // ===== Layer 2: CSR direct through map (no edge compaction) =====
    count2_kernel<<<Ee / 256, 256, 0, stream>>>(src, tgt, map1, wc2);
    scan_part_kernel<<<N1c / 1024, 256, 0, stream>>>(wc2, bsum);
    scan_mid_kernel<<<1, 64, 0, stream>>>(bsum, N1c / 1024, rp2 + N1c);
    scan_fin_kernel<<<N1c / 1024, 256, 0, stream>>>(wc2, bsum, rp2, cur2);
    fill2_kernel<<<Ee / 256, 256, 0, stream>>>(src, tgt, map1, cur2, col2);

    // SAGEConv2
    agg2_kernel<<<(N1c * 64) / 256, 256, 0, stream>>>(h1pb, rp2, col2, aggb2, N1c);
    {
        dim3 g(N1c / 64, H2c / 64);
        gemm_mfma_kernel<H1c, H2c><<<g, 256, 0, stream>>>(aggb2, h1pb, T2l, T2r, b2l, h2);
    }

    // BN2 + ReLU + score
    bnstats_kernel<<<256, 256, 0, stream>>>(h2, N1c, H2c, dsum2, dsq2);
    bnfin_kernel<<<1, H2c, 0, stream>>>(dsum2, dsq2, bn2g, bn2b, scale, shift, N1c, H2c);
    bn_relu_score_kernel<<<(N1c * 64) / 256, 256, 0, stream>>>(h2, scale, shift, p2Wrel,
                                                               p2Wroot, r2, root2, N1c, H2c);
    segscore_kernel<<<N1c / 256, 256, 0, stream>>>(r2, root2, rp2, col2, p2brel, s2, N1c);

    // SAGPool2
    topk_kernel<<<Bg, 1024, 0, stream>>>(s2, K1c, K2c, perm2, tv2, nullptr);
    gather_f32_kernel<<<(N2c * H2c) / 256, 256, 0, stream>>>(h2, perm2, tv2, h2p, N2c * H2c);

    // Final readout
    {
        dim3 g(Bg, K2c / 64);
        pool_part_kernel<<<g, 256, 0, stream>>>(h2p, pooled);
    }
    pool_fin_kernel<<<Bg, 256, 0, stream>>>(pooled, Wlin, blin, out);
}

// Round 4
// 434.776 us; speedup vs baseline: 2.1164x; 1.0986x over previous
//
#include <hip/hip_runtime.h>
#include <math.h>

#define Bg   32
#define NPGc 2048
#define Nn   (Bg*NPGc)      // 65536
#define DEGc 8
#define Ee   (Nn*DEGc)      // 524288
#define INc  64
#define H1c  128
#define H2c  256
#define K1c  1024
#define K2c  512
#define N1c  (Bg*K1c)       // 32768
#define N2c  (Bg*K2c)       // 16384

typedef __attribute__((ext_vector_type(8))) short short8;
typedef __attribute__((ext_vector_type(4))) float f32x4;

__device__ __forceinline__ ushort f2bf(float f) {
    uint u = __float_as_uint(f);
    uint r = (u + 0x7fffu + ((u >> 16) & 1u)) >> 16;
    return (ushort)r;
}
__device__ __forceinline__ float bfhi(uint v) { return __uint_as_float(v & 0xffff0000u); }
__device__ __forceinline__ float bflo(uint v) { return __uint_as_float(v << 16); }

// ---------------- prep: wt transpose + x->bf16 + count1 + all inits (1 kernel) ----------------
__global__ void prep_kernel(const float* __restrict__ x, const int* __restrict__ tgt,
                            const float* __restrict__ W1l, const float* __restrict__ W1r,
                            const float* __restrict__ W2l, const float* __restrict__ W2r,
                            ushort* __restrict__ T1l, ushort* __restrict__ T1r,
                            ushort* __restrict__ T2l, ushort* __restrict__ T2r,
                            ushort* __restrict__ xb, int* __restrict__ map1,
                            int* __restrict__ wc1, int* __restrict__ wc2,
                            int* __restrict__ dstats, int* __restrict__ pooled) {
    int id = blockIdx.x * blockDim.x + threadIdx.x;
    if (id < 8192) {
        int c = id / 64, k = id % 64;
        T1l[id] = f2bf(W1l[k * 128 + c]);
        T1r[id] = f2bf(W1r[k * 128 + c]);
        return;
    }
    id -= 8192;
    if (id < 32768) {
        int c = id / 128, k = id % 128;
        T2l[id] = f2bf(W2l[k * 256 + c]);
        T2r[id] = f2bf(W2r[k * 256 + c]);
        return;
    }
    id -= 32768;
    if (id < 16384) { ((int4*)map1)[id] = (int4){-1, -1, -1, -1}; return; }
    id -= 16384;
    if (id < 16384) { ((int4*)wc1)[id] = (int4){0, 0, 0, 0}; return; }
    id -= 16384;
    if (id < 8192)  { ((int4*)wc2)[id] = (int4){0, 0, 0, 0}; return; }
    id -= 8192;
    if (id < 384)   { ((int4*)dstats)[id] = (int4){0, 0, 0, 0}; return; }
    id -= 384;
    if (id < 2048)  { ((int4*)pooled)[id] = (int4){0, 0, 0, 0}; return; }
    id -= 2048;
    if (id < Nn * 64 / 4) {  // x -> bf16
        float4 v = ((const float4*)x)[id];
        ushort4 o; o.x = f2bf(v.x); o.y = f2bf(v.y); o.z = f2bf(v.z); o.w = f2bf(v.w);
        ((ushort4*)xb)[id] = o;
        return;
    }
    id -= Nn * 64 / 4;
    if (id < Ee) atomicAdd(&wc1[tgt[id]], 1);
}
#define PREP_TOTAL (8192 + 32768 + 16384 + 16384 + 8192 + 384 + 2048 + Nn*64/4 + Ee)

// ---------------- scan (2 kernels; mid-scan folded into fin) ----------------
__global__ void __launch_bounds__(256) scan_part_kernel(const int* __restrict__ in,
                                                        int* __restrict__ bsum) {
    __shared__ int red[256];
    int base = blockIdx.x * 1024;
    int4 v = ((const int4*)&in[base])[threadIdx.x];
    int s = v.x + v.y + v.z + v.w;
    red[threadIdx.x] = s;
    __syncthreads();
    for (int off = 128; off; off >>= 1) {
        if ((int)threadIdx.x < off) red[threadIdx.x] += red[threadIdx.x + off];
        __syncthreads();
    }
    if (threadIdx.x == 0) bsum[blockIdx.x] = red[0];
}

__global__ void __launch_bounds__(256) scan_fin_kernel(const int* __restrict__ in,
                                                       const int* __restrict__ bsum, int nb,
                                                       int* __restrict__ rp,
                                                       int* __restrict__ cur, int n) {
    __shared__ int red[256];
    __shared__ int sbase;
    if (threadIdx.x < 64) {   // wave 0: redundant 64-wide scan of block partials
        int t = threadIdx.x;
        int bv = (t < nb) ? bsum[t] : 0;
        int v = bv;
        for (int off = 1; off < 64; off <<= 1) {
            int u = __shfl_up(v, off);
            if (t >= off) v += u;
        }
        if (t == (int)blockIdx.x) sbase = v - bv;  // exclusive prefix for this block
    }
    int base = blockIdx.x * 1024;
    int4 v = ((const int4*)&in[base])[threadIdx.x];
    int s = v.x + v.y + v.z + v.w;
    red[threadIdx.x] = s;
    __syncthreads();
    int val = s;
    for (int off = 1; off < 256; off <<= 1) {
        int t = ((int)threadIdx.x >= off) ? red[threadIdx.x - off] : 0;
        __syncthreads();
        val += t;
        red[threadIdx.x] = val;
        __syncthreads();
    }
    int o = val - s + sbase;
    int i0 = base + threadIdx.x * 4;
    int4 w;
    w.x = o; o += v.x;
    w.y = o; o += v.y;
    w.z = o; o += v.z;
    w.w = o;
    *(int4*)&rp[i0] = w;
    *(int4*)&cur[i0] = w;
    if ((int)blockIdx.x == nb - 1 && threadIdx.x == 255) rp[n] = sbase + val;
}

__global__ void fill_kernel(const int* __restrict__ src, const int* __restrict__ tgt, int ne,
                            int* __restrict__ cur, int* __restrict__ col) {
    int e = blockIdx.x * blockDim.x + threadIdx.x;
    if (e >= ne) return;
    int p = atomicAdd(&cur[tgt[e]], 1);
    col[p] = src[e];
}

__global__ void fill2_kernel(const int* __restrict__ src, const int* __restrict__ tgt,
                             const int* __restrict__ map, int* __restrict__ cur,
                             int* __restrict__ col) {
    int e = blockIdx.x * blockDim.x + threadIdx.x;
    if (e >= Ee) return;
    int ns = map[src[e]];
    int nt = map[tgt[e]];
    if (ns >= 0 && nt >= 0) {
        int p = atomicAdd(&cur[nt], 1);
        col[p] = ns;
    }
}

// ---------------- mean aggregation, bf16 in/out, XCD-swizzled ----------------
// layer1: C=64, 32 lanes/node (2 bf16 ch per lane). 8192 blocks; graph = 256 logical blocks.
__global__ void agg1_kernel(const ushort* __restrict__ xb, const int* __restrict__ rowptr,
                            const int* __restrict__ col, ushort* __restrict__ out) {
    int b = blockIdx.x;
    int w = ((b & 7) << 10) + (b >> 3);   // XCD x owns graphs [4x,4x+4): 2MB slice < 4MB L2
    int gid = w * 256 + threadIdx.x;
    int node = gid >> 5, lane = gid & 31;
    int bg = rowptr[node], e = rowptr[node + 1];
    float a0 = 0.f, a1 = 0.f;
    for (int i = bg; i < e; i++) {
        uint v = *(const uint*)&xb[((size_t)col[i] << 6) + 2 * lane];
        a0 += bflo(v);
        a1 += bfhi(v);
    }
    int cnt = e - bg; if (cnt < 1) cnt = 1;
    float inv = 1.f / (float)cnt;
    ushort2 st; st.x = f2bf(a0 * inv); st.y = f2bf(a1 * inv);
    *(ushort2*)&out[((size_t)node << 6) + 2 * lane] = st;
}

// layer2: C=128, 64 lanes/node. 8192 blocks; graph = 256 logical blocks.
__global__ void agg2_kernel(const ushort* __restrict__ xb, const int* __restrict__ rowptr,
                            const int* __restrict__ col, ushort* __restrict__ out) {
    int b = blockIdx.x;
    int w = ((b & 7) << 10) + (b >> 3);
    int gid = w * 256 + threadIdx.x;
    int node = gid >> 6, lane = gid & 63;
    int bg = rowptr[node], e = rowptr[node + 1];
    float a0 = 0.f, a1 = 0.f;
    for (int i = bg; i < e; i++) {
        uint v = *(const uint*)&xb[((size_t)col[i] << 7) + 2 * lane];
        a0 += bflo(v);
        a1 += bfhi(v);
    }
    int cnt = e - bg; if (cnt < 1) cnt = 1;
    float inv = 1.f / (float)cnt;
    ushort2 st; st.x = f2bf(a0 * inv); st.y = f2bf(a1 * inv);
    *(ushort2*)&out[((size_t)node << 7) + 2 * lane] = st;
}

// ---------------- MFMA GEMM: out[M,COUT] = Aagg@Wl + Ax@Wr + bias ----------------
template<int K, int COUT>
__global__ __launch_bounds__(256) void gemm_mfma_kernel(
        const ushort* __restrict__ Aagg, const ushort* __restrict__ Ax,
        const ushort* __restrict__ Wtl, const ushort* __restrict__ Wtr,
        const float* __restrict__ bias, float* __restrict__ out) {
    __shared__ ushort As[2][64][72];
    __shared__ ushort Bs[2][64][72];
    int m0 = blockIdx.x * 64;
    int c0 = blockIdx.y * 64;
    int lane = threadIdx.x & 63;
    int wid = threadIdx.x >> 6;
    int wr = (wid & 1) * 32, wc = (wid >> 1) * 32;
    int l16 = lane & 15, quad = lane >> 4;

    f32x4 acc[2][2];
#pragma unroll
    for (int a = 0; a < 2; a++)
#pragma unroll
        for (int b = 0; b < 2; b++) acc[a][b] = (f32x4){0.f, 0.f, 0.f, 0.f};

    for (int kk0 = 0; kk0 < K; kk0 += 64) {
        for (int idx = threadIdx.x; idx < 512; idx += 256) {
            int r = idx >> 3, ck = (idx & 7) * 8;
            *(uint4*)&As[0][r][ck] = *(const uint4*)&Aagg[(size_t)(m0 + r) * K + kk0 + ck];
            *(uint4*)&As[1][r][ck] = *(const uint4*)&Ax[(size_t)(m0 + r) * K + kk0 + ck];
            *(uint4*)&Bs[0][r][ck] = *(const uint4*)&Wtl[(size_t)(c0 + r) * K + kk0 + ck];
            *(uint4*)&Bs[1][r][ck] = *(const uint4*)&Wtr[(size_t)(c0 + r) * K + kk0 + ck];
        }
        __syncthreads();
#pragma unroll
        for (int kk = 0; kk < 64; kk += 32) {
            short8 a[2][2], b[2][2];
#pragma unroll
            for (int s = 0; s < 2; s++)
#pragma unroll
                for (int mt = 0; mt < 2; mt++)
                    a[s][mt] = *(const short8*)&As[s][wr + mt * 16 + l16][kk + quad * 8];
#pragma unroll
            for (int s = 0; s < 2; s++)
#pragma unroll
                for (int nt = 0; nt < 2; nt++)
                    b[s][nt] = *(const short8*)&Bs[s][wc + nt * 16 + l16][kk + quad * 8];
#pragma unroll
            for (int mt = 0; mt < 2; mt++)
#pragma unroll
                for (int nt = 0; nt < 2; nt++) {
                    acc[mt][nt] = __builtin_amdgcn_mfma_f32_16x16x32_bf16(
                        a[0][mt], b[0][nt], acc[mt][nt], 0, 0, 0);
                    acc[mt][nt] = __builtin_amdgcn_mfma_f32_16x16x32_bf16(
                        a[1][mt], b[1][nt], acc[mt][nt], 0, 0, 0);
                }
        }
        __syncthreads();
    }
#pragma unroll
    for (int mt = 0; mt < 2; mt++)
#pragma unroll
        for (int nt = 0; nt < 2; nt++) {
            int col = c0 + wc + nt * 16 + l16;
            float bv = bias[col];
#pragma unroll
            for (int r = 0; r < 4; r++) {
                int row = m0 + wr + mt * 16 + quad * 4 + r;
                out[(size_t)row * COUT + col] = acc[mt][nt][r] + bv;
            }
        }
}

// ---------------- BatchNorm stats on RAW h (f64 atomics) ----------------
__global__ void __launch_bounds__(256) bnstats_kernel(const float* __restrict__ h, int n, int C,
                                                      double* __restrict__ dsum,
                                                      double* __restrict__ dsq) {
    __shared__ float s1[256], s2[256];
    int c = threadIdx.x & (C - 1);
    int rpg = 256 / C;
    int sub = threadIdx.x / C;
    float s = 0.f, sq = 0.f;
    for (int row = blockIdx.x * rpg + sub; row < n; row += gridDim.x * rpg) {
        float v = h[(size_t)row * C + c];
        s += v; sq += v * v;
    }
    s1[threadIdx.x] = s; s2[threadIdx.x] = sq;
    __syncthreads();
    if (C == 128 && threadIdx.x < 128) {
        s1[threadIdx.x] += s1[threadIdx.x + 128];
        s2[threadIdx.x] += s2[threadIdx.x + 128];
    }
    __syncthreads();
    if ((int)threadIdx.x < C) {
        atomicAdd(&dsum[threadIdx.x], (double)s1[threadIdx.x]);
        atomicAdd(&dsq[threadIdx.x], (double)s2[threadIdx.x]);
    }
}

// ---------------- score dots from RAW h; scale/shift computed in-block ----------------
template<int C>
__global__ __launch_bounds__(256) void score_kernel(const float* __restrict__ h,
                                                    const double* __restrict__ dsum,
                                                    const double* __restrict__ dsq,
                                                    const float* __restrict__ g,
                                                    const float* __restrict__ b,
                                                    const float* __restrict__ wrel,
                                                    const float* __restrict__ wroot,
                                                    float* __restrict__ r,
                                                    float* __restrict__ root, int n) {
    __shared__ float sc[C], sh[C], wrl[C], wrt[C];
    if ((int)threadIdx.x < C) {
        int c = threadIdx.x;
        double m = dsum[c] / (double)n;
        double var = dsq[c] / (double)n - m * m;
        float s = g[c] * (float)(1.0 / sqrt(var + 1e-5));
        sc[c] = s; sh[c] = b[c] - (float)m * s;
        wrl[c] = wrel[c]; wrt[c] = wroot[c];
    }
    __syncthreads();
    int gid = blockIdx.x * 256 + threadIdx.x;
    int node = gid >> 6, lane = gid & 63;
    float rr = 0.f, rt = 0.f;
    for (int c = lane; c < C; c += 64) {
        float v = fmaxf(h[(size_t)node * C + c] * sc[c] + sh[c], 0.f);
        rr += v * wrl[c];
        rt += v * wrt[c];
    }
    for (int off = 32; off; off >>= 1) {
        rr += __shfl_down(rr, off);
        rt += __shfl_down(rt, off);
    }
    if (lane == 0) { r[node] = rr; root[node] = rt; }
}

// ---------------- top-k with fused segment-score (bitonic, exact tie-break) ----------------
__device__ __forceinline__ bool before_cmp(float av, int ai, float bv, int bi) {
    return (av > bv) || (av == bv && ai < bi);
}

__global__ void __launch_bounds__(1024) topk_kernel(const float* __restrict__ r,
                                                    const float* __restrict__ root,
                                                    const int* __restrict__ rp,
                                                    const int* __restrict__ col,
                                                    const float* __restrict__ brel,
                                                    int npg, int k, int* __restrict__ perm,
                                                    float* __restrict__ tval,
                                                    int* __restrict__ map) {
    __shared__ float vals[2048];
    __shared__ int idxs[2048];
    int g = blockIdx.x;
    float bv = brel[0];
    for (int i = threadIdx.x; i < npg; i += 1024) {
        int gi = g * npg + i;
        float acc = bv + root[gi];
        int e1 = rp[gi + 1];
        for (int e = rp[gi]; e < e1; e++) acc += r[col[e]];
        vals[i] = acc; idxs[i] = i;
    }
    __syncthreads();
    for (int kk = 2; kk <= npg; kk <<= 1) {
        for (int j = kk >> 1; j > 0; j >>= 1) {
            for (int i = threadIdx.x; i < npg; i += 1024) {
                int ixj = i ^ j;
                if (ixj > i) {
                    bool up = ((i & kk) == 0);
                    float v1 = vals[i], v2 = vals[ixj];
                    int i1 = idxs[i], i2 = idxs[ixj];
                    bool sw = up ? before_cmp(v2, i2, v1, i1) : before_cmp(v1, i1, v2, i2);
                    if (sw) { vals[i] = v2; idxs[i] = i2; vals[ixj] = v1; idxs[ixj] = i1; }
                }
            }
            __syncthreads();
        }
    }
    for (int jj = threadIdx.x; jj < k; jj += 1024) {
        int old_global = g * npg + idxs[jj];
        int m = g * k + jj;
        perm[m] = old_global;
        tval[m] = tanhf(vals[jj]);
        if (map) map[old_global] = m;
    }
}

// ---------------- fused: BN-apply gather (layer1) + count2 ----------------
__global__ void __launch_bounds__(256) gcount_kernel(
        const float* __restrict__ h1, const int* __restrict__ perm1,
        const float* __restrict__ tv1, const double* __restrict__ dsum,
        const double* __restrict__ dsq, const float* __restrict__ g,
        const float* __restrict__ b, ushort* __restrict__ h1pb,
        const int* __restrict__ src, const int* __restrict__ tgt,
        const int* __restrict__ map, int* __restrict__ wc2) {
    int blockBase = blockIdx.x * 256;
    if (blockBase < N1c * H1c) {
        __shared__ float sc[128], sh[128];
        if (threadIdx.x < 128) {
            int c = threadIdx.x;
            double m = dsum[c] / (double)Nn;
            double var = dsq[c] / (double)Nn - m * m;
            float s = g[c] * (float)(1.0 / sqrt(var + 1e-5));
            sc[c] = s; sh[c] = b[c] - (float)m * s;
        }
        __syncthreads();
        int t = blockBase + threadIdx.x;
        int m = t >> 7, c = t & 127;
        float v = fmaxf(h1[((size_t)perm1[m] << 7) + c] * sc[c] + sh[c], 0.f);
        h1pb[t] = f2bf(v * tv1[m]);
    } else {
        int e = blockBase + threadIdx.x - N1c * H1c;
        if (e >= Ee) return;
        int ns = map[src[e]];
        int nt = map[tgt[e]];
        if (ns >= 0 && nt >= 0) atomicAdd(&wc2[nt], 1);
    }
}

// ---------------- fused: layer2 BN-apply + tanh-scale + pooled accumulate ----------------
__global__ void __launch_bounds__(256) pool_part_kernel(const float* __restrict__ h2,
                                                        const int* __restrict__ perm2,
                                                        const float* __restrict__ tv2,
                                                        const double* __restrict__ dsum,
                                                        const double* __restrict__ dsq,
                                                        const float* __restrict__ g,
                                                        const float* __restrict__ b,
                                                        float* __restrict__ pooled) {
    __shared__ float sc[256], sh[256];
    {
        int c = threadIdx.x;
        double m = dsum[c] / (double)N1c;
        double var = dsq[c] / (double)N1c - m * m;
        float s = g[c] * (float)(1.0 / sqrt(var + 1e-5));
        sc[c] = s; sh[c] = b[c] - (float)m * s;
    }
    __syncthreads();
    int gg = blockIdx.x, p = blockIdx.y, c = threadIdx.x;
    float s = 0.f;
    for (int j = 0; j < 64; j++) {
        int m = gg * K2c + p * 64 + j;
        int row = perm2[m];
        float v = fmaxf(h2[((size_t)row << 8) + c] * sc[c] + sh[c], 0.f);
        s += v * tv2[m];
    }
    atomicAdd(&pooled[gg * H2c + c], s);
}

__global__ void __launch_bounds__(256) pool_fin_kernel(const float* __restrict__ pooled,
                                                       const float* __restrict__ Wlin,
                                                       const float* __restrict__ blin,
                                                       float* __restrict__ out) {
    __shared__ float p0s[256], p1s[256];
    int g = blockIdx.x, c = threadIdx.x;
    float s = fmaxf(pooled[g * 256 + c] * (1.f / (float)K2c), 0.f);
    p0s[c] = s * Wlin[c * 2 + 0];
    p1s[c] = s * Wlin[c * 2 + 1];
    __syncthreads();
    for (int off = 128; off; off >>= 1) {
        if (c < off) { p0s[c] += p0s[c + off]; p1s[c] += p1s[c + off]; }
        __syncthreads();
    }
    if (c == 0) {
        float o0 = p0s[0] + blin[0], o1 = p1s[0] + blin[1];
        float m = fmaxf(o0, o1);
        float e0 = expf(o0 - m), e1 = expf(o1 - m);
        float inv = 1.f / (e0 + e1);
        out[g * 2 + 0] = e0 * inv;
        out[g * 2 + 1] = e1 * inv;
    }
}

extern "C" void kernel_launch(void* const* d_in, const int* in_sizes, int n_in,
                              void* d_out, int out_size, void* d_ws, size_t ws_size,
                              hipStream_t stream) {
    const float* x      = (const float*)d_in[0];
    const int*   ei     = (const int*)d_in[1];
    const int*   src    = ei;
    const int*   tgt    = ei + Ee;
    const float* W1l    = (const float*)d_in[3];
    const float* b1l    = (const float*)d_in[4];
    const float* W1r    = (const float*)d_in[5];
    const float* bn1g   = (const float*)d_in[6];
    const float* bn1b   = (const float*)d_in[7];
    const float* p1Wrel = (const float*)d_in[8];
    const float* p1brel = (const float*)d_in[9];
    const float* p1Wroot= (const float*)d_in[10];
    const float* W2l    = (const float*)d_in[11];
    const float* b2l    = (const float*)d_in[12];
    const float* W2r    = (const float*)d_in[13];
    const float* bn2g   = (const float*)d_in[14];
    const float* bn2b   = (const float*)d_in[15];
    const float* p2Wrel = (const float*)d_in[16];
    const float* p2brel = (const float*)d_in[17];
    const float* p2Wroot= (const float*)d_in[18];
    const float* Wlin   = (const float*)d_in[19];
    const float* blin   = (const float*)d_in[20];
    float* out = (float*)d_out;
    char* ws = (char*)d_ws;

    size_t o = 0;
    auto A = [&](size_t b) { size_t r = o; o += (b + 255) & ~(size_t)255; return r; };
    size_t oBIG1 = A((size_t)Nn * H1c * 4);        // h1 / h2 f32
    size_t oBIG2 = A((size_t)Nn * INc * 4);        // xb + aggb1 bf16
    size_t oPB   = A((size_t)N1c * H1c * 4);       // h1pb + aggb2 bf16
    size_t oCol1 = A((size_t)Ee * 4);
    size_t oCol2 = A((size_t)Ee * 4);
    size_t oRp1  = A((size_t)(Nn + 1) * 4);
    size_t oWc1  = A((size_t)Nn * 4);
    size_t oCur1 = A((size_t)Nn * 4);
    size_t oMap  = A((size_t)Nn * 4);
    size_t oR1   = A((size_t)Nn * 4);
    size_t oRoot1= A((size_t)Nn * 4);
    size_t oPerm1= A((size_t)N1c * 4);
    size_t oTv1  = A((size_t)N1c * 4);
    size_t oRp2  = A((size_t)(N1c + 1) * 4);
    size_t oWc2  = A((size_t)N1c * 4);
    size_t oCur2 = A((size_t)N1c * 4);
    size_t oR2   = A((size_t)N1c * 4);
    size_t oRoot2= A((size_t)N1c * 4);
    size_t oPerm2= A((size_t)N2c * 4);
    size_t oTv2  = A((size_t)N2c * 4);
    size_t oDst  = A(768 * 8);
    size_t oBsum = A(64 * 4);
    size_t oWt1l = A(8192 * 2);
    size_t oWt1r = A(8192 * 2);
    size_t oWt2l = A(32768 * 2);
    size_t oWt2r = A(32768 * 2);
    size_t oPool = A(Bg * H2c * 4);
    (void)ws_size; (void)in_sizes; (void)n_in; (void)out_size;

    float* h1    = (float*)(ws + oBIG1);
    float* h2    = (float*)(ws + oBIG1);
    ushort* xb   = (ushort*)(ws + oBIG2);
    ushort* aggb1= (ushort*)(ws + oBIG2 + (size_t)Nn * 64 * 2);
    ushort* h1pb = (ushort*)(ws + oPB);
    ushort* aggb2= (ushort*)(ws + oPB + (size_t)N1c * 128 * 2);
    int* col1    = (int*)(ws + oCol1);
    int* col2    = (int*)(ws + oCol2);
    int* rp1     = (int*)(ws + oRp1);
    int* wc1     = (int*)(ws + oWc1);
    int* cur1    = (int*)(ws + oCur1);
    int* map1    = (int*)(ws + oMap);
    float* r1    = (float*)(ws + oR1);
    float* root1 = (float*)(ws + oRoot1);
    int* perm1   = (int*)(ws + oPerm1);
    float* tv1   = (float*)(ws + oTv1);
    int* rp2     = (int*)(ws + oRp2);
    int* wc2     = (int*)(ws + oWc2);
    int* cur2    = (int*)(ws + oCur2);
    float* r2    = (float*)(ws + oR2);
    float* root2 = (float*)(ws + oRoot2);
    int* perm2   = (int*)(ws + oPerm2);
    float* tv2   = (float*)(ws + oTv2);
    double* dsum1= (double*)(ws + oDst);
    double* dsq1 = dsum1 + 128;
    double* dsum2= dsum1 + 256;
    double* dsq2 = dsum1 + 512;
    int* bsum    = (int*)(ws + oBsum);
    ushort* T1l  = (ushort*)(ws + oWt1l);
    ushort* T1r  = (ushort*)(ws + oWt1r);
    ushort* T2l  = (ushort*)(ws + oWt2l);
    ushort* T2r  = (ushort*)(ws + oWt2r);
    float* pooled= (float*)(ws + oPool);

    // 1. prep (wt transpose + inits + xconv + count1)
    prep_kernel<<<(PREP_TOTAL + 255) / 256, 256, 0, stream>>>(
        x, tgt, W1l, W1r, W2l, W2r, T1l, T1r, T2l, T2r, xb, map1, wc1, wc2,
        (int*)dsum1, (int*)pooled);

    // ===== Layer 1 CSR =====
    scan_part_kernel<<<Nn / 1024, 256, 0, stream>>>(wc1, bsum);
    scan_fin_kernel<<<Nn / 1024, 256, 0, stream>>>(wc1, bsum, Nn / 1024, rp1, cur1, Nn);
    fill_kernel<<<Ee / 256, 256, 0, stream>>>(src, tgt, Ee, cur1, col1);

    // SAGEConv1
    agg1_kernel<<<8192, 256, 0, stream>>>(xb, rp1, col1, aggb1);
    {
        dim3 g(Nn / 64, H1c / 64);
        gemm_mfma_kernel<INc, H1c><<<g, 256, 0, stream>>>(aggb1, xb, T1l, T1r, b1l, h1);
    }

    // BN1 stats + score + topk(+segscore)
    bnstats_kernel<<<256, 256, 0, stream>>>(h1, Nn, H1c, dsum1, dsq1);
    score_kernel<H1c><<<Nn / 4, 256, 0, stream>>>(h1, dsum1, dsq1, bn1g, bn1b, p1Wrel,
                                                  p1Wroot, r1, root1, Nn);
    topk_kernel<<<Bg, 1024, 0, stream>>>(r1, root1, rp1, col1, p1brel, NPGc, K1c,
                                         perm1, tv1, map1);

    // BN-apply gather (h1 -> h1pb) + count2
    gcount_kernel<<<(N1c * H1c + Ee) / 256, 256, 0, stream>>>(
        h1, perm1, tv1, dsum1, dsq1, bn1g, bn1b, h1pb, src, tgt, map1, wc2);

    // ===== Layer 2 CSR =====
    scan_part_kernel<<<N1c / 1024, 256, 0, stream>>>(wc2, bsum);
    scan_fin_kernel<<<N1c / 1024, 256, 0, stream>>>(wc2, bsum, N1c / 1024, rp2, cur2, N1c);
    fill2_kernel<<<Ee / 256, 256, 0, stream>>>(src, tgt, map1, cur2, col2);

    // SAGEConv2
    agg2_kernel<<<8192, 256, 0, stream>>>(h1pb, rp2, col2, aggb2);
    {
        dim3 g(N1c / 64, H2c / 64);
        gemm_mfma_kernel<H1c, H2c><<<g, 256, 0, stream>>>(aggb2, h1pb, T2l, T2r, b2l, h2);
    }

    // BN2 stats + score + topk(+segscore)
    bnstats_kernel<<<256, 256, 0, stream>>>(h2, N1c, H2c, dsum2, dsq2);
    score_kernel<H2c><<<N1c / 4, 256, 0, stream>>>(h2, dsum2, dsq2, bn2g, bn2b, p2Wrel,
                                                   p2Wroot, r2, root2, N1c);
    topk_kernel<<<Bg, 1024, 0, stream>>>(r2, root2, rp2, col2, p2brel, K1c, K2c,
                                         perm2, tv2, nullptr);

    // Fused BN-apply + tanh-scale + pool, then readout
    {
        dim3 g(Bg, K2c / 64);
        pool_part_kernel<<<g, 256, 0, stream>>>(h2, perm2, tv2, dsum2, dsq2, bn2g, bn2b,
                                                pooled);
    }
    pool_fin_kernel<<<Bg, 256, 0, stream>>>(pooled, Wlin, blin, out);
}

// Round 5
// 414.273 us; speedup vs baseline: 2.2211x; 1.0495x over previous
//
#include <hip/hip_runtime.h>
#include <math.h>

#define Bg   32
#define NPGc 2048
#define Nn   (Bg*NPGc)      // 65536
#define DEGc 8
#define Ee   (Nn*DEGc)      // 524288
#define INc  64
#define H1c  128
#define H2c  256
#define K1c  1024
#define K2c  512
#define N1c  (Bg*K1c)       // 32768
#define N2c  (Bg*K2c)       // 16384

typedef __attribute__((ext_vector_type(8))) short short8;
typedef __attribute__((ext_vector_type(4))) float f32x4;

__device__ __forceinline__ ushort f2bf(float f) {
    uint u = __float_as_uint(f);
    uint r = (u + 0x7fffu + ((u >> 16) & 1u)) >> 16;
    return (ushort)r;
}
__device__ __forceinline__ float bfhi(uint v) { return __uint_as_float(v & 0xffff0000u); }
__device__ __forceinline__ float bflo(uint v) { return __uint_as_float(v << 16); }
__device__ __forceinline__ uint fkey(float f) {
    uint u = __float_as_uint(f);
    return u ^ ((uint)((int)u >> 31) | 0x80000000u);
}

// ---------------- prep: wt transpose + x->bf16 + count1 + all inits (1 kernel) ----------------
__global__ void prep_kernel(const float* __restrict__ x, const int* __restrict__ tgt,
                            const float* __restrict__ W1l, const float* __restrict__ W1r,
                            const float* __restrict__ W2l, const float* __restrict__ W2r,
                            ushort* __restrict__ T1l, ushort* __restrict__ T1r,
                            ushort* __restrict__ T2l, ushort* __restrict__ T2r,
                            ushort* __restrict__ xb, int* __restrict__ map1,
                            int* __restrict__ wc1, int* __restrict__ wc2,
                            int* __restrict__ dstats, int* __restrict__ pooled) {
    int id = blockIdx.x * blockDim.x + threadIdx.x;
    if (id < 8192) {
        int c = id / 64, k = id % 64;
        T1l[id] = f2bf(W1l[k * 128 + c]);
        T1r[id] = f2bf(W1r[k * 128 + c]);
        return;
    }
    id -= 8192;
    if (id < 32768) {
        int c = id / 128, k = id % 128;
        T2l[id] = f2bf(W2l[k * 256 + c]);
        T2r[id] = f2bf(W2r[k * 256 + c]);
        return;
    }
    id -= 32768;
    if (id < 16384) { ((int4*)map1)[id] = (int4){-1, -1, -1, -1}; return; }
    id -= 16384;
    if (id < 16384) { ((int4*)wc1)[id] = (int4){0, 0, 0, 0}; return; }
    id -= 16384;
    if (id < 8192)  { ((int4*)wc2)[id] = (int4){0, 0, 0, 0}; return; }
    id -= 8192;
    if (id < 384)   { ((int4*)dstats)[id] = (int4){0, 0, 0, 0}; return; }
    id -= 384;
    if (id < 2048)  { ((int4*)pooled)[id] = (int4){0, 0, 0, 0}; return; }
    id -= 2048;
    if (id < Nn * 64 / 4) {  // x -> bf16
        float4 v = ((const float4*)x)[id];
        ushort4 o; o.x = f2bf(v.x); o.y = f2bf(v.y); o.z = f2bf(v.z); o.w = f2bf(v.w);
        ((ushort4*)xb)[id] = o;
        return;
    }
    id -= Nn * 64 / 4;
    if (id < Ee) atomicAdd(&wc1[tgt[id]], 1);
}
#define PREP_TOTAL (8192 + 32768 + 16384 + 16384 + 8192 + 384 + 2048 + Nn*64/4 + Ee)

// ---------------- scan (2 kernels; mid-scan folded into fin) ----------------
__global__ void __launch_bounds__(256) scan_part_kernel(const int* __restrict__ in,
                                                        int* __restrict__ bsum) {
    __shared__ int red[256];
    int base = blockIdx.x * 1024;
    int4 v = ((const int4*)&in[base])[threadIdx.x];
    int s = v.x + v.y + v.z + v.w;
    red[threadIdx.x] = s;
    __syncthreads();
    for (int off = 128; off; off >>= 1) {
        if ((int)threadIdx.x < off) red[threadIdx.x] += red[threadIdx.x + off];
        __syncthreads();
    }
    if (threadIdx.x == 0) bsum[blockIdx.x] = red[0];
}

__global__ void __launch_bounds__(256) scan_fin_kernel(const int* __restrict__ in,
                                                       const int* __restrict__ bsum, int nb,
                                                       int* __restrict__ rp,
                                                       int* __restrict__ cur, int n) {
    __shared__ int red[256];
    __shared__ int sbase;
    if (threadIdx.x < 64) {   // wave 0: redundant 64-wide scan of block partials
        int t = threadIdx.x;
        int bv = (t < nb) ? bsum[t] : 0;
        int v = bv;
        for (int off = 1; off < 64; off <<= 1) {
            int u = __shfl_up(v, off);
            if (t >= off) v += u;
        }
        if (t == (int)blockIdx.x) sbase = v - bv;  // exclusive prefix for this block
    }
    int base = blockIdx.x * 1024;
    int4 v = ((const int4*)&in[base])[threadIdx.x];
    int s = v.x + v.y + v.z + v.w;
    red[threadIdx.x] = s;
    __syncthreads();
    int val = s;
    for (int off = 1; off < 256; off <<= 1) {
        int t = ((int)threadIdx.x >= off) ? red[threadIdx.x - off] : 0;
        __syncthreads();
        val += t;
        red[threadIdx.x] = val;
        __syncthreads();
    }
    int o = val - s + sbase;
    int i0 = base + threadIdx.x * 4;
    int4 w;
    w.x = o; o += v.x;
    w.y = o; o += v.y;
    w.z = o; o += v.z;
    w.w = o;
    *(int4*)&rp[i0] = w;
    *(int4*)&cur[i0] = w;
    if ((int)blockIdx.x == nb - 1 && threadIdx.x == 255) rp[n] = sbase + val;
}

__global__ void fill_kernel(const int* __restrict__ src, const int* __restrict__ tgt, int ne,
                            int* __restrict__ cur, int* __restrict__ col) {
    int e = blockIdx.x * blockDim.x + threadIdx.x;
    if (e >= ne) return;
    int p = atomicAdd(&cur[tgt[e]], 1);
    col[p] = src[e];
}

__global__ void fill2_kernel(const int* __restrict__ src, const int* __restrict__ tgt,
                             const int* __restrict__ map, int* __restrict__ cur,
                             int* __restrict__ col) {
    int e = blockIdx.x * blockDim.x + threadIdx.x;
    if (e >= Ee) return;
    int ns = map[src[e]];
    int nt = map[tgt[e]];
    if (ns >= 0 && nt >= 0) {
        int p = atomicAdd(&cur[nt], 1);
        col[p] = ns;
    }
}

// ---------------- mean aggregation, bf16 in/out, XCD-swizzled ----------------
__global__ void agg1_kernel(const ushort* __restrict__ xb, const int* __restrict__ rowptr,
                            const int* __restrict__ col, ushort* __restrict__ out) {
    int b = blockIdx.x;
    int w = ((b & 7) << 10) + (b >> 3);   // XCD x owns graphs [4x,4x+4): 2MB slice < 4MB L2
    int gid = w * 256 + threadIdx.x;
    int node = gid >> 5, lane = gid & 31;
    int bg = rowptr[node], e = rowptr[node + 1];
    float a0 = 0.f, a1 = 0.f;
    for (int i = bg; i < e; i++) {
        uint v = *(const uint*)&xb[((size_t)col[i] << 6) + 2 * lane];
        a0 += bflo(v);
        a1 += bfhi(v);
    }
    int cnt = e - bg; if (cnt < 1) cnt = 1;
    float inv = 1.f / (float)cnt;
    ushort2 st; st.x = f2bf(a0 * inv); st.y = f2bf(a1 * inv);
    *(ushort2*)&out[((size_t)node << 6) + 2 * lane] = st;
}

__global__ void agg2_kernel(const ushort* __restrict__ xb, const int* __restrict__ rowptr,
                            const int* __restrict__ col, ushort* __restrict__ out) {
    int b = blockIdx.x;
    int w = ((b & 7) << 10) + (b >> 3);
    int gid = w * 256 + threadIdx.x;
    int node = gid >> 6, lane = gid & 63;
    int bg = rowptr[node], e = rowptr[node + 1];
    float a0 = 0.f, a1 = 0.f;
    for (int i = bg; i < e; i++) {
        uint v = *(const uint*)&xb[((size_t)col[i] << 7) + 2 * lane];
        a0 += bflo(v);
        a1 += bfhi(v);
    }
    int cnt = e - bg; if (cnt < 1) cnt = 1;
    float inv = 1.f / (float)cnt;
    ushort2 st; st.x = f2bf(a0 * inv); st.y = f2bf(a1 * inv);
    *(ushort2*)&out[((size_t)node << 7) + 2 * lane] = st;
}

// ---------------- MFMA GEMM: out[M,COUT] = Aagg@Wl + Ax@Wr + bias ----------------
template<int K, int COUT>
__global__ __launch_bounds__(256) void gemm_mfma_kernel(
        const ushort* __restrict__ Aagg, const ushort* __restrict__ Ax,
        const ushort* __restrict__ Wtl, const ushort* __restrict__ Wtr,
        const float* __restrict__ bias, float* __restrict__ out) {
    __shared__ ushort As[2][64][72];
    __shared__ ushort Bs[2][64][72];
    int m0 = blockIdx.x * 64;
    int c0 = blockIdx.y * 64;
    int lane = threadIdx.x & 63;
    int wid = threadIdx.x >> 6;
    int wr = (wid & 1) * 32, wc = (wid >> 1) * 32;
    int l16 = lane & 15, quad = lane >> 4;

    f32x4 acc[2][2];
#pragma unroll
    for (int a = 0; a < 2; a++)
#pragma unroll
        for (int b = 0; b < 2; b++) acc[a][b] = (f32x4){0.f, 0.f, 0.f, 0.f};

    for (int kk0 = 0; kk0 < K; kk0 += 64) {
        for (int idx = threadIdx.x; idx < 512; idx += 256) {
            int r = idx >> 3, ck = (idx & 7) * 8;
            *(uint4*)&As[0][r][ck] = *(const uint4*)&Aagg[(size_t)(m0 + r) * K + kk0 + ck];
            *(uint4*)&As[1][r][ck] = *(const uint4*)&Ax[(size_t)(m0 + r) * K + kk0 + ck];
            *(uint4*)&Bs[0][r][ck] = *(const uint4*)&Wtl[(size_t)(c0 + r) * K + kk0 + ck];
            *(uint4*)&Bs[1][r][ck] = *(const uint4*)&Wtr[(size_t)(c0 + r) * K + kk0 + ck];
        }
        __syncthreads();
#pragma unroll
        for (int kk = 0; kk < 64; kk += 32) {
            short8 a[2][2], b[2][2];
#pragma unroll
            for (int s = 0; s < 2; s++)
#pragma unroll
                for (int mt = 0; mt < 2; mt++)
                    a[s][mt] = *(const short8*)&As[s][wr + mt * 16 + l16][kk + quad * 8];
#pragma unroll
            for (int s = 0; s < 2; s++)
#pragma unroll
                for (int nt = 0; nt < 2; nt++)
                    b[s][nt] = *(const short8*)&Bs[s][wc + nt * 16 + l16][kk + quad * 8];
#pragma unroll
            for (int mt = 0; mt < 2; mt++)
#pragma unroll
                for (int nt = 0; nt < 2; nt++) {
                    acc[mt][nt] = __builtin_amdgcn_mfma_f32_16x16x32_bf16(
                        a[0][mt], b[0][nt], acc[mt][nt], 0, 0, 0);
                    acc[mt][nt] = __builtin_amdgcn_mfma_f32_16x16x32_bf16(
                        a[1][mt], b[1][nt], acc[mt][nt], 0, 0, 0);
                }
        }
        __syncthreads();
    }
#pragma unroll
    for (int mt = 0; mt < 2; mt++)
#pragma unroll
        for (int nt = 0; nt < 2; nt++) {
            int col = c0 + wc + nt * 16 + l16;
            float bv = bias[col];
#pragma unroll
            for (int r = 0; r < 4; r++) {
                int row = m0 + wr + mt * 16 + quad * 4 + r;
                out[(size_t)row * COUT + col] = acc[mt][nt][r] + bv;
            }
        }
}

// ---------------- BatchNorm stats on RAW h (f64 atomics) ----------------
__global__ void __launch_bounds__(256) bnstats_kernel(const float* __restrict__ h, int n, int C,
                                                      double* __restrict__ dsum,
                                                      double* __restrict__ dsq) {
    __shared__ float s1[256], s2[256];
    int c = threadIdx.x & (C - 1);
    int rpg = 256 / C;
    int sub = threadIdx.x / C;
    float s = 0.f, sq = 0.f;
    for (int row = blockIdx.x * rpg + sub; row < n; row += gridDim.x * rpg) {
        float v = h[(size_t)row * C + c];
        s += v; sq += v * v;
    }
    s1[threadIdx.x] = s; s2[threadIdx.x] = sq;
    __syncthreads();
    if (C == 128 && threadIdx.x < 128) {
        s1[threadIdx.x] += s1[threadIdx.x + 128];
        s2[threadIdx.x] += s2[threadIdx.x + 128];
    }
    __syncthreads();
    if ((int)threadIdx.x < C) {
        atomicAdd(&dsum[threadIdx.x], (double)s1[threadIdx.x]);
        atomicAdd(&dsq[threadIdx.x], (double)s2[threadIdx.x]);
    }
}

// ---------------- score dots from RAW h; scale/shift computed in-block ----------------
template<int C>
__global__ __launch_bounds__(256) void score_kernel(const float* __restrict__ h,
                                                    const double* __restrict__ dsum,
                                                    const double* __restrict__ dsq,
                                                    const float* __restrict__ g,
                                                    const float* __restrict__ b,
                                                    const float* __restrict__ wrel,
                                                    const float* __restrict__ wroot,
                                                    float* __restrict__ r,
                                                    float* __restrict__ root, int n) {
    __shared__ float sc[C], sh[C], wrl[C], wrt[C];
    if ((int)threadIdx.x < C) {
        int c = threadIdx.x;
        double m = dsum[c] / (double)n;
        double var = dsq[c] / (double)n - m * m;
        float s = g[c] * (float)(1.0 / sqrt(var + 1e-5));
        sc[c] = s; sh[c] = b[c] - (float)m * s;
        wrl[c] = wrel[c]; wrt[c] = wroot[c];
    }
    __syncthreads();
    int gid = blockIdx.x * 256 + threadIdx.x;
    int node = gid >> 6, lane = gid & 63;
    float rr = 0.f, rt = 0.f;
    for (int c = lane; c < C; c += 64) {
        float v = fmaxf(h[(size_t)node * C + c] * sc[c] + sh[c], 0.f);
        rr += v * wrl[c];
        rt += v * wrt[c];
    }
    for (int off = 32; off; off >>= 1) {
        rr += __shfl_down(rr, off);
        rt += __shfl_down(rt, off);
    }
    if (lane == 0) { r[node] = rr; root[node] = rt; }
}

// ---------------- top-k via exact 32-bit radix select (selection set == lax.top_k's) ----------
// Output perm in index-ascending order (order affects only layer-2 numbering; see notes).
__global__ void __launch_bounds__(256) topk_kernel(const float* __restrict__ r,
                                                   const float* __restrict__ root,
                                                   const int* __restrict__ rp,
                                                   const int* __restrict__ col,
                                                   const float* __restrict__ brel,
                                                   int npg, int k, int* __restrict__ perm,
                                                   float* __restrict__ tval,
                                                   int* __restrict__ map) {
    __shared__ float svals[2048];
    __shared__ uint hist[257];
    __shared__ uint pscan[256];
    __shared__ uint s_b, s_rem;
    int g = blockIdx.x;
    int tid = threadIdx.x;
    float bv = brel[0];
    for (int i = tid; i < npg; i += 256) {
        int gi = g * npg + i;
        float acc = bv + root[gi];
        int e1 = rp[gi + 1];
        for (int e = rp[gi]; e < e1; e++) acc += r[col[e]];
        svals[i] = acc;
    }
    if (tid == 0) hist[256] = 0;
    __syncthreads();

    // 4 rounds x 8 bits: find exact k-th largest key
    uint prefix = 0, himask = 0, rem = (uint)k;
    for (int shift = 24; shift >= 0; shift -= 8) {
        hist[tid] = 0;
        __syncthreads();
        for (int i = tid; i < npg; i += 256) {
            uint kk = fkey(svals[i]);
            if ((kk & himask) == prefix) atomicAdd(&hist[(kk >> shift) & 255], 1);
        }
        __syncthreads();
        // suffix sum: hist[b] = count of candidates with byte >= b
        for (int off = 1; off < 256; off <<= 1) {
            uint u = (tid + off < 256) ? hist[tid + off] : 0;
            __syncthreads();
            hist[tid] += u;
            __syncthreads();
        }
        uint sb = hist[tid], sb1 = hist[tid + 1];
        if (sb >= rem && sb1 < rem) { s_b = (uint)tid; s_rem = rem - sb1; }
        __syncthreads();
        prefix |= (s_b << shift);
        rem = s_rem;
        himask |= (0xFFu << shift);
        __syncthreads();
    }
    uint thr = prefix;   // exact k-th largest key
    uint m = rem;        // # ties at thr to take (smallest indices first)

    // selection + compaction in index order
    int chunk = npg >> 8;
    int i0 = tid * chunk;
    uint gcnt = 0, ecnt = 0, gflags = 0, eflags = 0;
    for (int j = 0; j < chunk; j++) {
        uint kk = fkey(svals[i0 + j]);
        if (kk > thr) { gflags |= 1u << j; gcnt++; }
        else if (kk == thr) { eflags |= 1u << j; ecnt++; }
    }
    pscan[tid] = (gcnt << 16) | ecnt;
    __syncthreads();
    uint v = pscan[tid];
    for (int off = 1; off < 256; off <<= 1) {
        uint u = (tid >= off) ? pscan[tid - off] : 0;
        __syncthreads();
        v += u;
        pscan[tid] = v;
        __syncthreads();
    }
    uint excl = v - ((gcnt << 16) | ecnt);
    uint gbase = excl >> 16, ebase = excl & 0xFFFFu;
    for (int j = 0; j < chunk; j++) {
        bool gt = (gflags >> j) & 1u;
        bool eq = (eflags >> j) & 1u;
        if (gt || (eq && ebase < m)) {
            uint pos = gbase + min(ebase, m);
            int gi = g * npg + i0 + j;
            int o = g * k + (int)pos;
            perm[o] = gi;
            tval[o] = tanhf(svals[i0 + j]);
            if (map) map[gi] = o;
        }
        gbase += gt ? 1u : 0u;
        ebase += eq ? 1u : 0u;
    }
}

// ---------------- fused: BN-apply gather (layer1) + count2 ----------------
__global__ void __launch_bounds__(256) gcount_kernel(
        const float* __restrict__ h1, const int* __restrict__ perm1,
        const float* __restrict__ tv1, const double* __restrict__ dsum,
        const double* __restrict__ dsq, const float* __restrict__ g,
        const float* __restrict__ b, ushort* __restrict__ h1pb,
        const int* __restrict__ src, const int* __restrict__ tgt,
        const int* __restrict__ map, int* __restrict__ wc2) {
    int blockBase = blockIdx.x * 256;
    if (blockBase < N1c * H1c) {
        __shared__ float sc[128], sh[128];
        if (threadIdx.x < 128) {
            int c = threadIdx.x;
            double m = dsum[c] / (double)Nn;
            double var = dsq[c] / (double)Nn - m * m;
            float s = g[c] * (float)(1.0 / sqrt(var + 1e-5));
            sc[c] = s; sh[c] = b[c] - (float)m * s;
        }
        __syncthreads();
        int t = blockBase + threadIdx.x;
        int m = t >> 7, c = t & 127;
        float v = fmaxf(h1[((size_t)perm1[m] << 7) + c] * sc[c] + sh[c], 0.f);
        h1pb[t] = f2bf(v * tv1[m]);
    } else {
        int e = blockBase + threadIdx.x - N1c * H1c;
        if (e >= Ee) return;
        int ns = map[src[e]];
        int nt = map[tgt[e]];
        if (ns >= 0 && nt >= 0) atomicAdd(&wc2[nt], 1);
    }
}

// ---------------- fused: layer2 BN-apply + tanh-scale + pooled accumulate ----------------
__global__ void __launch_bounds__(256) pool_part_kernel(const float* __restrict__ h2,
                                                        const int* __restrict__ perm2,
                                                        const float* __restrict__ tv2,
                                                        const double* __restrict__ dsum,
                                                        const double* __restrict__ dsq,
                                                        const float* __restrict__ g,
                                                        const float* __restrict__ b,
                                                        float* __restrict__ pooled) {
    __shared__ float sc[256], sh[256];
    {
        int c = threadIdx.x;
        double m = dsum[c] / (double)N1c;
        double var = dsq[c] / (double)N1c - m * m;
        float s = g[c] * (float)(1.0 / sqrt(var + 1e-5));
        sc[c] = s; sh[c] = b[c] - (float)m * s;
    }
    __syncthreads();
    int gg = blockIdx.x, p = blockIdx.y, c = threadIdx.x;
    float s = 0.f;
    for (int j = 0; j < 64; j++) {
        int m = gg * K2c + p * 64 + j;
        int row = perm2[m];
        float v = fmaxf(h2[((size_t)row << 8) + c] * sc[c] + sh[c], 0.f);
        s += v * tv2[m];
    }
    atomicAdd(&pooled[gg * H2c + c], s);
}

__global__ void __launch_bounds__(256) pool_fin_kernel(const float* __restrict__ pooled,
                                                       const float* __restrict__ Wlin,
                                                       const float* __restrict__ blin,
                                                       float* __restrict__ out) {
    __shared__ float p0s[256], p1s[256];
    int g = blockIdx.x, c = threadIdx.x;
    float s = fmaxf(pooled[g * 256 + c] * (1.f / (float)K2c), 0.f);
    p0s[c] = s * Wlin[c * 2 + 0];
    p1s[c] = s * Wlin[c * 2 + 1];
    __syncthreads();
    for (int off = 128; off; off >>= 1) {
        if (c < off) { p0s[c] += p0s[c + off]; p1s[c] += p1s[c + off]; }
        __syncthreads();
    }
    if (c == 0) {
        float o0 = p0s[0] + blin[0], o1 = p1s[0] + blin[1];
        float m = fmaxf(o0, o1);
        float e0 = expf(o0 - m), e1 = expf(o1 - m);
        float inv = 1.f / (e0 + e1);
        out[g * 2 + 0] = e0 * inv;
        out[g * 2 + 1] = e1 * inv;
    }
}

extern "C" void kernel_launch(void* const* d_in, const int* in_sizes, int n_in,
                              void* d_out, int out_size, void* d_ws, size_t ws_size,
                              hipStream_t stream) {
    const float* x      = (const float*)d_in[0];
    const int*   ei     = (const int*)d_in[1];
    const int*   src    = ei;
    const int*   tgt    = ei + Ee;
    const float* W1l    = (const float*)d_in[3];
    const float* b1l    = (const float*)d_in[4];
    const float* W1r    = (const float*)d_in[5];
    const float* bn1g   = (const float*)d_in[6];
    const float* bn1b   = (const float*)d_in[7];
    const float* p1Wrel = (const float*)d_in[8];
    const float* p1brel = (const float*)d_in[9];
    const float* p1Wroot= (const float*)d_in[10];
    const float* W2l    = (const float*)d_in[11];
    const float* b2l    = (const float*)d_in[12];
    const float* W2r    = (const float*)d_in[13];
    const float* bn2g   = (const float*)d_in[14];
    const float* bn2b   = (const float*)d_in[15];
    const float* p2Wrel = (const float*)d_in[16];
    const float* p2brel = (const float*)d_in[17];
    const float* p2Wroot= (const float*)d_in[18];
    const float* Wlin   = (const float*)d_in[19];
    const float* blin   = (const float*)d_in[20];
    float* out = (float*)d_out;
    char* ws = (char*)d_ws;

    size_t o = 0;
    auto A = [&](size_t b) { size_t r = o; o += (b + 255) & ~(size_t)255; return r; };
    size_t oBIG1 = A((size_t)Nn * H1c * 4);        // h1 / h2 f32
    size_t oBIG2 = A((size_t)Nn * INc * 4);        // xb + aggb1 bf16
    size_t oPB   = A((size_t)N1c * H1c * 4);       // h1pb + aggb2 bf16
    size_t oCol1 = A((size_t)Ee * 4);
    size_t oCol2 = A((size_t)Ee * 4);
    size_t oRp1  = A((size_t)(Nn + 1) * 4);
    size_t oWc1  = A((size_t)Nn * 4);
    size_t oCur1 = A((size_t)Nn * 4);
    size_t oMap  = A((size_t)Nn * 4);
    size_t oR1   = A((size_t)Nn * 4);
    size_t oRoot1= A((size_t)Nn * 4);
    size_t oPerm1= A((size_t)N1c * 4);
    size_t oTv1  = A((size_t)N1c * 4);
    size_t oRp2  = A((size_t)(N1c + 1) * 4);
    size_t oWc2  = A((size_t)N1c * 4);
    size_t oCur2 = A((size_t)N1c * 4);
    size_t oR2   = A((size_t)N1c * 4);
    size_t oRoot2= A((size_t)N1c * 4);
    size_t oPerm2= A((size_t)N2c * 4);
    size_t oTv2  = A((size_t)N2c * 4);
    size_t oDst  = A(768 * 8);
    size_t oBsum = A(64 * 4);
    size_t oWt1l = A(8192 * 2);
    size_t oWt1r = A(8192 * 2);
    size_t oWt2l = A(32768 * 2);
    size_t oWt2r = A(32768 * 2);
    size_t oPool = A(Bg * H2c * 4);
    (void)ws_size; (void)in_sizes; (void)n_in; (void)out_size;

    float* h1    = (float*)(ws + oBIG1);
    float* h2    = (float*)(ws + oBIG1);
    ushort* xb   = (ushort*)(ws + oBIG2);
    ushort* aggb1= (ushort*)(ws + oBIG2 + (size_t)Nn * 64 * 2);
    ushort* h1pb = (ushort*)(ws + oPB);
    ushort* aggb2= (ushort*)(ws + oPB + (size_t)N1c * 128 * 2);
    int* col1    = (int*)(ws + oCol1);
    int* col2    = (int*)(ws + oCol2);
    int* rp1     = (int*)(ws + oRp1);
    int* wc1     = (int*)(ws + oWc1);
    int* cur1    = (int*)(ws + oCur1);
    int* map1    = (int*)(ws + oMap);
    float* r1    = (float*)(ws + oR1);
    float* root1 = (float*)(ws + oRoot1);
    int* perm1   = (int*)(ws + oPerm1);
    float* tv1   = (float*)(ws + oTv1);
    int* rp2     = (int*)(ws + oRp2);
    int* wc2     = (int*)(ws + oWc2);
    int* cur2    = (int*)(ws + oCur2);
    float* r2    = (float*)(ws + oR2);
    float* root2 = (float*)(ws + oRoot2);
    int* perm2   = (int*)(ws + oPerm2);
    float* tv2   = (float*)(ws + oTv2);
    double* dsum1= (double*)(ws + oDst);
    double* dsq1 = dsum1 + 128;
    double* dsum2= dsum1 + 256;
    double* dsq2 = dsum1 + 512;
    int* bsum    = (int*)(ws + oBsum);
    ushort* T1l  = (ushort*)(ws + oWt1l);
    ushort* T1r  = (ushort*)(ws + oWt1r);
    ushort* T2l  = (ushort*)(ws + oWt2l);
    ushort* T2r  = (ushort*)(ws + oWt2r);
    float* pooled= (float*)(ws + oPool);

    // 1. prep (wt transpose + inits + xconv + count1)
    prep_kernel<<<(PREP_TOTAL + 255) / 256, 256, 0, stream>>>(
        x, tgt, W1l, W1r, W2l, W2r, T1l, T1r, T2l, T2r, xb, map1, wc1, wc2,
        (int*)dsum1, (int*)pooled);

    // ===== Layer 1 CSR =====
    scan_part_kernel<<<Nn / 1024, 256, 0, stream>>>(wc1, bsum);
    scan_fin_kernel<<<Nn / 1024, 256, 0, stream>>>(wc1, bsum, Nn / 1024, rp1, cur1, Nn);
    fill_kernel<<<Ee / 256, 256, 0, stream>>>(src, tgt, Ee, cur1, col1);

    // SAGEConv1
    agg1_kernel<<<8192, 256, 0, stream>>>(xb, rp1, col1, aggb1);
    {
        dim3 g(Nn / 64, H1c / 64);
        gemm_mfma_kernel<INc, H1c><<<g, 256, 0, stream>>>(aggb1, xb, T1l, T1r, b1l, h1);
    }

    // BN1 stats + score + topk(+segscore)
    bnstats_kernel<<<256, 256, 0, stream>>>(h1, Nn, H1c, dsum1, dsq1);
    score_kernel<H1c><<<Nn / 4, 256, 0, stream>>>(h1, dsum1, dsq1, bn1g, bn1b, p1Wrel,
                                                  p1Wroot, r1, root1, Nn);
    topk_kernel<<<Bg, 256, 0, stream>>>(r1, root1, rp1, col1, p1brel, NPGc, K1c,
                                        perm1, tv1, map1);

    // BN-apply gather (h1 -> h1pb) + count2
    gcount_kernel<<<(N1c * H1c + Ee) / 256, 256, 0, stream>>>(
        h1, perm1, tv1, dsum1, dsq1, bn1g, bn1b, h1pb, src, tgt, map1, wc2);

    // ===== Layer 2 CSR =====
    scan_part_kernel<<<N1c / 1024, 256, 0, stream>>>(wc2, bsum);
    scan_fin_kernel<<<N1c / 1024, 256, 0, stream>>>(wc2, bsum, N1c / 1024, rp2, cur2, N1c);
    fill2_kernel<<<Ee / 256, 256, 0, stream>>>(src, tgt, map1, cur2, col2);

    // SAGEConv2
    agg2_kernel<<<8192, 256, 0, stream>>>(h1pb, rp2, col2, aggb2);
    {
        dim3 g(N1c / 64, H2c / 64);
        gemm_mfma_kernel<H1c, H2c><<<g, 256, 0, stream>>>(aggb2, h1pb, T2l, T2r, b2l, h2);
    }

    // BN2 stats + score + topk(+segscore)
    bnstats_kernel<<<256, 256, 0, stream>>>(h2, N1c, H2c, dsum2, dsq2);
    score_kernel<H2c><<<N1c / 4, 256, 0, stream>>>(h2, dsum2, dsq2, bn2g, bn2b, p2Wrel,
                                                   p2Wroot, r2, root2, N1c);
    topk_kernel<<<Bg, 256, 0, stream>>>(r2, root2, rp2, col2, p2brel, K1c, K2c,
                                        perm2, tv2, nullptr);

    // Fused BN-apply + tanh-scale + pool, then readout
    {
        dim3 g(Bg, K2c / 64);
        pool_part_kernel<<<g, 256, 0, stream>>>(h2, perm2, tv2, dsum2, dsq2, bn2g, bn2b,
                                                pooled);
    }
    pool_fin_kernel<<<Bg, 256, 0, stream>>>(pooled, Wlin, blin, out);
}

// Round 6
// 381.391 us; speedup vs baseline: 2.4126x; 1.0862x over previous
//
#include <hip/hip_runtime.h>
#include <math.h>

#define Bg   32
#define NPGc 2048
#define Nn   (Bg*NPGc)      // 65536
#define DEGc 8
#define Ee   (Nn*DEGc)      // 524288
#define INc  64
#define H1c  128
#define H2c  256
#define K1c  1024
#define K2c  512
#define N1c  (Bg*K1c)       // 32768
#define N2c  (Bg*K2c)       // 16384

typedef __attribute__((ext_vector_type(8))) short short8;
typedef __attribute__((ext_vector_type(4))) float f32x4;

__device__ __forceinline__ ushort f2bf(float f) {
    uint u = __float_as_uint(f);
    uint r = (u + 0x7fffu + ((u >> 16) & 1u)) >> 16;
    return (ushort)r;
}
__device__ __forceinline__ float bfhi(uint v) { return __uint_as_float(v & 0xffff0000u); }
__device__ __forceinline__ float bflo(uint v) { return __uint_as_float(v << 16); }
__device__ __forceinline__ uint fkey(float f) {
    uint u = __float_as_uint(f);
    return u ^ ((uint)((int)u >> 31) | 0x80000000u);
}

// ---------------- prep: wt transpose + x->bf16 + count1 + all inits (1 kernel) ----------------
__global__ void prep_kernel(const float* __restrict__ x, const int* __restrict__ tgt,
                            const float* __restrict__ W1l, const float* __restrict__ W1r,
                            const float* __restrict__ W2l, const float* __restrict__ W2r,
                            ushort* __restrict__ T1l, ushort* __restrict__ T1r,
                            ushort* __restrict__ T2l, ushort* __restrict__ T2r,
                            ushort* __restrict__ xb, int* __restrict__ map1,
                            int* __restrict__ wc1, int* __restrict__ wc2,
                            int* __restrict__ dstats, int* __restrict__ pooled) {
    int id = blockIdx.x * blockDim.x + threadIdx.x;
    if (id < 8192) {
        int c = id / 64, k = id % 64;
        T1l[id] = f2bf(W1l[k * 128 + c]);
        T1r[id] = f2bf(W1r[k * 128 + c]);
        return;
    }
    id -= 8192;
    if (id < 32768) {
        int c = id / 128, k = id % 128;
        T2l[id] = f2bf(W2l[k * 256 + c]);
        T2r[id] = f2bf(W2r[k * 256 + c]);
        return;
    }
    id -= 32768;
    if (id < 16384) { ((int4*)map1)[id] = (int4){-1, -1, -1, -1}; return; }
    id -= 16384;
    if (id < 16384) { ((int4*)wc1)[id] = (int4){0, 0, 0, 0}; return; }
    id -= 16384;
    if (id < 8192)  { ((int4*)wc2)[id] = (int4){0, 0, 0, 0}; return; }
    id -= 8192;
    if (id < 384)   { ((int4*)dstats)[id] = (int4){0, 0, 0, 0}; return; }
    id -= 384;
    if (id < 2048)  { ((int4*)pooled)[id] = (int4){0, 0, 0, 0}; return; }
    id -= 2048;
    if (id < Nn * 64 / 4) {  // x -> bf16
        float4 v = ((const float4*)x)[id];
        ushort4 o; o.x = f2bf(v.x); o.y = f2bf(v.y); o.z = f2bf(v.z); o.w = f2bf(v.w);
        ((ushort4*)xb)[id] = o;
        return;
    }
    id -= Nn * 64 / 4;
    if (id < Ee) atomicAdd(&wc1[tgt[id]], 1);
}
#define PREP_TOTAL (8192 + 32768 + 16384 + 16384 + 8192 + 384 + 2048 + Nn*64/4 + Ee)

// ---------------- scan (2 kernels; mid-scan folded into fin) ----------------
__global__ void __launch_bounds__(256) scan_part_kernel(const int* __restrict__ in,
                                                        int* __restrict__ bsum) {
    __shared__ int red[256];
    int base = blockIdx.x * 1024;
    int4 v = ((const int4*)&in[base])[threadIdx.x];
    int s = v.x + v.y + v.z + v.w;
    red[threadIdx.x] = s;
    __syncthreads();
    for (int off = 128; off; off >>= 1) {
        if ((int)threadIdx.x < off) red[threadIdx.x] += red[threadIdx.x + off];
        __syncthreads();
    }
    if (threadIdx.x == 0) bsum[blockIdx.x] = red[0];
}

__global__ void __launch_bounds__(256) scan_fin_kernel(const int* __restrict__ in,
                                                       const int* __restrict__ bsum, int nb,
                                                       int* __restrict__ rp,
                                                       int* __restrict__ cur, int n) {
    __shared__ int red[256];
    __shared__ int sbase;
    if (threadIdx.x < 64) {   // wave 0: redundant 64-wide scan of block partials
        int t = threadIdx.x;
        int bv = (t < nb) ? bsum[t] : 0;
        int v = bv;
        for (int off = 1; off < 64; off <<= 1) {
            int u = __shfl_up(v, off);
            if (t >= off) v += u;
        }
        if (t == (int)blockIdx.x) sbase = v - bv;  // exclusive prefix for this block
    }
    int base = blockIdx.x * 1024;
    int4 v = ((const int4*)&in[base])[threadIdx.x];
    int s = v.x + v.y + v.z + v.w;
    red[threadIdx.x] = s;
    __syncthreads();
    int val = s;
    for (int off = 1; off < 256; off <<= 1) {
        int t = ((int)threadIdx.x >= off) ? red[threadIdx.x - off] : 0;
        __syncthreads();
        val += t;
        red[threadIdx.x] = val;
        __syncthreads();
    }
    int o = val - s + sbase;
    int i0 = base + threadIdx.x * 4;
    int4 w;
    w.x = o; o += v.x;
    w.y = o; o += v.y;
    w.z = o; o += v.z;
    w.w = o;
    *(int4*)&rp[i0] = w;
    *(int4*)&cur[i0] = w;
    if ((int)blockIdx.x == nb - 1 && threadIdx.x == 255) rp[n] = sbase + val;
}

__global__ void fill_kernel(const int* __restrict__ src, const int* __restrict__ tgt, int ne,
                            int* __restrict__ cur, int* __restrict__ col) {
    int e = blockIdx.x * blockDim.x + threadIdx.x;
    if (e >= ne) return;
    int p = atomicAdd(&cur[tgt[e]], 1);
    col[p] = src[e];
}

__global__ void fill2_kernel(const int* __restrict__ src, const int* __restrict__ tgt,
                             const int* __restrict__ map, int* __restrict__ cur,
                             int* __restrict__ col) {
    int e = blockIdx.x * blockDim.x + threadIdx.x;
    if (e >= Ee) return;
    int ns = map[src[e]];
    int nt = map[tgt[e]];
    if (ns >= 0 && nt >= 0) {
        int p = atomicAdd(&cur[nt], 1);
        col[p] = ns;
    }
}

// ---------------- mean aggregation, bf16 in/out, XCD-swizzled ----------------
__global__ void agg1_kernel(const ushort* __restrict__ xb, const int* __restrict__ rowptr,
                            const int* __restrict__ col, ushort* __restrict__ out) {
    int b = blockIdx.x;
    int w = ((b & 7) << 10) + (b >> 3);   // XCD x owns graphs [4x,4x+4): 2MB slice < 4MB L2
    int gid = w * 256 + threadIdx.x;
    int node = gid >> 5, lane = gid & 31;
    int bg = rowptr[node], e = rowptr[node + 1];
    float a0 = 0.f, a1 = 0.f;
    for (int i = bg; i < e; i++) {
        uint v = *(const uint*)&xb[((size_t)col[i] << 6) + 2 * lane];
        a0 += bflo(v);
        a1 += bfhi(v);
    }
    int cnt = e - bg; if (cnt < 1) cnt = 1;
    float inv = 1.f / (float)cnt;
    ushort2 st; st.x = f2bf(a0 * inv); st.y = f2bf(a1 * inv);
    *(ushort2*)&out[((size_t)node << 6) + 2 * lane] = st;
}

__global__ void agg2_kernel(const ushort* __restrict__ xb, const int* __restrict__ rowptr,
                            const int* __restrict__ col, ushort* __restrict__ out) {
    int b = blockIdx.x;
    int w = ((b & 7) << 10) + (b >> 3);
    int gid = w * 256 + threadIdx.x;
    int node = gid >> 6, lane = gid & 63;
    int bg = rowptr[node], e = rowptr[node + 1];
    float a0 = 0.f, a1 = 0.f;
    for (int i = bg; i < e; i++) {
        uint v = *(const uint*)&xb[((size_t)col[i] << 7) + 2 * lane];
        a0 += bflo(v);
        a1 += bfhi(v);
    }
    int cnt = e - bg; if (cnt < 1) cnt = 1;
    float inv = 1.f / (float)cnt;
    ushort2 st; st.x = f2bf(a0 * inv); st.y = f2bf(a1 * inv);
    *(ushort2*)&out[((size_t)node << 7) + 2 * lane] = st;
}

// ---------------- MFMA GEMM: out[M,COUT] = Aagg@Wl + Ax@Wr + bias ----------------
template<int K, int COUT>
__global__ __launch_bounds__(256) void gemm_mfma_kernel(
        const ushort* __restrict__ Aagg, const ushort* __restrict__ Ax,
        const ushort* __restrict__ Wtl, const ushort* __restrict__ Wtr,
        const float* __restrict__ bias, float* __restrict__ out) {
    __shared__ ushort As[2][64][72];
    __shared__ ushort Bs[2][64][72];
    int m0 = blockIdx.x * 64;
    int c0 = blockIdx.y * 64;
    int lane = threadIdx.x & 63;
    int wid = threadIdx.x >> 6;
    int wr = (wid & 1) * 32, wc = (wid >> 1) * 32;
    int l16 = lane & 15, quad = lane >> 4;

    f32x4 acc[2][2];
#pragma unroll
    for (int a = 0; a < 2; a++)
#pragma unroll
        for (int b = 0; b < 2; b++) acc[a][b] = (f32x4){0.f, 0.f, 0.f, 0.f};

    for (int kk0 = 0; kk0 < K; kk0 += 64) {
        for (int idx = threadIdx.x; idx < 512; idx += 256) {
            int r = idx >> 3, ck = (idx & 7) * 8;
            *(uint4*)&As[0][r][ck] = *(const uint4*)&Aagg[(size_t)(m0 + r) * K + kk0 + ck];
            *(uint4*)&As[1][r][ck] = *(const uint4*)&Ax[(size_t)(m0 + r) * K + kk0 + ck];
            *(uint4*)&Bs[0][r][ck] = *(const uint4*)&Wtl[(size_t)(c0 + r) * K + kk0 + ck];
            *(uint4*)&Bs[1][r][ck] = *(const uint4*)&Wtr[(size_t)(c0 + r) * K + kk0 + ck];
        }
        __syncthreads();
#pragma unroll
        for (int kk = 0; kk < 64; kk += 32) {
            short8 a[2][2], b[2][2];
#pragma unroll
            for (int s = 0; s < 2; s++)
#pragma unroll
                for (int mt = 0; mt < 2; mt++)
                    a[s][mt] = *(const short8*)&As[s][wr + mt * 16 + l16][kk + quad * 8];
#pragma unroll
            for (int s = 0; s < 2; s++)
#pragma unroll
                for (int nt = 0; nt < 2; nt++)
                    b[s][nt] = *(const short8*)&Bs[s][wc + nt * 16 + l16][kk + quad * 8];
#pragma unroll
            for (int mt = 0; mt < 2; mt++)
#pragma unroll
                for (int nt = 0; nt < 2; nt++) {
                    acc[mt][nt] = __builtin_amdgcn_mfma_f32_16x16x32_bf16(
                        a[0][mt], b[0][nt], acc[mt][nt], 0, 0, 0);
                    acc[mt][nt] = __builtin_amdgcn_mfma_f32_16x16x32_bf16(
                        a[1][mt], b[1][nt], acc[mt][nt], 0, 0, 0);
                }
        }
        __syncthreads();
    }
#pragma unroll
    for (int mt = 0; mt < 2; mt++)
#pragma unroll
        for (int nt = 0; nt < 2; nt++) {
            int col = c0 + wc + nt * 16 + l16;
            float bv = bias[col];
#pragma unroll
            for (int r = 0; r < 4; r++) {
                int row = m0 + wr + mt * 16 + quad * 4 + r;
                out[(size_t)row * COUT + col] = acc[mt][nt][r] + bv;
            }
        }
}

// ---------------- BatchNorm stats on RAW h (f64 atomics) ----------------
__global__ void __launch_bounds__(256) bnstats_kernel(const float* __restrict__ h, int n, int C,
                                                      double* __restrict__ dsum,
                                                      double* __restrict__ dsq) {
    __shared__ float s1[256], s2[256];
    int c = threadIdx.x & (C - 1);
    int rpg = 256 / C;
    int sub = threadIdx.x / C;
    float s = 0.f, sq = 0.f;
    for (int row = blockIdx.x * rpg + sub; row < n; row += gridDim.x * rpg) {
        float v = h[(size_t)row * C + c];
        s += v; sq += v * v;
    }
    s1[threadIdx.x] = s; s2[threadIdx.x] = sq;
    __syncthreads();
    if (C == 128 && threadIdx.x < 128) {
        s1[threadIdx.x] += s1[threadIdx.x + 128];
        s2[threadIdx.x] += s2[threadIdx.x + 128];
    }
    __syncthreads();
    if ((int)threadIdx.x < C) {
        atomicAdd(&dsum[threadIdx.x], (double)s1[threadIdx.x]);
        atomicAdd(&dsq[threadIdx.x], (double)s2[threadIdx.x]);
    }
}

// ---------------- score dots from RAW h; scale/shift computed in-block ----------------
template<int C>
__global__ __launch_bounds__(256) void score_kernel(const float* __restrict__ h,
                                                    const double* __restrict__ dsum,
                                                    const double* __restrict__ dsq,
                                                    const float* __restrict__ g,
                                                    const float* __restrict__ b,
                                                    const float* __restrict__ wrel,
                                                    const float* __restrict__ wroot,
                                                    float* __restrict__ r,
                                                    float* __restrict__ root, int n) {
    __shared__ float sc[C], sh[C], wrl[C], wrt[C];
    if ((int)threadIdx.x < C) {
        int c = threadIdx.x;
        double m = dsum[c] / (double)n;
        double var = dsq[c] / (double)n - m * m;
        float s = g[c] * (float)(1.0 / sqrt(var + 1e-5));
        sc[c] = s; sh[c] = b[c] - (float)m * s;
        wrl[c] = wrel[c]; wrt[c] = wroot[c];
    }
    __syncthreads();
    int gid = blockIdx.x * 256 + threadIdx.x;
    int node = gid >> 6, lane = gid & 63;
    float rr = 0.f, rt = 0.f;
    for (int c = lane; c < C; c += 64) {
        float v = fmaxf(h[(size_t)node * C + c] * sc[c] + sh[c], 0.f);
        rr += v * wrl[c];
        rt += v * wrt[c];
    }
    for (int off = 32; off; off >>= 1) {
        rr += __shfl_down(rr, off);
        rt += __shfl_down(rt, off);
    }
    if (lane == 0) { r[node] = rr; root[node] = rt; }
}

// ---------------- top-k: exact 32-bit radix select, 1024 thr, wave-scan (few barriers) -------
__global__ void __launch_bounds__(1024) topk_kernel(const float* __restrict__ r,
                                                    const float* __restrict__ root,
                                                    const int* __restrict__ rp,
                                                    const int* __restrict__ col,
                                                    const float* __restrict__ brel,
                                                    int npg, int k, int* __restrict__ perm,
                                                    float* __restrict__ tval,
                                                    int* __restrict__ map) {
    __shared__ float svals[2048];
    __shared__ uint hist[257];
    __shared__ uint wsum[16];
    __shared__ uint s_b, s_rem;
    int g = blockIdx.x;
    int tid = threadIdx.x;
    int lane = tid & 63, wid = tid >> 6;
    float bv = brel[0];
    for (int i = tid; i < npg; i += 1024) {
        int gi = g * npg + i;
        float acc = bv + root[gi];
        int e1 = rp[gi + 1];
        for (int e = rp[gi]; e < e1; e++) acc += r[col[e]];
        svals[i] = acc;
    }
    if (tid == 256) hist[256] = 0;
    if (tid < 256) hist[tid] = 0;
    __syncthreads();

    // 4 rounds x 8 bits: exact k-th largest key
    uint prefix = 0, himask = 0, rem = (uint)k;
    for (int shift = 24; shift >= 0; shift -= 8) {
        for (int i = tid; i < npg; i += 1024) {
            uint kk = fkey(svals[i]);
            if ((kk & himask) == prefix) atomicAdd(&hist[(kk >> shift) & 255], 1);
        }
        __syncthreads();
        if (tid < 64) {  // wave 0: suffix-sum of 256 bins, 4 bins/lane, zero barriers
            int L = tid;
            uint h0 = hist[4 * L], h1 = hist[4 * L + 1], h2 = hist[4 * L + 2],
                 h3 = hist[4 * L + 3];
            uint s3 = h3, s2 = h2 + s3, s1 = h1 + s2, s0 = h0 + s1;
            uint v = s0;
            for (int off = 1; off < 64; off <<= 1) {
                uint u = __shfl_down(v, off);
                if (L + off < 64) v += u;
            }
            uint above = v - s0;  // strictly higher lanes
            hist[4 * L] = s0 + above;
            hist[4 * L + 1] = s1 + above;
            hist[4 * L + 2] = s2 + above;
            hist[4 * L + 3] = s3 + above;
        }
        __syncthreads();
        if (tid < 256) {
            uint sb = hist[tid], sb1 = hist[tid + 1];
            if (sb >= rem && sb1 < rem) { s_b = (uint)tid; s_rem = rem - sb1; }
        }
        __syncthreads();
        prefix |= (s_b << shift);
        rem = s_rem;
        himask |= (0xFFu << shift);
        if (tid < 256) hist[tid] = 0;   // clear for next round
        __syncthreads();
    }
    uint thr = prefix;   // exact k-th largest key
    uint m = rem;        // # ties at thr still to take

    // selection + compaction, interleaved order (conflict-free), wave-scan prefix
    int nchunk = npg >> 10;   // 2 or 1
    uint gcnt = 0, ecnt = 0, gflags = 0, eflags = 0;
    for (int j = 0; j < nchunk; j++) {
        uint kk = fkey(svals[tid + (j << 10)]);
        if (kk > thr) { gflags |= 1u << j; gcnt++; }
        else if (kk == thr) { eflags |= 1u << j; ecnt++; }
    }
    uint key = (gcnt << 16) | ecnt;
    uint v = key;
    for (int off = 1; off < 64; off <<= 1) {
        uint u = __shfl_up(v, off);
        if (lane >= off) v += u;
    }
    if (lane == 63) wsum[wid] = v;
    __syncthreads();
    if (tid < 16) {
        uint w0 = wsum[tid], w = w0;
        for (int off = 1; off < 16; off <<= 1) {
            uint u = __shfl_up(w, off);
            if ((int)tid >= off) w += u;
        }
        wsum[tid] = w - w0;  // exclusive wave offset
    }
    __syncthreads();
    uint excl = (v - key) + wsum[wid];
    uint gbase = excl >> 16, ebase = excl & 0xFFFFu;
    for (int j = 0; j < nchunk; j++) {
        bool gt = (gflags >> j) & 1u;
        bool eq = (eflags >> j) & 1u;
        if (gt || (eq && ebase < m)) {
            uint pos = gbase + min(ebase, m);
            int i = tid + (j << 10);
            int gi = g * npg + i;
            int o = g * k + (int)pos;
            perm[o] = gi;
            tval[o] = tanhf(svals[i]);
            if (map) map[gi] = o;
        }
        gbase += gt ? 1u : 0u;
        ebase += eq ? 1u : 0u;
    }
}

// ---------------- fused: BN-apply gather (layer1) + count2 ----------------
__global__ void __launch_bounds__(256) gcount_kernel(
        const float* __restrict__ h1, const int* __restrict__ perm1,
        const float* __restrict__ tv1, const double* __restrict__ dsum,
        const double* __restrict__ dsq, const float* __restrict__ g,
        const float* __restrict__ b, ushort* __restrict__ h1pb,
        const int* __restrict__ src, const int* __restrict__ tgt,
        const int* __restrict__ map, int* __restrict__ wc2) {
    int blockBase = blockIdx.x * 256;
    if (blockBase < N1c * H1c) {
        __shared__ float sc[128], sh[128];
        if (threadIdx.x < 128) {
            int c = threadIdx.x;
            double m = dsum[c] / (double)Nn;
            double var = dsq[c] / (double)Nn - m * m;
            float s = g[c] * (float)(1.0 / sqrt(var + 1e-5));
            sc[c] = s; sh[c] = b[c] - (float)m * s;
        }
        __syncthreads();
        int t = blockBase + threadIdx.x;
        int m = t >> 7, c = t & 127;
        float v = fmaxf(h1[((size_t)perm1[m] << 7) + c] * sc[c] + sh[c], 0.f);
        h1pb[t] = f2bf(v * tv1[m]);
    } else {
        int e = blockBase + threadIdx.x - N1c * H1c;
        if (e >= Ee) return;
        int ns = map[src[e]];
        int nt = map[tgt[e]];
        if (ns >= 0 && nt >= 0) atomicAdd(&wc2[nt], 1);
    }
}

// ---------------- fused: layer2 BN-apply + tanh-scale + pooled accumulate ----------------
__global__ void __launch_bounds__(256) pool_part_kernel(const float* __restrict__ h2,
                                                        const int* __restrict__ perm2,
                                                        const float* __restrict__ tv2,
                                                        const double* __restrict__ dsum,
                                                        const double* __restrict__ dsq,
                                                        const float* __restrict__ g,
                                                        const float* __restrict__ b,
                                                        float* __restrict__ pooled) {
    __shared__ float sc[256], sh[256];
    {
        int c = threadIdx.x;
        double m = dsum[c] / (double)N1c;
        double var = dsq[c] / (double)N1c - m * m;
        float s = g[c] * (float)(1.0 / sqrt(var + 1e-5));
        sc[c] = s; sh[c] = b[c] - (float)m * s;
    }
    __syncthreads();
    int gg = blockIdx.x, p = blockIdx.y, c = threadIdx.x;
    float s = 0.f;
    for (int j = 0; j < 64; j++) {
        int m = gg * K2c + p * 64 + j;
        int row = perm2[m];
        float v = fmaxf(h2[((size_t)row << 8) + c] * sc[c] + sh[c], 0.f);
        s += v * tv2[m];
    }
    atomicAdd(&pooled[gg * H2c + c], s);
}

__global__ void __launch_bounds__(256) pool_fin_kernel(const float* __restrict__ pooled,
                                                       const float* __restrict__ Wlin,
                                                       const float* __restrict__ blin,
                                                       float* __restrict__ out) {
    __shared__ float p0s[256], p1s[256];
    int g = blockIdx.x, c = threadIdx.x;
    float s = fmaxf(pooled[g * 256 + c] * (1.f / (float)K2c), 0.f);
    p0s[c] = s * Wlin[c * 2 + 0];
    p1s[c] = s * Wlin[c * 2 + 1];
    __syncthreads();
    for (int off = 128; off; off >>= 1) {
        if (c < off) { p0s[c] += p0s[c + off]; p1s[c] += p1s[c + off]; }
        __syncthreads();
    }
    if (c == 0) {
        float o0 = p0s[0] + blin[0], o1 = p1s[0] + blin[1];
        float m = fmaxf(o0, o1);
        float e0 = expf(o0 - m), e1 = expf(o1 - m);
        float inv = 1.f / (e0 + e1);
        out[g * 2 + 0] = e0 * inv;
        out[g * 2 + 1] = e1 * inv;
    }
}

extern "C" void kernel_launch(void* const* d_in, const int* in_sizes, int n_in,
                              void* d_out, int out_size, void* d_ws, size_t ws_size,
                              hipStream_t stream) {
    const float* x      = (const float*)d_in[0];
    const int*   ei     = (const int*)d_in[1];
    const int*   src    = ei;
    const int*   tgt    = ei + Ee;
    const float* W1l    = (const float*)d_in[3];
    const float* b1l    = (const float*)d_in[4];
    const float* W1r    = (const float*)d_in[5];
    const float* bn1g   = (const float*)d_in[6];
    const float* bn1b   = (const float*)d_in[7];
    const float* p1Wrel = (const float*)d_in[8];
    const float* p1brel = (const float*)d_in[9];
    const float* p1Wroot= (const float*)d_in[10];
    const float* W2l    = (const float*)d_in[11];
    const float* b2l    = (const float*)d_in[12];
    const float* W2r    = (const float*)d_in[13];
    const float* bn2g   = (const float*)d_in[14];
    const float* bn2b   = (const float*)d_in[15];
    const float* p2Wrel = (const float*)d_in[16];
    const float* p2brel = (const float*)d_in[17];
    const float* p2Wroot= (const float*)d_in[18];
    const float* Wlin   = (const float*)d_in[19];
    const float* blin   = (const float*)d_in[20];
    float* out = (float*)d_out;
    char* ws = (char*)d_ws;

    size_t o = 0;
    auto A = [&](size_t b) { size_t r = o; o += (b + 255) & ~(size_t)255; return r; };
    size_t oBIG1 = A((size_t)Nn * H1c * 4);        // h1 / h2 f32
    size_t oBIG2 = A((size_t)Nn * INc * 4);        // xb + aggb1 bf16
    size_t oPB   = A((size_t)N1c * H1c * 4);       // h1pb + aggb2 bf16
    size_t oCol1 = A((size_t)Ee * 4);
    size_t oCol2 = A((size_t)Ee * 4);
    size_t oRp1  = A((size_t)(Nn + 1) * 4);
    size_t oWc1  = A((size_t)Nn * 4);
    size_t oCur1 = A((size_t)Nn * 4);
    size_t oMap  = A((size_t)Nn * 4);
    size_t oR1   = A((size_t)Nn * 4);
    size_t oRoot1= A((size_t)Nn * 4);
    size_t oPerm1= A((size_t)N1c * 4);
    size_t oTv1  = A((size_t)N1c * 4);
    size_t oRp2  = A((size_t)(N1c + 1) * 4);
    size_t oWc2  = A((size_t)N1c * 4);
    size_t oCur2 = A((size_t)N1c * 4);
    size_t oR2   = A((size_t)N1c * 4);
    size_t oRoot2= A((size_t)N1c * 4);
    size_t oPerm2= A((size_t)N2c * 4);
    size_t oTv2  = A((size_t)N2c * 4);
    size_t oDst  = A(768 * 8);
    size_t oBsum = A(64 * 4);
    size_t oWt1l = A(8192 * 2);
    size_t oWt1r = A(8192 * 2);
    size_t oWt2l = A(32768 * 2);
    size_t oWt2r = A(32768 * 2);
    size_t oPool = A(Bg * H2c * 4);
    (void)ws_size; (void)in_sizes; (void)n_in; (void)out_size;

    float* h1    = (float*)(ws + oBIG1);
    float* h2    = (float*)(ws + oBIG1);
    ushort* xb   = (ushort*)(ws + oBIG2);
    ushort* aggb1= (ushort*)(ws + oBIG2 + (size_t)Nn * 64 * 2);
    ushort* h1pb = (ushort*)(ws + oPB);
    ushort* aggb2= (ushort*)(ws + oPB + (size_t)N1c * 128 * 2);
    int* col1    = (int*)(ws + oCol1);
    int* col2    = (int*)(ws + oCol2);
    int* rp1     = (int*)(ws + oRp1);
    int* wc1     = (int*)(ws + oWc1);
    int* cur1    = (int*)(ws + oCur1);
    int* map1    = (int*)(ws + oMap);
    float* r1    = (float*)(ws + oR1);
    float* root1 = (float*)(ws + oRoot1);
    int* perm1   = (int*)(ws + oPerm1);
    float* tv1   = (float*)(ws + oTv1);
    int* rp2     = (int*)(ws + oRp2);
    int* wc2     = (int*)(ws + oWc2);
    int* cur2    = (int*)(ws + oCur2);
    float* r2    = (float*)(ws + oR2);
    float* root2 = (float*)(ws + oRoot2);
    int* perm2   = (int*)(ws + oPerm2);
    float* tv2   = (float*)(ws + oTv2);
    double* dsum1= (double*)(ws + oDst);
    double* dsq1 = dsum1 + 128;
    double* dsum2= dsum1 + 256;
    double* dsq2 = dsum1 + 512;
    int* bsum    = (int*)(ws + oBsum);
    ushort* T1l  = (ushort*)(ws + oWt1l);
    ushort* T1r  = (ushort*)(ws + oWt1r);
    ushort* T2l  = (ushort*)(ws + oWt2l);
    ushort* T2r  = (ushort*)(ws + oWt2r);
    float* pooled= (float*)(ws + oPool);

    // 1. prep (wt transpose + inits + xconv + count1)
    prep_kernel<<<(PREP_TOTAL + 255) / 256, 256, 0, stream>>>(
        x, tgt, W1l, W1r, W2l, W2r, T1l, T1r, T2l, T2r, xb, map1, wc1, wc2,
        (int*)dsum1, (int*)pooled);

    // ===== Layer 1 CSR =====
    scan_part_kernel<<<Nn / 1024, 256, 0, stream>>>(wc1, bsum);
    scan_fin_kernel<<<Nn / 1024, 256, 0, stream>>>(wc1, bsum, Nn / 1024, rp1, cur1, Nn);
    fill_kernel<<<Ee / 256, 256, 0, stream>>>(src, tgt, Ee, cur1, col1);

    // SAGEConv1
    agg1_kernel<<<8192, 256, 0, stream>>>(xb, rp1, col1, aggb1);
    {
        dim3 g(Nn / 64, H1c / 64);
        gemm_mfma_kernel<INc, H1c><<<g, 256, 0, stream>>>(aggb1, xb, T1l, T1r, b1l, h1);
    }

    // BN1 stats + score + topk(+segscore)
    bnstats_kernel<<<256, 256, 0, stream>>>(h1, Nn, H1c, dsum1, dsq1);
    score_kernel<H1c><<<Nn / 4, 256, 0, stream>>>(h1, dsum1, dsq1, bn1g, bn1b, p1Wrel,
                                                  p1Wroot, r1, root1, Nn);
    topk_kernel<<<Bg, 1024, 0, stream>>>(r1, root1, rp1, col1, p1brel, NPGc, K1c,
                                         perm1, tv1, map1);

    // BN-apply gather (h1 -> h1pb) + count2
    gcount_kernel<<<(N1c * H1c + Ee) / 256, 256, 0, stream>>>(
        h1, perm1, tv1, dsum1, dsq1, bn1g, bn1b, h1pb, src, tgt, map1, wc2);

    // ===== Layer 2 CSR =====
    scan_part_kernel<<<N1c / 1024, 256, 0, stream>>>(wc2, bsum);
    scan_fin_kernel<<<N1c / 1024, 256, 0, stream>>>(wc2, bsum, N1c / 1024, rp2, cur2, N1c);
    fill2_kernel<<<Ee / 256, 256, 0, stream>>>(src, tgt, map1, cur2, col2);

    // SAGEConv2
    agg2_kernel<<<8192, 256, 0, stream>>>(h1pb, rp2, col2, aggb2);
    {
        dim3 g(N1c / 64, H2c / 64);
        gemm_mfma_kernel<H1c, H2c><<<g, 256, 0, stream>>>(aggb2, h1pb, T2l, T2r, b2l, h2);
    }

    // BN2 stats + score + topk(+segscore)
    bnstats_kernel<<<256, 256, 0, stream>>>(h2, N1c, H2c, dsum2, dsq2);
    score_kernel<H2c><<<N1c / 4, 256, 0, stream>>>(h2, dsum2, dsq2, bn2g, bn2b, p2Wrel,
                                                   p2Wroot, r2, root2, N1c);
    topk_kernel<<<Bg, 1024, 0, stream>>>(r2, root2, rp2, col2, p2brel, K1c, K2c,
                                         perm2, tv2, nullptr);

    // Fused BN-apply + tanh-scale + pool, then readout
    {
        dim3 g(Bg, K2c / 64);
        pool_part_kernel<<<g, 256, 0, stream>>>(h2, perm2, tv2, dsum2, dsq2, bn2g, bn2b,
                                                pooled);
    }
    pool_fin_kernel<<<Bg, 256, 0, stream>>>(pooled, Wlin, blin, out);
}

// Round 7
// 362.931 us; speedup vs baseline: 2.5353x; 1.0509x over previous
//
#include <hip/hip_runtime.h>
#include <math.h>

#define Bg   32
#define NPGc 2048
#define Nn   (Bg*NPGc)      // 65536
#define DEGc 8
#define Ee   (Nn*DEGc)      // 524288
#define INc  64
#define H1c  128
#define H2c  256
#define K1c  1024
#define K2c  512
#define N1c  (Bg*K1c)       // 32768
#define N2c  (Bg*K2c)       // 16384
#define EPGc (NPGc*DEGc)    // 16384 edges per graph slab

typedef __attribute__((ext_vector_type(8))) short short8;
typedef __attribute__((ext_vector_type(4))) float f32x4;

__device__ __forceinline__ ushort f2bf(float f) {
    uint u = __float_as_uint(f);
    uint r = (u + 0x7fffu + ((u >> 16) & 1u)) >> 16;
    return (ushort)r;
}
__device__ __forceinline__ float bfhi(uint v) { return __uint_as_float(v & 0xffff0000u); }
__device__ __forceinline__ float bflo(uint v) { return __uint_as_float(v << 16); }
__device__ __forceinline__ uint fkey(float f) {
    uint u = __float_as_uint(f);
    return u ^ ((uint)((int)u >> 31) | 0x80000000u);
}

// ---------------- prep: wt transpose + x->bf16 + count1 + all inits (1 kernel) ----------------
__global__ void prep_kernel(const float* __restrict__ x, const int* __restrict__ tgt,
                            const float* __restrict__ W1l, const float* __restrict__ W1r,
                            const float* __restrict__ W2l, const float* __restrict__ W2r,
                            ushort* __restrict__ T1l, ushort* __restrict__ T1r,
                            ushort* __restrict__ T2l, ushort* __restrict__ T2r,
                            ushort* __restrict__ xb, int* __restrict__ map1,
                            int* __restrict__ wc1, int* __restrict__ wc2,
                            int* __restrict__ dstats, int* __restrict__ pooled) {
    int id = blockIdx.x * blockDim.x + threadIdx.x;
    if (id < 8192) {
        int c = id / 64, k = id % 64;
        T1l[id] = f2bf(W1l[k * 128 + c]);
        T1r[id] = f2bf(W1r[k * 128 + c]);
        return;
    }
    id -= 8192;
    if (id < 32768) {
        int c = id / 128, k = id % 128;
        T2l[id] = f2bf(W2l[k * 256 + c]);
        T2r[id] = f2bf(W2r[k * 256 + c]);
        return;
    }
    id -= 32768;
    if (id < 16384) { ((int4*)map1)[id] = (int4){-1, -1, -1, -1}; return; }
    id -= 16384;
    if (id < 16384) { ((int4*)wc1)[id] = (int4){0, 0, 0, 0}; return; }
    id -= 16384;
    if (id < 8192)  { ((int4*)wc2)[id] = (int4){0, 0, 0, 0}; return; }
    id -= 8192;
    if (id < 384)   { ((int4*)dstats)[id] = (int4){0, 0, 0, 0}; return; }
    id -= 384;
    if (id < 2048)  { ((int4*)pooled)[id] = (int4){0, 0, 0, 0}; return; }
    id -= 2048;
    if (id < Nn * 64 / 4) {  // x -> bf16
        float4 v = ((const float4*)x)[id];
        ushort4 o; o.x = f2bf(v.x); o.y = f2bf(v.y); o.z = f2bf(v.z); o.w = f2bf(v.w);
        ((ushort4*)xb)[id] = o;
        return;
    }
    id -= Nn * 64 / 4;
    if (id < Ee) atomicAdd(&wc1[tgt[id]], 1);
}
#define PREP_TOTAL (8192 + 32768 + 16384 + 16384 + 8192 + 384 + 2048 + Nn*64/4 + Ee)

// ---------------- per-graph scan: rowptr starts within fixed per-graph edge slab ------------
// block g scans its graph's npg counts; base = g*EPGc. Consumers use rp[i] + deg[i].
__global__ void __launch_bounds__(256) scan_graph_kernel(const int* __restrict__ cnt,
                                                         int* __restrict__ rp,
                                                         int* __restrict__ cur, int npg) {
    __shared__ int wsum[4];
    int g = blockIdx.x, tid = threadIdx.x;
    int ept = npg >> 8;         // 8 (layer1) or 4 (layer2)
    int nq = ept >> 2;          // int4 quads per thread
    int base = g * npg + tid * ept;
    int v[8];
    int s = 0;
#pragma unroll
    for (int q = 0; q < 2; q++) {
        if (q < nq) {
            int4 t = *(const int4*)&cnt[base + q * 4];
            v[q * 4 + 0] = t.x; v[q * 4 + 1] = t.y; v[q * 4 + 2] = t.z; v[q * 4 + 3] = t.w;
            s += t.x + t.y + t.z + t.w;
        }
    }
    int lane = tid & 63, wid = tid >> 6;
    int p = s;
    for (int off = 1; off < 64; off <<= 1) {
        int u = __shfl_up(p, off);
        if (lane >= off) p += u;
    }
    if (lane == 63) wsum[wid] = p;
    __syncthreads();
    int woff = 0;
    for (int k = 0; k < wid; k++) woff += wsum[k];
    int o = (p - s) + woff + g * EPGc;
#pragma unroll
    for (int q = 0; q < 2; q++) {
        if (q < nq) {
            int4 w;
            w.x = o; o += v[q * 4 + 0];
            w.y = o; o += v[q * 4 + 1];
            w.z = o; o += v[q * 4 + 2];
            w.w = o; o += v[q * 4 + 3];
            *(int4*)&rp[base + q * 4] = w;
            *(int4*)&cur[base + q * 4] = w;
        }
    }
}

__global__ void fill_kernel(const int* __restrict__ src, const int* __restrict__ tgt, int ne,
                            int* __restrict__ cur, int* __restrict__ col) {
    int e = blockIdx.x * blockDim.x + threadIdx.x;
    if (e >= ne) return;
    int p = atomicAdd(&cur[tgt[e]], 1);
    col[p] = src[e];
}

__global__ void fill2_kernel(const int* __restrict__ src, const int* __restrict__ tgt,
                             const int* __restrict__ map, int* __restrict__ cur,
                             int* __restrict__ col) {
    int e = blockIdx.x * blockDim.x + threadIdx.x;
    if (e >= Ee) return;
    int ns = map[src[e]];
    int nt = map[tgt[e]];
    if (ns >= 0 && nt >= 0) {
        int p = atomicAdd(&cur[nt], 1);
        col[p] = ns;
    }
}

// ---------------- mean aggregation: 16B/lane gathers, bf16 in/out, XCD-swizzled -------------
__device__ __forceinline__ void acc8(float* a, uint4 v) {
    a[0] += bflo(v.x); a[1] += bfhi(v.x);
    a[2] += bflo(v.y); a[3] += bfhi(v.y);
    a[4] += bflo(v.z); a[5] += bfhi(v.z);
    a[6] += bflo(v.w); a[7] += bfhi(v.w);
}
__device__ __forceinline__ uint4 pack8(const float* a, float inv) {
    uint4 o;
    o.x = (uint)f2bf(a[0] * inv) | ((uint)f2bf(a[1] * inv) << 16);
    o.y = (uint)f2bf(a[2] * inv) | ((uint)f2bf(a[3] * inv) << 16);
    o.z = (uint)f2bf(a[4] * inv) | ((uint)f2bf(a[5] * inv) << 16);
    o.w = (uint)f2bf(a[6] * inv) | ((uint)f2bf(a[7] * inv) << 16);
    return o;
}

// layer1: C=64, 8 lanes/node x 8ch. 2048 blocks; XCD x owns graphs [4x,4x+4).
__global__ void agg1_kernel(const ushort* __restrict__ xb, const int* __restrict__ rp,
                            const int* __restrict__ deg, const int* __restrict__ col,
                            ushort* __restrict__ out) {
    int b = blockIdx.x;
    int w = ((b & 7) << 8) + (b >> 3);
    int gid = w * 256 + threadIdx.x;
    int node = gid >> 3, ln = gid & 7;
    int bg = rp[node], dg = deg[node];
    float a[8] = {0.f, 0.f, 0.f, 0.f, 0.f, 0.f, 0.f, 0.f};
    for (int i = bg; i < bg + dg; i++)
        acc8(a, *(const uint4*)&xb[((size_t)col[i] << 6) + ln * 8]);
    int c = dg < 1 ? 1 : dg;
    *(uint4*)&out[((size_t)node << 6) + ln * 8] = pack8(a, 1.f / (float)c);
}

// layer2: C=128, 16 lanes/node x 8ch. 2048 blocks.
__global__ void agg2_kernel(const ushort* __restrict__ xb, const int* __restrict__ rp,
                            const int* __restrict__ deg, const int* __restrict__ col,
                            ushort* __restrict__ out) {
    int b = blockIdx.x;
    int w = ((b & 7) << 8) + (b >> 3);
    int gid = w * 256 + threadIdx.x;
    int node = gid >> 4, ln = gid & 15;
    int bg = rp[node], dg = deg[node];
    float a[8] = {0.f, 0.f, 0.f, 0.f, 0.f, 0.f, 0.f, 0.f};
    for (int i = bg; i < bg + dg; i++)
        acc8(a, *(const uint4*)&xb[((size_t)col[i] << 7) + ln * 8]);
    int c = dg < 1 ? 1 : dg;
    *(uint4*)&out[((size_t)node << 7) + ln * 8] = pack8(a, 1.f / (float)c);
}

// ---------------- MFMA GEMM: 128x64 tile, BK=64; out = Aagg@Wl + Ax@Wr + bias ----------------
template<int K, int COUT>
__global__ __launch_bounds__(256) void gemm_mfma_kernel(
        const ushort* __restrict__ Aagg, const ushort* __restrict__ Ax,
        const ushort* __restrict__ Wtl, const ushort* __restrict__ Wtr,
        const float* __restrict__ bias, float* __restrict__ out) {
    __shared__ ushort As[2][128][72];   // 36.9 KB (pad 72: 2-way LDS = free)
    __shared__ ushort Bs[2][64][72];    // 18.4 KB
    int m0 = blockIdx.x * 128;
    int c0 = blockIdx.y * 64;
    int lane = threadIdx.x & 63;
    int wid = threadIdx.x >> 6;
    int wr = (wid & 1) * 64, wc = (wid >> 1) * 32;
    int l16 = lane & 15, quad = lane >> 4;

    f32x4 acc[4][2];
#pragma unroll
    for (int a = 0; a < 4; a++)
#pragma unroll
        for (int b = 0; b < 2; b++) acc[a][b] = (f32x4){0.f, 0.f, 0.f, 0.f};

    for (int kk0 = 0; kk0 < K; kk0 += 64) {
        for (int idx = threadIdx.x; idx < 1024; idx += 256) {
            int r = idx >> 3, ck = (idx & 7) * 8;
            *(uint4*)&As[0][r][ck] = *(const uint4*)&Aagg[(size_t)(m0 + r) * K + kk0 + ck];
            *(uint4*)&As[1][r][ck] = *(const uint4*)&Ax[(size_t)(m0 + r) * K + kk0 + ck];
        }
        for (int idx = threadIdx.x; idx < 512; idx += 256) {
            int r = idx >> 3, ck = (idx & 7) * 8;
            *(uint4*)&Bs[0][r][ck] = *(const uint4*)&Wtl[(size_t)(c0 + r) * K + kk0 + ck];
            *(uint4*)&Bs[1][r][ck] = *(const uint4*)&Wtr[(size_t)(c0 + r) * K + kk0 + ck];
        }
        __syncthreads();
#pragma unroll
        for (int kk = 0; kk < 64; kk += 32) {
            short8 a[2][4], b[2][2];
#pragma unroll
            for (int s = 0; s < 2; s++)
#pragma unroll
                for (int mt = 0; mt < 4; mt++)
                    a[s][mt] = *(const short8*)&As[s][wr + mt * 16 + l16][kk + quad * 8];
#pragma unroll
            for (int s = 0; s < 2; s++)
#pragma unroll
                for (int nt = 0; nt < 2; nt++)
                    b[s][nt] = *(const short8*)&Bs[s][wc + nt * 16 + l16][kk + quad * 8];
#pragma unroll
            for (int mt = 0; mt < 4; mt++)
#pragma unroll
                for (int nt = 0; nt < 2; nt++) {
                    acc[mt][nt] = __builtin_amdgcn_mfma_f32_16x16x32_bf16(
                        a[0][mt], b[0][nt], acc[mt][nt], 0, 0, 0);
                    acc[mt][nt] = __builtin_amdgcn_mfma_f32_16x16x32_bf16(
                        a[1][mt], b[1][nt], acc[mt][nt], 0, 0, 0);
                }
        }
        __syncthreads();
    }
#pragma unroll
    for (int mt = 0; mt < 4; mt++)
#pragma unroll
        for (int nt = 0; nt < 2; nt++) {
            int col = c0 + wc + nt * 16 + l16;
            float bv = bias[col];
#pragma unroll
            for (int r = 0; r < 4; r++) {
                int row = m0 + wr + mt * 16 + quad * 4 + r;
                out[(size_t)row * COUT + col] = acc[mt][nt][r] + bv;
            }
        }
}

// ---------------- BatchNorm stats on RAW h (f64 atomics) ----------------
__global__ void __launch_bounds__(256) bnstats_kernel(const float* __restrict__ h, int n, int C,
                                                      double* __restrict__ dsum,
                                                      double* __restrict__ dsq) {
    __shared__ float s1[256], s2[256];
    int c = threadIdx.x & (C - 1);
    int rpg = 256 / C;
    int sub = threadIdx.x / C;
    float s = 0.f, sq = 0.f;
    for (int row = blockIdx.x * rpg + sub; row < n; row += gridDim.x * rpg) {
        float v = h[(size_t)row * C + c];
        s += v; sq += v * v;
    }
    s1[threadIdx.x] = s; s2[threadIdx.x] = sq;
    __syncthreads();
    if (C == 128 && threadIdx.x < 128) {
        s1[threadIdx.x] += s1[threadIdx.x + 128];
        s2[threadIdx.x] += s2[threadIdx.x + 128];
    }
    __syncthreads();
    if ((int)threadIdx.x < C) {
        atomicAdd(&dsum[threadIdx.x], (double)s1[threadIdx.x]);
        atomicAdd(&dsq[threadIdx.x], (double)s2[threadIdx.x]);
    }
}

// ---------------- score dots from RAW h; scale/shift computed in-block ----------------
template<int C>
__global__ __launch_bounds__(256) void score_kernel(const float* __restrict__ h,
                                                    const double* __restrict__ dsum,
                                                    const double* __restrict__ dsq,
                                                    const float* __restrict__ g,
                                                    const float* __restrict__ b,
                                                    const float* __restrict__ wrel,
                                                    const float* __restrict__ wroot,
                                                    float* __restrict__ r,
                                                    float* __restrict__ root, int n) {
    __shared__ float sc[C], sh[C], wrl[C], wrt[C];
    if ((int)threadIdx.x < C) {
        int c = threadIdx.x;
        double m = dsum[c] / (double)n;
        double var = dsq[c] / (double)n - m * m;
        float s = g[c] * (float)(1.0 / sqrt(var + 1e-5));
        sc[c] = s; sh[c] = b[c] - (float)m * s;
        wrl[c] = wrel[c]; wrt[c] = wroot[c];
    }
    __syncthreads();
    int gid = blockIdx.x * 256 + threadIdx.x;
    int node = gid >> 6, lane = gid & 63;
    float rr = 0.f, rt = 0.f;
    for (int c = lane; c < C; c += 64) {
        float v = fmaxf(h[(size_t)node * C + c] * sc[c] + sh[c], 0.f);
        rr += v * wrl[c];
        rt += v * wrt[c];
    }
    for (int off = 32; off; off >>= 1) {
        rr += __shfl_down(rr, off);
        rt += __shfl_down(rt, off);
    }
    if (lane == 0) { r[node] = rr; root[node] = rt; }
}

// ---------------- top-k: exact 32-bit radix select, 1024 thr, wave-scan ----------------
__global__ void __launch_bounds__(1024) topk_kernel(const float* __restrict__ r,
                                                    const float* __restrict__ root,
                                                    const int* __restrict__ rp,
                                                    const int* __restrict__ deg,
                                                    const int* __restrict__ col,
                                                    const float* __restrict__ brel,
                                                    int npg, int k, int* __restrict__ perm,
                                                    float* __restrict__ tval,
                                                    int* __restrict__ map) {
    __shared__ float svals[2048];
    __shared__ uint hist[257];
    __shared__ uint wsum[16];
    __shared__ uint s_b, s_rem;
    int g = blockIdx.x;
    int tid = threadIdx.x;
    int lane = tid & 63, wid = tid >> 6;
    float bv = brel[0];
    for (int i = tid; i < npg; i += 1024) {
        int gi = g * npg + i;
        float acc = bv + root[gi];
        int e0 = rp[gi], e1 = e0 + deg[gi];
        for (int e = e0; e < e1; e++) acc += r[col[e]];
        svals[i] = acc;
    }
    if (tid == 256) hist[256] = 0;
    if (tid < 256) hist[tid] = 0;
    __syncthreads();

    uint prefix = 0, himask = 0, rem = (uint)k;
    for (int shift = 24; shift >= 0; shift -= 8) {
        for (int i = tid; i < npg; i += 1024) {
            uint kk = fkey(svals[i]);
            if ((kk & himask) == prefix) atomicAdd(&hist[(kk >> shift) & 255], 1);
        }
        __syncthreads();
        if (tid < 64) {  // wave 0: suffix-sum of 256 bins, 4/lane, no barriers
            int L = tid;
            uint h0 = hist[4 * L], h1 = hist[4 * L + 1], h2 = hist[4 * L + 2],
                 h3 = hist[4 * L + 3];
            uint s3 = h3, s2 = h2 + s3, s1 = h1 + s2, s0 = h0 + s1;
            uint v = s0;
            for (int off = 1; off < 64; off <<= 1) {
                uint u = __shfl_down(v, off);
                if (L + off < 64) v += u;
            }
            uint above = v - s0;
            hist[4 * L] = s0 + above;
            hist[4 * L + 1] = s1 + above;
            hist[4 * L + 2] = s2 + above;
            hist[4 * L + 3] = s3 + above;
        }
        __syncthreads();
        if (tid < 256) {
            uint sb = hist[tid], sb1 = hist[tid + 1];
            if (sb >= rem && sb1 < rem) { s_b = (uint)tid; s_rem = rem - sb1; }
        }
        __syncthreads();
        prefix |= (s_b << shift);
        rem = s_rem;
        himask |= (0xFFu << shift);
        if (tid < 256) hist[tid] = 0;
        __syncthreads();
    }
    uint thr = prefix;
    uint m = rem;

    int nchunk = npg >> 10;
    uint gcnt = 0, ecnt = 0, gflags = 0, eflags = 0;
    for (int j = 0; j < nchunk; j++) {
        uint kk = fkey(svals[tid + (j << 10)]);
        if (kk > thr) { gflags |= 1u << j; gcnt++; }
        else if (kk == thr) { eflags |= 1u << j; ecnt++; }
    }
    uint key = (gcnt << 16) | ecnt;
    uint v = key;
    for (int off = 1; off < 64; off <<= 1) {
        uint u = __shfl_up(v, off);
        if (lane >= off) v += u;
    }
    if (lane == 63) wsum[wid] = v;
    __syncthreads();
    if (tid < 16) {
        uint w0 = wsum[tid], w = w0;
        for (int off = 1; off < 16; off <<= 1) {
            uint u = __shfl_up(w, off);
            if ((int)tid >= off) w += u;
        }
        wsum[tid] = w - w0;
    }
    __syncthreads();
    uint excl = (v - key) + wsum[wid];
    uint gbase = excl >> 16, ebase = excl & 0xFFFFu;
    for (int j = 0; j < nchunk; j++) {
        bool gt = (gflags >> j) & 1u;
        bool eq = (eflags >> j) & 1u;
        if (gt || (eq && ebase < m)) {
            uint pos = gbase + min(ebase, m);
            int i = tid + (j << 10);
            int gi = g * npg + i;
            int o = g * k + (int)pos;
            perm[o] = gi;
            tval[o] = tanhf(svals[i]);
            if (map) map[gi] = o;
        }
        gbase += gt ? 1u : 0u;
        ebase += eq ? 1u : 0u;
    }
}

// ---------------- fused: BN-apply gather (layer1) + count2 ----------------
__global__ void __launch_bounds__(256) gcount_kernel(
        const float* __restrict__ h1, const int* __restrict__ perm1,
        const float* __restrict__ tv1, const double* __restrict__ dsum,
        const double* __restrict__ dsq, const float* __restrict__ g,
        const float* __restrict__ b, ushort* __restrict__ h1pb,
        const int* __restrict__ src, const int* __restrict__ tgt,
        const int* __restrict__ map, int* __restrict__ wc2) {
    int blockBase = blockIdx.x * 256;
    if (blockBase < N1c * H1c) {
        __shared__ float sc[128], sh[128];
        if (threadIdx.x < 128) {
            int c = threadIdx.x;
            double m = dsum[c] / (double)Nn;
            double var = dsq[c] / (double)Nn - m * m;
            float s = g[c] * (float)(1.0 / sqrt(var + 1e-5));
            sc[c] = s; sh[c] = b[c] - (float)m * s;
        }
        __syncthreads();
        int t = blockBase + threadIdx.x;
        int m = t >> 7, c = t & 127;
        float v = fmaxf(h1[((size_t)perm1[m] << 7) + c] * sc[c] + sh[c], 0.f);
        h1pb[t] = f2bf(v * tv1[m]);
    } else {
        int e = blockBase + threadIdx.x - N1c * H1c;
        if (e >= Ee) return;
        int ns = map[src[e]];
        int nt = map[tgt[e]];
        if (ns >= 0 && nt >= 0) atomicAdd(&wc2[nt], 1);
    }
}

// ---------------- fused: layer2 BN-apply + tanh-scale + pooled accumulate ----------------
__global__ void __launch_bounds__(256) pool_part_kernel(const float* __restrict__ h2,
                                                        const int* __restrict__ perm2,
                                                        const float* __restrict__ tv2,
                                                        const double* __restrict__ dsum,
                                                        const double* __restrict__ dsq,
                                                        const float* __restrict__ g,
                                                        const float* __restrict__ b,
                                                        float* __restrict__ pooled) {
    __shared__ float sc[256], sh[256];
    {
        int c = threadIdx.x;
        double m = dsum[c] / (double)N1c;
        double var = dsq[c] / (double)N1c - m * m;
        float s = g[c] * (float)(1.0 / sqrt(var + 1e-5));
        sc[c] = s; sh[c] = b[c] - (float)m * s;
    }
    __syncthreads();
    int gg = blockIdx.x, p = blockIdx.y, c = threadIdx.x;
    float s = 0.f;
    for (int j = 0; j < 64; j++) {
        int m = gg * K2c + p * 64 + j;
        int row = perm2[m];
        float v = fmaxf(h2[((size_t)row << 8) + c] * sc[c] + sh[c], 0.f);
        s += v * tv2[m];
    }
    atomicAdd(&pooled[gg * H2c + c], s);
}

__global__ void __launch_bounds__(256) pool_fin_kernel(const float* __restrict__ pooled,
                                                       const float* __restrict__ Wlin,
                                                       const float* __restrict__ blin,
                                                       float* __restrict__ out) {
    __shared__ float p0s[256], p1s[256];
    int g = blockIdx.x, c = threadIdx.x;
    float s = fmaxf(pooled[g * 256 + c] * (1.f / (float)K2c), 0.f);
    p0s[c] = s * Wlin[c * 2 + 0];
    p1s[c] = s * Wlin[c * 2 + 1];
    __syncthreads();
    for (int off = 128; off; off >>= 1) {
        if (c < off) { p0s[c] += p0s[c + off]; p1s[c] += p1s[c + off]; }
        __syncthreads();
    }
    if (c == 0) {
        float o0 = p0s[0] + blin[0], o1 = p1s[0] + blin[1];
        float m = fmaxf(o0, o1);
        float e0 = expf(o0 - m), e1 = expf(o1 - m);
        float inv = 1.f / (e0 + e1);
        out[g * 2 + 0] = e0 * inv;
        out[g * 2 + 1] = e1 * inv;
    }
}

extern "C" void kernel_launch(void* const* d_in, const int* in_sizes, int n_in,
                              void* d_out, int out_size, void* d_ws, size_t ws_size,
                              hipStream_t stream) {
    const float* x      = (const float*)d_in[0];
    const int*   ei     = (const int*)d_in[1];
    const int*   src    = ei;
    const int*   tgt    = ei + Ee;
    const float* W1l    = (const float*)d_in[3];
    const float* b1l    = (const float*)d_in[4];
    const float* W1r    = (const float*)d_in[5];
    const float* bn1g   = (const float*)d_in[6];
    const float* bn1b   = (const float*)d_in[7];
    const float* p1Wrel = (const float*)d_in[8];
    const float* p1brel = (const float*)d_in[9];
    const float* p1Wroot= (const float*)d_in[10];
    const float* W2l    = (const float*)d_in[11];
    const float* b2l    = (const float*)d_in[12];
    const float* W2r    = (const float*)d_in[13];
    const float* bn2g   = (const float*)d_in[14];
    const float* bn2b   = (const float*)d_in[15];
    const float* p2Wrel = (const float*)d_in[16];
    const float* p2brel = (const float*)d_in[17];
    const float* p2Wroot= (const float*)d_in[18];
    const float* Wlin   = (const float*)d_in[19];
    const float* blin   = (const float*)d_in[20];
    float* out = (float*)d_out;
    char* ws = (char*)d_ws;

    size_t o = 0;
    auto A = [&](size_t b) { size_t r = o; o += (b + 255) & ~(size_t)255; return r; };
    size_t oBIG1 = A((size_t)Nn * H1c * 4);        // h1 / h2 f32
    size_t oBIG2 = A((size_t)Nn * INc * 4);        // xb + aggb1 bf16
    size_t oPB   = A((size_t)N1c * H1c * 4);       // h1pb + aggb2 bf16
    size_t oCol1 = A((size_t)Ee * 4);
    size_t oCol2 = A((size_t)Ee * 4);
    size_t oRp1  = A((size_t)(Nn + 1) * 4);
    size_t oWc1  = A((size_t)Nn * 4);
    size_t oCur1 = A((size_t)Nn * 4);
    size_t oMap  = A((size_t)Nn * 4);
    size_t oR1   = A((size_t)Nn * 4);
    size_t oRoot1= A((size_t)Nn * 4);
    size_t oPerm1= A((size_t)N1c * 4);
    size_t oTv1  = A((size_t)N1c * 4);
    size_t oRp2  = A((size_t)(N1c + 1) * 4);
    size_t oWc2  = A((size_t)N1c * 4);
    size_t oCur2 = A((size_t)N1c * 4);
    size_t oR2   = A((size_t)N1c * 4);
    size_t oRoot2= A((size_t)N1c * 4);
    size_t oPerm2= A((size_t)N2c * 4);
    size_t oTv2  = A((size_t)N2c * 4);
    size_t oDst  = A(768 * 8);
    size_t oWt1l = A(8192 * 2);
    size_t oWt1r = A(8192 * 2);
    size_t oWt2l = A(32768 * 2);
    size_t oWt2r = A(32768 * 2);
    size_t oPool = A(Bg * H2c * 4);
    (void)ws_size; (void)in_sizes; (void)n_in; (void)out_size;

    float* h1    = (float*)(ws + oBIG1);
    float* h2    = (float*)(ws + oBIG1);
    ushort* xb   = (ushort*)(ws + oBIG2);
    ushort* aggb1= (ushort*)(ws + oBIG2 + (size_t)Nn * 64 * 2);
    ushort* h1pb = (ushort*)(ws + oPB);
    ushort* aggb2= (ushort*)(ws + oPB + (size_t)N1c * 128 * 2);
    int* col1    = (int*)(ws + oCol1);
    int* col2    = (int*)(ws + oCol2);
    int* rp1     = (int*)(ws + oRp1);
    int* wc1     = (int*)(ws + oWc1);
    int* cur1    = (int*)(ws + oCur1);
    int* map1    = (int*)(ws + oMap);
    float* r1    = (float*)(ws + oR1);
    float* root1 = (float*)(ws + oRoot1);
    int* perm1   = (int*)(ws + oPerm1);
    float* tv1   = (float*)(ws + oTv1);
    int* rp2     = (int*)(ws + oRp2);
    int* wc2     = (int*)(ws + oWc2);
    int* cur2    = (int*)(ws + oCur2);
    float* r2    = (float*)(ws + oR2);
    float* root2 = (float*)(ws + oRoot2);
    int* perm2   = (int*)(ws + oPerm2);
    float* tv2   = (float*)(ws + oTv2);
    double* dsum1= (double*)(ws + oDst);
    double* dsq1 = dsum1 + 128;
    double* dsum2= dsum1 + 256;
    double* dsq2 = dsum1 + 512;
    ushort* T1l  = (ushort*)(ws + oWt1l);
    ushort* T1r  = (ushort*)(ws + oWt1r);
    ushort* T2l  = (ushort*)(ws + oWt2l);
    ushort* T2r  = (ushort*)(ws + oWt2r);
    float* pooled= (float*)(ws + oPool);

    // 1. prep (wt transpose + inits + xconv + count1)
    prep_kernel<<<(PREP_TOTAL + 255) / 256, 256, 0, stream>>>(
        x, tgt, W1l, W1r, W2l, W2r, T1l, T1r, T2l, T2r, xb, map1, wc1, wc2,
        (int*)dsum1, (int*)pooled);

    // ===== Layer 1 CSR (per-graph scan) =====
    scan_graph_kernel<<<Bg, 256, 0, stream>>>(wc1, rp1, cur1, NPGc);
    fill_kernel<<<Ee / 256, 256, 0, stream>>>(src, tgt, Ee, cur1, col1);

    // SAGEConv1
    agg1_kernel<<<2048, 256, 0, stream>>>(xb, rp1, wc1, col1, aggb1);
    {
        dim3 g(Nn / 128, H1c / 64);
        gemm_mfma_kernel<INc, H1c><<<g, 256, 0, stream>>>(aggb1, xb, T1l, T1r, b1l, h1);
    }

    // BN1 stats + score + topk(+segscore)
    bnstats_kernel<<<256, 256, 0, stream>>>(h1, Nn, H1c, dsum1, dsq1);
    score_kernel<H1c><<<Nn / 4, 256, 0, stream>>>(h1, dsum1, dsq1, bn1g, bn1b, p1Wrel,
                                                  p1Wroot, r1, root1, Nn);
    topk_kernel<<<Bg, 1024, 0, stream>>>(r1, root1, rp1, wc1, col1, p1brel, NPGc, K1c,
                                         perm1, tv1, map1);

    // BN-apply gather (h1 -> h1pb) + count2
    gcount_kernel<<<(N1c * H1c + Ee) / 256, 256, 0, stream>>>(
        h1, perm1, tv1, dsum1, dsq1, bn1g, bn1b, h1pb, src, tgt, map1, wc2);

    // ===== Layer 2 CSR (per-graph scan over padded slabs) =====
    scan_graph_kernel<<<Bg, 256, 0, stream>>>(wc2, rp2, cur2, K1c);
    fill2_kernel<<<Ee / 256, 256, 0, stream>>>(src, tgt, map1, cur2, col2);

    // SAGEConv2
    agg2_kernel<<<2048, 256, 0, stream>>>(h1pb, rp2, wc2, col2, aggb2);
    {
        dim3 g(N1c / 128, H2c / 64);
        gemm_mfma_kernel<H1c, H2c><<<g, 256, 0, stream>>>(aggb2, h1pb, T2l, T2r, b2l, h2);
    }

    // BN2 stats + score + topk(+segscore)
    bnstats_kernel<<<256, 256, 0, stream>>>(h2, N1c, H2c, dsum2, dsq2);
    score_kernel<H2c><<<N1c / 4, 256, 0, stream>>>(h2, dsum2, dsq2, bn2g, bn2b, p2Wrel,
                                                   p2Wroot, r2, root2, N1c);
    topk_kernel<<<Bg, 1024, 0, stream>>>(r2, root2, rp2, wc2, col2, p2brel, K1c, K2c,
                                         perm2, tv2, nullptr);

    // Fused BN-apply + tanh-scale + pool, then readout
    {
        dim3 g(Bg, K2c / 64);
        pool_part_kernel<<<g, 256, 0, stream>>>(h2, perm2, tv2, dsum2, dsq2, bn2g, bn2b,
                                                pooled);
    }
    pool_fin_kernel<<<Bg, 256, 0, stream>>>(pooled, Wlin, blin, out);
}

// Round 8
// 289.021 us; speedup vs baseline: 3.1837x; 1.2557x over previous
//
#include <hip/hip_runtime.h>
#include <math.h>

#define Bg   32
#define NPGc 2048
#define Nn   (Bg*NPGc)      // 65536
#define DEGc 8
#define Ee   (Nn*DEGc)      // 524288
#define INc  64
#define H1c  128
#define H2c  256
#define K1c  1024
#define K2c  512
#define N1c  (Bg*K1c)       // 32768
#define N2c  (Bg*K2c)       // 16384
#define SLAB 64             // fixed CSR slab per node (max in-degree headroom)

typedef __attribute__((ext_vector_type(8))) short short8;
typedef __attribute__((ext_vector_type(4))) float f32x4;

__device__ __forceinline__ ushort f2bf(float f) {
    uint u = __float_as_uint(f);
    uint r = (u + 0x7fffu + ((u >> 16) & 1u)) >> 16;
    return (ushort)r;
}
__device__ __forceinline__ float bfhi(uint v) { return __uint_as_float(v & 0xffff0000u); }
__device__ __forceinline__ float bflo(uint v) { return __uint_as_float(v << 16); }
__device__ __forceinline__ uint fkey(float f) {
    uint u = __float_as_uint(f);
    return u ^ ((uint)((int)u >> 31) | 0x80000000u);
}

// ---------------- prep: wt transpose + x->bf16 + all inits (1 kernel, no edge pass) ---------
__global__ void prep_kernel(const float* __restrict__ x,
                            const float* __restrict__ W1l, const float* __restrict__ W1r,
                            const float* __restrict__ W2l, const float* __restrict__ W2r,
                            ushort* __restrict__ T1l, ushort* __restrict__ T1r,
                            ushort* __restrict__ T2l, ushort* __restrict__ T2r,
                            ushort* __restrict__ xb, int* __restrict__ map1,
                            int* __restrict__ wc1, int* __restrict__ wc2,
                            int* __restrict__ dstats, int* __restrict__ pooled) {
    int id = blockIdx.x * blockDim.x + threadIdx.x;
    if (id < 8192) {
        int c = id / 64, k = id % 64;
        T1l[id] = f2bf(W1l[k * 128 + c]);
        T1r[id] = f2bf(W1r[k * 128 + c]);
        return;
    }
    id -= 8192;
    if (id < 32768) {
        int c = id / 128, k = id % 128;
        T2l[id] = f2bf(W2l[k * 256 + c]);
        T2r[id] = f2bf(W2r[k * 256 + c]);
        return;
    }
    id -= 32768;
    if (id < 16384) { ((int4*)map1)[id] = (int4){-1, -1, -1, -1}; return; }
    id -= 16384;
    if (id < 16384) { ((int4*)wc1)[id] = (int4){0, 0, 0, 0}; return; }
    id -= 16384;
    if (id < 8192)  { ((int4*)wc2)[id] = (int4){0, 0, 0, 0}; return; }
    id -= 8192;
    if (id < 384)   { ((int4*)dstats)[id] = (int4){0, 0, 0, 0}; return; }
    id -= 384;
    if (id < 2048)  { ((int4*)pooled)[id] = (int4){0, 0, 0, 0}; return; }
    id -= 2048;
    if (id < Nn * 64 / 4) {  // x -> bf16
        float4 v = ((const float4*)x)[id];
        ushort4 o; o.x = f2bf(v.x); o.y = f2bf(v.y); o.z = f2bf(v.z); o.w = f2bf(v.w);
        ((ushort4*)xb)[id] = o;
    }
}
#define PREP_TOTAL (8192 + 32768 + 16384 + 16384 + 8192 + 384 + 2048 + Nn*64/4)

// ---------------- self-counting fills into fixed slabs (wc = cursor -> degree) --------------
__global__ void fill1_kernel(const int* __restrict__ src, const int* __restrict__ tgt,
                             int* __restrict__ wc1, int* __restrict__ col1) {
    int e = blockIdx.x * blockDim.x + threadIdx.x;
    if (e >= Ee) return;
    int t = tgt[e];
    int p = atomicAdd(&wc1[t], 1);
    col1[t * SLAB + p] = src[e];
}

// ---------------- mean aggregation: 16B/lane gathers, bf16 in/out, XCD-swizzled -------------
__device__ __forceinline__ void acc8(float* a, uint4 v) {
    a[0] += bflo(v.x); a[1] += bfhi(v.x);
    a[2] += bflo(v.y); a[3] += bfhi(v.y);
    a[4] += bflo(v.z); a[5] += bfhi(v.z);
    a[6] += bflo(v.w); a[7] += bfhi(v.w);
}
__device__ __forceinline__ uint4 pack8(const float* a, float inv) {
    uint4 o;
    o.x = (uint)f2bf(a[0] * inv) | ((uint)f2bf(a[1] * inv) << 16);
    o.y = (uint)f2bf(a[2] * inv) | ((uint)f2bf(a[3] * inv) << 16);
    o.z = (uint)f2bf(a[4] * inv) | ((uint)f2bf(a[5] * inv) << 16);
    o.w = (uint)f2bf(a[6] * inv) | ((uint)f2bf(a[7] * inv) << 16);
    return o;
}

// layer1: C=64, 8 lanes/node x 8ch. 2048 blocks; XCD x owns graphs [4x,4x+4).
__global__ void agg1_kernel(const ushort* __restrict__ xb, const int* __restrict__ deg,
                            const int* __restrict__ col, ushort* __restrict__ out) {
    int b = blockIdx.x;
    int w = ((b & 7) << 8) + (b >> 3);
    int gid = w * 256 + threadIdx.x;
    int node = gid >> 3, ln = gid & 7;
    int bg = node * SLAB, dg = deg[node];
    float a[8] = {0.f, 0.f, 0.f, 0.f, 0.f, 0.f, 0.f, 0.f};
    for (int i = bg; i < bg + dg; i++)
        acc8(a, *(const uint4*)&xb[((size_t)col[i] << 6) + ln * 8]);
    int c = dg < 1 ? 1 : dg;
    *(uint4*)&out[((size_t)node << 6) + ln * 8] = pack8(a, 1.f / (float)c);
}

// layer2: C=128, 16 lanes/node x 8ch. 2048 blocks.
__global__ void agg2_kernel(const ushort* __restrict__ xb, const int* __restrict__ deg,
                            const int* __restrict__ col, ushort* __restrict__ out) {
    int b = blockIdx.x;
    int w = ((b & 7) << 8) + (b >> 3);
    int gid = w * 256 + threadIdx.x;
    int node = gid >> 4, ln = gid & 15;
    int bg = node * SLAB, dg = deg[node];
    float a[8] = {0.f, 0.f, 0.f, 0.f, 0.f, 0.f, 0.f, 0.f};
    for (int i = bg; i < bg + dg; i++)
        acc8(a, *(const uint4*)&xb[((size_t)col[i] << 7) + ln * 8]);
    int c = dg < 1 ? 1 : dg;
    *(uint4*)&out[((size_t)node << 7) + ln * 8] = pack8(a, 1.f / (float)c);
}

// ------- MFMA GEMM 128x64 tile + fused per-channel BN-stat partials (f64 atomics) -----------
template<int K, int COUT>
__global__ __launch_bounds__(256) void gemm_mfma_kernel(
        const ushort* __restrict__ Aagg, const ushort* __restrict__ Ax,
        const ushort* __restrict__ Wtl, const ushort* __restrict__ Wtr,
        const float* __restrict__ bias, float* __restrict__ out,
        double* __restrict__ dsum, double* __restrict__ dsq) {
    __shared__ ushort As[2][128][72];
    __shared__ ushort Bs[2][64][72];
    __shared__ float bsumS[2][64], bsqS[2][64];
    int m0 = blockIdx.x * 128;
    int c0 = blockIdx.y * 64;
    int lane = threadIdx.x & 63;
    int wid = threadIdx.x >> 6;
    int wr = (wid & 1) * 64, wc = (wid >> 1) * 32;
    int l16 = lane & 15, quad = lane >> 4;

    f32x4 acc[4][2];
#pragma unroll
    for (int a = 0; a < 4; a++)
#pragma unroll
        for (int b = 0; b < 2; b++) acc[a][b] = (f32x4){0.f, 0.f, 0.f, 0.f};

    for (int kk0 = 0; kk0 < K; kk0 += 64) {
        for (int idx = threadIdx.x; idx < 1024; idx += 256) {
            int r = idx >> 3, ck = (idx & 7) * 8;
            *(uint4*)&As[0][r][ck] = *(const uint4*)&Aagg[(size_t)(m0 + r) * K + kk0 + ck];
            *(uint4*)&As[1][r][ck] = *(const uint4*)&Ax[(size_t)(m0 + r) * K + kk0 + ck];
        }
        for (int idx = threadIdx.x; idx < 512; idx += 256) {
            int r = idx >> 3, ck = (idx & 7) * 8;
            *(uint4*)&Bs[0][r][ck] = *(const uint4*)&Wtl[(size_t)(c0 + r) * K + kk0 + ck];
            *(uint4*)&Bs[1][r][ck] = *(const uint4*)&Wtr[(size_t)(c0 + r) * K + kk0 + ck];
        }
        __syncthreads();
#pragma unroll
        for (int kk = 0; kk < 64; kk += 32) {
            short8 a[2][4], b[2][2];
#pragma unroll
            for (int s = 0; s < 2; s++)
#pragma unroll
                for (int mt = 0; mt < 4; mt++)
                    a[s][mt] = *(const short8*)&As[s][wr + mt * 16 + l16][kk + quad * 8];
#pragma unroll
            for (int s = 0; s < 2; s++)
#pragma unroll
                for (int nt = 0; nt < 2; nt++)
                    b[s][nt] = *(const short8*)&Bs[s][wc + nt * 16 + l16][kk + quad * 8];
#pragma unroll
            for (int mt = 0; mt < 4; mt++)
#pragma unroll
                for (int nt = 0; nt < 2; nt++) {
                    acc[mt][nt] = __builtin_amdgcn_mfma_f32_16x16x32_bf16(
                        a[0][mt], b[0][nt], acc[mt][nt], 0, 0, 0);
                    acc[mt][nt] = __builtin_amdgcn_mfma_f32_16x16x32_bf16(
                        a[1][mt], b[1][nt], acc[mt][nt], 0, 0, 0);
                }
        }
        __syncthreads();
    }
    // epilogue + per-column partial stats
    float s[2] = {0.f, 0.f}, sq[2] = {0.f, 0.f};
#pragma unroll
    for (int nt = 0; nt < 2; nt++) {
        int col = c0 + wc + nt * 16 + l16;
        float bv = bias[col];
#pragma unroll
        for (int mt = 0; mt < 4; mt++)
#pragma unroll
            for (int r = 0; r < 4; r++) {
                int row = m0 + wr + mt * 16 + quad * 4 + r;
                float ov = acc[mt][nt][r] + bv;
                out[(size_t)row * COUT + col] = ov;
                s[nt] += ov; sq[nt] += ov * ov;
            }
    }
#pragma unroll
    for (int nt = 0; nt < 2; nt++) {
        float ss = s[nt], qq = sq[nt];
        ss += __shfl_down(ss, 16); qq += __shfl_down(qq, 16);
        ss += __shfl_down(ss, 32); qq += __shfl_down(qq, 32);
        if (quad == 0) {
            bsumS[wid & 1][wc + nt * 16 + l16] = ss;
            bsqS[wid & 1][wc + nt * 16 + l16] = qq;
        }
    }
    __syncthreads();
    if (threadIdx.x < 64) {
        int c = threadIdx.x;
        atomicAdd(&dsum[c0 + c], (double)(bsumS[0][c] + bsumS[1][c]));
        atomicAdd(&dsq[c0 + c], (double)(bsqS[0][c] + bsqS[1][c]));
    }
}

// ---------------- score dots from RAW h; scale/shift computed in-block ----------------
template<int C>
__global__ __launch_bounds__(256) void score_kernel(const float* __restrict__ h,
                                                    const double* __restrict__ dsum,
                                                    const double* __restrict__ dsq,
                                                    const float* __restrict__ g,
                                                    const float* __restrict__ b,
                                                    const float* __restrict__ wrel,
                                                    const float* __restrict__ wroot,
                                                    float* __restrict__ r,
                                                    float* __restrict__ root, int n) {
    __shared__ float sc[C], sh[C], wrl[C], wrt[C];
    if ((int)threadIdx.x < C) {
        int c = threadIdx.x;
        double m = dsum[c] / (double)n;
        double var = dsq[c] / (double)n - m * m;
        float s = g[c] * (float)(1.0 / sqrt(var + 1e-5));
        sc[c] = s; sh[c] = b[c] - (float)m * s;
        wrl[c] = wrel[c]; wrt[c] = wroot[c];
    }
    __syncthreads();
    int gid = blockIdx.x * 256 + threadIdx.x;
    int node = gid >> 6, lane = gid & 63;
    float rr = 0.f, rt = 0.f;
    for (int c = lane; c < C; c += 64) {
        float v = fmaxf(h[(size_t)node * C + c] * sc[c] + sh[c], 0.f);
        rr += v * wrl[c];
        rt += v * wrt[c];
    }
    for (int off = 32; off; off >>= 1) {
        rr += __shfl_down(rr, off);
        rt += __shfl_down(rt, off);
    }
    if (lane == 0) { r[node] = rr; root[node] = rt; }
}

// ---------------- top-k: exact 32-bit radix select, 1024 thr, wave-scan ----------------
__global__ void __launch_bounds__(1024) topk_kernel(const float* __restrict__ r,
                                                    const float* __restrict__ root,
                                                    const int* __restrict__ deg,
                                                    const int* __restrict__ col,
                                                    const float* __restrict__ brel,
                                                    int npg, int k, int* __restrict__ perm,
                                                    float* __restrict__ tval,
                                                    int* __restrict__ map) {
    __shared__ float svals[2048];
    __shared__ uint hist[257];
    __shared__ uint wsum[16];
    __shared__ uint s_b, s_rem;
    int g = blockIdx.x;
    int tid = threadIdx.x;
    int lane = tid & 63, wid = tid >> 6;
    float bv = brel[0];
    for (int i = tid; i < npg; i += 1024) {
        int gi = g * npg + i;
        float acc = bv + root[gi];
        int e0 = gi * SLAB, e1 = e0 + deg[gi];
        for (int e = e0; e < e1; e++) acc += r[col[e]];
        svals[i] = acc;
    }
    if (tid == 256) hist[256] = 0;
    if (tid < 256) hist[tid] = 0;
    __syncthreads();

    uint prefix = 0, himask = 0, rem = (uint)k;
    for (int shift = 24; shift >= 0; shift -= 8) {
        for (int i = tid; i < npg; i += 1024) {
            uint kk = fkey(svals[i]);
            if ((kk & himask) == prefix) atomicAdd(&hist[(kk >> shift) & 255], 1);
        }
        __syncthreads();
        if (tid < 64) {
            int L = tid;
            uint h0 = hist[4 * L], h1 = hist[4 * L + 1], h2 = hist[4 * L + 2],
                 h3 = hist[4 * L + 3];
            uint s3 = h3, s2 = h2 + s3, s1 = h1 + s2, s0 = h0 + s1;
            uint v = s0;
            for (int off = 1; off < 64; off <<= 1) {
                uint u = __shfl_down(v, off);
                if (L + off < 64) v += u;
            }
            uint above = v - s0;
            hist[4 * L] = s0 + above;
            hist[4 * L + 1] = s1 + above;
            hist[4 * L + 2] = s2 + above;
            hist[4 * L + 3] = s3 + above;
        }
        __syncthreads();
        if (tid < 256) {
            uint sb = hist[tid], sb1 = hist[tid + 1];
            if (sb >= rem && sb1 < rem) { s_b = (uint)tid; s_rem = rem - sb1; }
        }
        __syncthreads();
        prefix |= (s_b << shift);
        rem = s_rem;
        himask |= (0xFFu << shift);
        if (tid < 256) hist[tid] = 0;
        __syncthreads();
    }
    uint thr = prefix;
    uint m = rem;

    int nchunk = npg >> 10;
    uint gcnt = 0, ecnt = 0, gflags = 0, eflags = 0;
    for (int j = 0; j < nchunk; j++) {
        uint kk = fkey(svals[tid + (j << 10)]);
        if (kk > thr) { gflags |= 1u << j; gcnt++; }
        else if (kk == thr) { eflags |= 1u << j; ecnt++; }
    }
    uint key = (gcnt << 16) | ecnt;
    uint v = key;
    for (int off = 1; off < 64; off <<= 1) {
        uint u = __shfl_up(v, off);
        if (lane >= off) v += u;
    }
    if (lane == 63) wsum[wid] = v;
    __syncthreads();
    if (tid < 16) {
        uint w0 = wsum[tid], w = w0;
        for (int off = 1; off < 16; off <<= 1) {
            uint u = __shfl_up(w, off);
            if ((int)tid >= off) w += u;
        }
        wsum[tid] = w - w0;
    }
    __syncthreads();
    uint excl = (v - key) + wsum[wid];
    uint gbase = excl >> 16, ebase = excl & 0xFFFFu;
    for (int j = 0; j < nchunk; j++) {
        bool gt = (gflags >> j) & 1u;
        bool eq = (eflags >> j) & 1u;
        if (gt || (eq && ebase < m)) {
            uint pos = gbase + min(ebase, m);
            int i = tid + (j << 10);
            int gi = g * npg + i;
            int o = g * k + (int)pos;
            perm[o] = gi;
            tval[o] = tanhf(svals[i]);
            if (map) map[gi] = o;
        }
        gbase += gt ? 1u : 0u;
        ebase += eq ? 1u : 0u;
    }
}

// -------- fused: BN-apply gather (h1 -> h1pb bf16) + layer2 self-counting fill --------------
__global__ void __launch_bounds__(256) gfill_kernel(
        const float* __restrict__ h1, const int* __restrict__ perm1,
        const float* __restrict__ tv1, const double* __restrict__ dsum,
        const double* __restrict__ dsq, const float* __restrict__ g,
        const float* __restrict__ b, ushort* __restrict__ h1pb,
        const int* __restrict__ src, const int* __restrict__ tgt,
        const int* __restrict__ map, int* __restrict__ wc2, int* __restrict__ col2) {
    int blockBase = blockIdx.x * 256;
    if (blockBase < N1c * H1c) {
        __shared__ float sc[128], sh[128];
        if (threadIdx.x < 128) {
            int c = threadIdx.x;
            double m = dsum[c] / (double)Nn;
            double var = dsq[c] / (double)Nn - m * m;
            float s = g[c] * (float)(1.0 / sqrt(var + 1e-5));
            sc[c] = s; sh[c] = b[c] - (float)m * s;
        }
        __syncthreads();
        int t = blockBase + threadIdx.x;
        int m = t >> 7, c = t & 127;
        float v = fmaxf(h1[((size_t)perm1[m] << 7) + c] * sc[c] + sh[c], 0.f);
        h1pb[t] = f2bf(v * tv1[m]);
    } else {
        int e = blockBase + threadIdx.x - N1c * H1c;
        if (e >= Ee) return;
        int ns = map[src[e]];
        int nt = map[tgt[e]];
        if (ns >= 0 && nt >= 0) {
            int p = atomicAdd(&wc2[nt], 1);
            col2[nt * SLAB + p] = ns;
        }
    }
}

// ---------------- fused: layer2 BN-apply + tanh-scale + pooled accumulate ----------------
__global__ void __launch_bounds__(256) pool_part_kernel(const float* __restrict__ h2,
                                                        const int* __restrict__ perm2,
                                                        const float* __restrict__ tv2,
                                                        const double* __restrict__ dsum,
                                                        const double* __restrict__ dsq,
                                                        const float* __restrict__ g,
                                                        const float* __restrict__ b,
                                                        float* __restrict__ pooled) {
    __shared__ float sc[256], sh[256];
    {
        int c = threadIdx.x;
        double m = dsum[c] / (double)N1c;
        double var = dsq[c] / (double)N1c - m * m;
        float s = g[c] * (float)(1.0 / sqrt(var + 1e-5));
        sc[c] = s; sh[c] = b[c] - (float)m * s;
    }
    __syncthreads();
    int gg = blockIdx.x, p = blockIdx.y, c = threadIdx.x;
    float s = 0.f;
    for (int j = 0; j < 64; j++) {
        int m = gg * K2c + p * 64 + j;
        int row = perm2[m];
        float v = fmaxf(h2[((size_t)row << 8) + c] * sc[c] + sh[c], 0.f);
        s += v * tv2[m];
    }
    atomicAdd(&pooled[gg * H2c + c], s);
}

__global__ void __launch_bounds__(256) pool_fin_kernel(const float* __restrict__ pooled,
                                                       const float* __restrict__ Wlin,
                                                       const float* __restrict__ blin,
                                                       float* __restrict__ out) {
    __shared__ float p0s[256], p1s[256];
    int g = blockIdx.x, c = threadIdx.x;
    float s = fmaxf(pooled[g * 256 + c] * (1.f / (float)K2c), 0.f);
    p0s[c] = s * Wlin[c * 2 + 0];
    p1s[c] = s * Wlin[c * 2 + 1];
    __syncthreads();
    for (int off = 128; off; off >>= 1) {
        if (c < off) { p0s[c] += p0s[c + off]; p1s[c] += p1s[c + off]; }
        __syncthreads();
    }
    if (c == 0) {
        float o0 = p0s[0] + blin[0], o1 = p1s[0] + blin[1];
        float m = fmaxf(o0, o1);
        float e0 = expf(o0 - m), e1 = expf(o1 - m);
        float inv = 1.f / (e0 + e1);
        out[g * 2 + 0] = e0 * inv;
        out[g * 2 + 1] = e1 * inv;
    }
}

extern "C" void kernel_launch(void* const* d_in, const int* in_sizes, int n_in,
                              void* d_out, int out_size, void* d_ws, size_t ws_size,
                              hipStream_t stream) {
    const float* x      = (const float*)d_in[0];
    const int*   ei     = (const int*)d_in[1];
    const int*   src    = ei;
    const int*   tgt    = ei + Ee;
    const float* W1l    = (const float*)d_in[3];
    const float* b1l    = (const float*)d_in[4];
    const float* W1r    = (const float*)d_in[5];
    const float* bn1g   = (const float*)d_in[6];
    const float* bn1b   = (const float*)d_in[7];
    const float* p1Wrel = (const float*)d_in[8];
    const float* p1brel = (const float*)d_in[9];
    const float* p1Wroot= (const float*)d_in[10];
    const float* W2l    = (const float*)d_in[11];
    const float* b2l    = (const float*)d_in[12];
    const float* W2r    = (const float*)d_in[13];
    const float* bn2g   = (const float*)d_in[14];
    const float* bn2b   = (const float*)d_in[15];
    const float* p2Wrel = (const float*)d_in[16];
    const float* p2brel = (const float*)d_in[17];
    const float* p2Wroot= (const float*)d_in[18];
    const float* Wlin   = (const float*)d_in[19];
    const float* blin   = (const float*)d_in[20];
    float* out = (float*)d_out;
    char* ws = (char*)d_ws;

    size_t o = 0;
    auto A = [&](size_t b) { size_t r = o; o += (b + 255) & ~(size_t)255; return r; };
    size_t oBIG1 = A((size_t)Nn * H1c * 4);        // h1 / h2 f32
    size_t oBIG2 = A((size_t)Nn * INc * 4);        // xb + aggb1 bf16
    size_t oPB   = A((size_t)N1c * H1c * 4);       // h1pb + aggb2 bf16
    size_t oCol1 = A((size_t)Nn * SLAB * 4);       // slab CSR layer1 (16.8MB)
    size_t oCol2 = A((size_t)N1c * SLAB * 4);      // slab CSR layer2 (8.4MB)
    size_t oWc1  = A((size_t)Nn * 4);
    size_t oMap  = A((size_t)Nn * 4);
    size_t oR1   = A((size_t)Nn * 4);
    size_t oRoot1= A((size_t)Nn * 4);
    size_t oPerm1= A((size_t)N1c * 4);
    size_t oTv1  = A((size_t)N1c * 4);
    size_t oWc2  = A((size_t)N1c * 4);
    size_t oR2   = A((size_t)N1c * 4);
    size_t oRoot2= A((size_t)N1c * 4);
    size_t oPerm2= A((size_t)N2c * 4);
    size_t oTv2  = A((size_t)N2c * 4);
    size_t oDst  = A(768 * 8);
    size_t oWt1l = A(8192 * 2);
    size_t oWt1r = A(8192 * 2);
    size_t oWt2l = A(32768 * 2);
    size_t oWt2r = A(32768 * 2);
    size_t oPool = A(Bg * H2c * 4);
    (void)ws_size; (void)in_sizes; (void)n_in; (void)out_size;

    float* h1    = (float*)(ws + oBIG1);
    float* h2    = (float*)(ws + oBIG1);
    ushort* xb   = (ushort*)(ws + oBIG2);
    ushort* aggb1= (ushort*)(ws + oBIG2 + (size_t)Nn * 64 * 2);
    ushort* h1pb = (ushort*)(ws + oPB);
    ushort* aggb2= (ushort*)(ws + oPB + (size_t)N1c * 128 * 2);
    int* col1    = (int*)(ws + oCol1);
    int* col2    = (int*)(ws + oCol2);
    int* wc1     = (int*)(ws + oWc1);
    int* map1    = (int*)(ws + oMap);
    float* r1    = (float*)(ws + oR1);
    float* root1 = (float*)(ws + oRoot1);
    int* perm1   = (int*)(ws + oPerm1);
    float* tv1   = (float*)(ws + oTv1);
    int* wc2     = (int*)(ws + oWc2);
    float* r2    = (float*)(ws + oR2);
    float* root2 = (float*)(ws + oRoot2);
    int* perm2   = (int*)(ws + oPerm2);
    float* tv2   = (float*)(ws + oTv2);
    double* dsum1= (double*)(ws + oDst);
    double* dsq1 = dsum1 + 128;
    double* dsum2= dsum1 + 256;
    double* dsq2 = dsum1 + 512;
    ushort* T1l  = (ushort*)(ws + oWt1l);
    ushort* T1r  = (ushort*)(ws + oWt1r);
    ushort* T2l  = (ushort*)(ws + oWt2l);
    ushort* T2r  = (ushort*)(ws + oWt2r);
    float* pooled= (float*)(ws + oPool);

    // 1. prep (wt transpose + inits + xconv)
    prep_kernel<<<(PREP_TOTAL + 255) / 256, 256, 0, stream>>>(
        x, W1l, W1r, W2l, W2r, T1l, T1r, T2l, T2r, xb, map1, wc1, wc2,
        (int*)dsum1, (int*)pooled);

    // 2. layer1 slab CSR (self-counting)
    fill1_kernel<<<Ee / 256, 256, 0, stream>>>(src, tgt, wc1, col1);

    // 3-4. SAGEConv1 (+ fused BN1 stats)
    agg1_kernel<<<2048, 256, 0, stream>>>(xb, wc1, col1, aggb1);
    {
        dim3 g(Nn / 128, H1c / 64);
        gemm_mfma_kernel<INc, H1c><<<g, 256, 0, stream>>>(aggb1, xb, T1l, T1r, b1l, h1,
                                                          dsum1, dsq1);
    }

    // 5-6. score + topk
    score_kernel<H1c><<<Nn / 4, 256, 0, stream>>>(h1, dsum1, dsq1, bn1g, bn1b, p1Wrel,
                                                  p1Wroot, r1, root1, Nn);
    topk_kernel<<<Bg, 1024, 0, stream>>>(r1, root1, wc1, col1, p1brel, NPGc, K1c,
                                         perm1, tv1, map1);

    // 7. BN-apply gather (h1 -> h1pb) + layer2 slab fill
    gfill_kernel<<<(N1c * H1c + Ee) / 256, 256, 0, stream>>>(
        h1, perm1, tv1, dsum1, dsq1, bn1g, bn1b, h1pb, src, tgt, map1, wc2, col2);

    // 8-9. SAGEConv2 (+ fused BN2 stats)
    agg2_kernel<<<2048, 256, 0, stream>>>(h1pb, wc2, col2, aggb2);
    {
        dim3 g(N1c / 128, H2c / 64);
        gemm_mfma_kernel<H1c, H2c><<<g, 256, 0, stream>>>(aggb2, h1pb, T2l, T2r, b2l, h2,
                                                          dsum2, dsq2);
    }

    // 10-11. score + topk
    score_kernel<H2c><<<N1c / 4, 256, 0, stream>>>(h2, dsum2, dsq2, bn2g, bn2b, p2Wrel,
                                                   p2Wroot, r2, root2, N1c);
    topk_kernel<<<Bg, 1024, 0, stream>>>(r2, root2, wc2, col2, p2brel, K1c, K2c,
                                         perm2, tv2, nullptr);

    // 12-13. fused BN-apply + tanh-scale + pool, then readout
    {
        dim3 g(Bg, K2c / 64);
        pool_part_kernel<<<g, 256, 0, stream>>>(h2, perm2, tv2, dsum2, dsq2, bn2g, bn2b,
                                                pooled);
    }
    pool_fin_kernel<<<Bg, 256, 0, stream>>>(pooled, Wlin, blin, out);
}